// Round 8
// baseline (753.262 us; speedup 1.0000x reference)
//
#include <hip/hip_runtime.h>
#include <hip/hip_bf16.h>
#include <cstddef>

// ---------------- zero fill (graph-capture-safe memset) ----------------

__global__ void k_zero_i(int* __restrict__ p, int total) {
    int i = blockIdx.x * blockDim.x + threadIdx.x;
    int stride = gridDim.x * blockDim.x;
    for (; i < total; i += stride) p[i] = 0;
}

// ---------------- degree / norm ----------------

__global__ void k_deg_i(const int* __restrict__ dst, int* __restrict__ deg, int E) {
    int e = blockIdx.x * blockDim.x + threadIdx.x;
    if (e < E) atomicAdd(&deg[dst[e]], 1);
}

__global__ void k_dinv(const int* __restrict__ deg, float* __restrict__ dinv, int N) {
    int i = blockIdx.x * blockDim.x + threadIdx.x;
    if (i < N) dinv[i] = rsqrtf((float)deg[i] + 1.0f);
}

// ---------------- exclusive scan (3-phase, N <= 1024*1024) ----------------

#define SCAN_B 1024

__global__ void k_scan1(const int* __restrict__ in, int* __restrict__ out,
                        int* __restrict__ sums, int n) {
    __shared__ int tmp[SCAN_B];
    int tid = threadIdx.x;
    int gid = blockIdx.x * SCAN_B + tid;
    int v = (gid < n) ? in[gid] : 0;
    tmp[tid] = v;
    __syncthreads();
    for (int off = 1; off < SCAN_B; off <<= 1) {
        int t = (tid >= off) ? tmp[tid - off] : 0;
        __syncthreads();
        tmp[tid] += t;
        __syncthreads();
    }
    if (gid < n) out[gid] = tmp[tid] - v;          // exclusive
    if (tid == SCAN_B - 1) sums[blockIdx.x] = tmp[tid];
}

__global__ void k_scan2(int* __restrict__ sums, int nb) {
    __shared__ int tmp[128];
    int tid = threadIdx.x;
    int v = (tid < nb) ? sums[tid] : 0;
    tmp[tid] = v;
    __syncthreads();
    for (int off = 1; off < 128; off <<= 1) {
        int t = (tid >= off) ? tmp[tid - off] : 0;
        __syncthreads();
        tmp[tid] += t;
        __syncthreads();
    }
    if (tid < nb) sums[tid] = tmp[tid] - v;        // exclusive block offsets
}

__global__ void k_scan3(int* __restrict__ out, int* __restrict__ cursor,
                        const int* __restrict__ sums, int n) {
    int gid = blockIdx.x * SCAN_B + threadIdx.x;
    if (gid < n) {
        int v = out[gid] + sums[blockIdx.x];
        out[gid] = v;
        cursor[gid] = v;
    }
}

// ---------------- CSR fill ----------------

__global__ void k_fill(const int* __restrict__ src, const int* __restrict__ dst,
                       int* __restrict__ cursor, int* __restrict__ csr_src, int E) {
    int e = blockIdx.x * blockDim.x + threadIdx.x;
    if (e < E) {
        int pos = atomicAdd(&cursor[dst[e]], 1);
        csr_src[pos] = src[e];
    }
}

// ---------------- fused gather aggregation + self-loop + bias + relu ----------
// out[n] = relu( sum_{s in in(n)} h[s]*dinv[s]*dinv[n] + h[n]*dinv[n]^2 + bias )
// One wave per node. F=128: 32 lanes/edge (float4), 2 edges per step, 2-unrolled.
// F=64: 16 lanes/edge (float4), 4 edges per step, 2-unrolled.

__device__ __forceinline__ float4 shfl_xor4(float4 v, int m) {
    return make_float4(__shfl_xor(v.x, m), __shfl_xor(v.y, m),
                       __shfl_xor(v.z, m), __shfl_xor(v.w, m));
}

__device__ __forceinline__ void fmaa4(float4& c, float w, const float4& v) {
    c.x = fmaf(w, v.x, c.x);
    c.y = fmaf(w, v.y, c.y);
    c.z = fmaf(w, v.z, c.z);
    c.w = fmaf(w, v.w, c.w);
}

template<int F>
__launch_bounds__(256)
__global__ void k_gather(const float* __restrict__ h, const int* __restrict__ csr_src,
                         const int* __restrict__ off, const float* __restrict__ dinv,
                         const float* __restrict__ bias, float* __restrict__ out,
                         int N, int E)
{
    int node = blockIdx.x * (blockDim.x / 64) + (threadIdx.x >> 6);
    int lane = threadIdx.x & 63;
    if (node >= N) return;
    float dn = dinv[node];
    int beg = off[node];
    int end = (node + 1 < N) ? off[node + 1] : E;

    constexpr int G = (F == 128) ? 2 : 4;      // edge groups per wave
    constexpr int SUBW = 64 / G;               // lanes per edge
    const int grp = lane / SUBW;
    const int sub = lane % SUBW;

    float4 acc = make_float4(0.f, 0.f, 0.f, 0.f);
    int i = beg + grp;
    for (; i + G < end; i += 2 * G) {
        int s0 = csr_src[i];
        int s1 = csr_src[i + G];
        float w0 = dinv[s0] * dn;
        float w1 = dinv[s1] * dn;
        float4 v0 = *(const float4*)(h + (size_t)s0 * F + sub * 4);
        float4 v1 = *(const float4*)(h + (size_t)s1 * F + sub * 4);
        fmaa4(acc, w0, v0);
        fmaa4(acc, w1, v1);
    }
    if (i < end) {
        int s = csr_src[i];
        float w = dinv[s] * dn;
        float4 v = *(const float4*)(h + (size_t)s * F + sub * 4);
        fmaa4(acc, w, v);
    }

    // cross-group reduce
    if (F == 64) acc = make_float4(acc.x + __shfl_xor(acc.x, 16),
                                   acc.y + __shfl_xor(acc.y, 16),
                                   acc.z + __shfl_xor(acc.z, 16),
                                   acc.w + __shfl_xor(acc.w, 16));
    {
        float4 o = shfl_xor4(acc, 32);
        acc.x += o.x; acc.y += o.y; acc.z += o.z; acc.w += o.w;
    }

    if (grp == 0) {
        float4 hv = *(const float4*)(h + (size_t)node * F + sub * 4);
        float4 bv = *(const float4*)(bias + sub * 4);
        float w = dn * dn;
        acc.x = fmaxf(fmaf(hv.x, w, acc.x) + bv.x, 0.f);
        acc.y = fmaxf(fmaf(hv.y, w, acc.y) + bv.y, 0.f);
        acc.z = fmaxf(fmaf(hv.z, w, acc.z) + bv.z, 0.f);
        acc.w = fmaxf(fmaf(hv.w, w, acc.w) + bv.w, 0.f);
        *(float4*)(out + (size_t)node * F + sub * 4) = acc;
    }
}

// ---------------- wave-tile fp32 GEMM (reg-prefetch pipelined) ----------------
// C[M,N] = A[M,K] @ B[K,N] (+bias). 256 threads = 4 waves WR x WC; wave tile
// (32*RM)x(32*RN); lane l = (l%8, l/8), RM x RN 4x4 sub-blocks at (+32i,+32j).
// Inner-loop LDS reads = aligned conflict-free ds_read_b128. Pipeline: tile
// t+1 is loaded into REGISTERS while tile t computes; LDS write happens at
// the phase boundary (loads overlap compute instead of sitting after the
// barrier — R7 measured VALUBusy 44% from exposed load latency).

__device__ __forceinline__ void fma4(float4& c, float a, const float4& b) {
    c.x = fmaf(a, b.x, c.x);
    c.y = fmaf(a, b.y, c.y);
    c.z = fmaf(a, b.z, c.z);
    c.w = fmaf(a, b.w, c.w);
}

template<int WR, int WC, int BK, int RM, int RN>
__launch_bounds__(256, 2)
__global__ void gemm_wt(const float* __restrict__ A, const float* __restrict__ B,
                        const float* __restrict__ bias, float* __restrict__ C,
                        int M, int N, int K)
{
    constexpr int TMW = 32 * RM;
    constexpr int TNW = 32 * RN;
    constexpr int BM = WR * TMW;
    constexpr int BN = WC * TNW;
    constexpr int LDA = BM + 4;
    __shared__ float As[BK * LDA];
    __shared__ float Bs[BK * BN];

    const int tid  = threadIdx.x;
    const int wave = tid >> 6, lane = tid & 63;
    const int wr = wave / WC, wc = wave % WC;
    const int ar = wr * TMW + (lane & 7) * 4;
    const int bc = wc * TNW + (lane >> 3) * 4;
    const int m0 = blockIdx.x * BM;
    const int n0 = blockIdx.y * BN;

    constexpr int AC4   = BK / 4;
    constexpr int AROWS = 256 / AC4;
    constexpr int PA    = BM / AROWS;
    const int a_c4 = tid % AC4;
    const int a_m  = tid / AC4;
    constexpr int BC4   = BN / 4;
    constexpr int BROWS = 256 / BC4;
    constexpr int PB    = BK / BROWS;
    const int b_c4 = tid % BC4;
    const int b_r  = tid / BC4;

    float4 aR[PA], bR[PB];
    auto load_tile = [&](int k0) {
#pragma unroll
        for (int p = 0; p < PA; ++p) {
            int gr = m0 + a_m + p * AROWS;
            float4 v = make_float4(0.f, 0.f, 0.f, 0.f);
            if (gr < M) v = *(const float4*)(A + (size_t)gr * K + k0 + 4 * a_c4);
            aR[p] = v;
        }
#pragma unroll
        for (int p = 0; p < PB; ++p) {
            int r = b_r + p * BROWS;
            int gc = n0 + 4 * b_c4;
            const float* Brow = B + (size_t)(k0 + r) * N;
            float4 v = make_float4(0.f, 0.f, 0.f, 0.f);
            if (gc + 3 < N) {
                v = *(const float4*)(Brow + gc);
            } else {
                if (gc + 0 < N) v.x = Brow[gc + 0];
                if (gc + 1 < N) v.y = Brow[gc + 1];
                if (gc + 2 < N) v.z = Brow[gc + 2];
            }
            bR[p] = v;
        }
    };

    float4 acc[RM][RN][4];
#pragma unroll
    for (int i = 0; i < RM; ++i)
#pragma unroll
        for (int j = 0; j < RN; ++j)
#pragma unroll
            for (int r = 0; r < 4; ++r) acc[i][j][r] = make_float4(0.f, 0.f, 0.f, 0.f);

    load_tile(0);

    for (int k0 = 0; k0 < K; k0 += BK) {
        __syncthreads();                        // prior compute done reading LDS
        // ---- write staged regs -> LDS ----
#pragma unroll
        for (int p = 0; p < PA; ++p) {
            int m = a_m + p * AROWS;
            As[(4 * a_c4 + 0) * LDA + m] = aR[p].x;
            As[(4 * a_c4 + 1) * LDA + m] = aR[p].y;
            As[(4 * a_c4 + 2) * LDA + m] = aR[p].z;
            As[(4 * a_c4 + 3) * LDA + m] = aR[p].w;
        }
#pragma unroll
        for (int p = 0; p < PB; ++p) {
            int r = b_r + p * BROWS;
            *(float4*)&Bs[r * BN + 4 * b_c4] = bR[p];
        }
        if (k0 + BK < K) load_tile(k0 + BK);    // overlaps next compute
        __syncthreads();

#pragma unroll 8
        for (int kk = 0; kk < BK; ++kk) {
            const float* as = &As[kk * LDA];
            const float* bs = &Bs[kk * BN];
            float4 af[RM], bf[RN];
#pragma unroll
            for (int i = 0; i < RM; ++i) af[i] = *(const float4*)(as + ar + 32 * i);
#pragma unroll
            for (int j = 0; j < RN; ++j) bf[j] = *(const float4*)(bs + bc + 32 * j);
#pragma unroll
            for (int i = 0; i < RM; ++i) {
                float ae[4] = {af[i].x, af[i].y, af[i].z, af[i].w};
#pragma unroll
                for (int r = 0; r < 4; ++r)
#pragma unroll
                    for (int j = 0; j < RN; ++j)
                        fma4(acc[i][j][r], ae[r], bf[j]);
            }
        }
    }

    // ---- epilogue ----
#pragma unroll
    for (int i = 0; i < RM; ++i)
#pragma unroll
        for (int r = 0; r < 4; ++r) {
            int gr = m0 + ar + 32 * i + r;
            if (gr >= M) continue;
#pragma unroll
            for (int j = 0; j < RN; ++j) {
                int gc = n0 + bc + 32 * j;
                float4 v = acc[i][j][r];
                if (gc + 3 < N) {
                    if (bias) {
                        v.x += bias[gc + 0];
                        v.y += bias[gc + 1];
                        v.z += bias[gc + 2];
                        v.w += bias[gc + 3];
                    }
                    *(float4*)(C + (size_t)gr * N + gc) = v;
                } else {
                    float vv[4] = {v.x, v.y, v.z, v.w};
#pragma unroll
                    for (int e = 0; e < 4; ++e)
                        if (gc + e < N)
                            C[(size_t)gr * N + gc + e] = vv[e] + (bias ? bias[gc + e] : 0.f);
                }
            }
        }
}

// ---------------- output GEMM: C[M,1000] = A[M,64] @ B[64,1000] + bias -------
// K=64 fits LDS: stage the 128x64 A-tile ONCE per block, then loop all column
// chunks of B in-block (kills the 8x A re-fetch), prefetching the next B chunk
// into registers during compute. 4 waves 2x2, wave tile 64x64, RM=RN=2.

__launch_bounds__(256, 2)
__global__ void gemm_out(const float* __restrict__ A, const float* __restrict__ B,
                         const float* __restrict__ bias, float* __restrict__ C,
                         int M, int N)
{
    constexpr int BM = 128, BKF = 64, BN = 128;
    constexpr int LDA = BM + 4;
    __shared__ float As[BKF * LDA];        // 33.8 KB
    __shared__ float Bs[BKF * BN];         // 32.8 KB

    const int tid  = threadIdx.x;
    const int wave = tid >> 6, lane = tid & 63;
    const int wr = wave >> 1, wc = wave & 1;
    const int ar = wr * 64 + (lane & 7) * 4;
    const int bc = wc * 64 + (lane >> 3) * 4;
    const int m0 = blockIdx.x * BM;

    // ---- stage A once: As[k][m] = A[m0+m][k], 2048 float4s, 8/thread ----
    float4 aR[8];
#pragma unroll
    for (int p = 0; p < 8; ++p) {
        int f = tid + p * 256;
        int row = f >> 4, kq = f & 15;
        int gr = m0 + row;
        float4 v = make_float4(0.f, 0.f, 0.f, 0.f);
        if (gr < M) v = *(const float4*)(A + (size_t)gr * BKF + kq * 4);
        aR[p] = v;
    }
    // ---- prefetch B chunk 0 ----
    float4 bR[8];
    auto load_b = [&](int base) {
#pragma unroll
        for (int p = 0; p < 8; ++p) {
            int f = tid + p * 256;
            int k = f >> 5, nq = f & 31;
            int gc = base + nq * 4;
            const float* Brow = B + (size_t)k * N;
            float4 v = make_float4(0.f, 0.f, 0.f, 0.f);
            if (gc + 3 < N) {
                v = *(const float4*)(Brow + gc);
            } else {
                if (gc + 0 < N) v.x = Brow[gc + 0];
                if (gc + 1 < N) v.y = Brow[gc + 1];
                if (gc + 2 < N) v.z = Brow[gc + 2];
            }
            bR[p] = v;
        }
    };
    load_b(0);

    // write As (no barrier needed yet; first in-loop barrier covers visibility)
#pragma unroll
    for (int p = 0; p < 8; ++p) {
        int f = tid + p * 256;
        int row = f >> 4, kq = f & 15;
        As[(4 * kq + 0) * LDA + row] = aR[p].x;
        As[(4 * kq + 1) * LDA + row] = aR[p].y;
        As[(4 * kq + 2) * LDA + row] = aR[p].z;
        As[(4 * kq + 3) * LDA + row] = aR[p].w;
    }

    const int nchunks = (N + BN - 1) / BN;
    float4 acc[2][2][4];

    for (int c = 0; c < nchunks; ++c) {
        __syncthreads();                    // prev compute done reading Bs
        // ---- write B chunk c regs -> LDS ----
#pragma unroll
        for (int p = 0; p < 8; ++p) {
            int f = tid + p * 256;
            int k = f >> 5, nq = f & 31;
            *(float4*)&Bs[k * BN + 4 * nq] = bR[p];
        }
        if (c + 1 < nchunks) load_b((c + 1) * BN);   // overlaps compute
        __syncthreads();

#pragma unroll
        for (int i = 0; i < 2; ++i)
#pragma unroll
            for (int j = 0; j < 2; ++j)
#pragma unroll
                for (int r = 0; r < 4; ++r) acc[i][j][r] = make_float4(0.f, 0.f, 0.f, 0.f);

#pragma unroll 8
        for (int kk = 0; kk < BKF; ++kk) {
            const float* as = &As[kk * LDA];
            const float* bs = &Bs[kk * BN];
            float4 a0 = *(const float4*)(as + ar);
            float4 a1 = *(const float4*)(as + ar + 32);
            float4 b0 = *(const float4*)(bs + bc);
            float4 b1 = *(const float4*)(bs + bc + 32);
            float ae0[4] = {a0.x, a0.y, a0.z, a0.w};
            float ae1[4] = {a1.x, a1.y, a1.z, a1.w};
#pragma unroll
            for (int r = 0; r < 4; ++r) {
                fma4(acc[0][0][r], ae0[r], b0);
                fma4(acc[0][1][r], ae0[r], b1);
                fma4(acc[1][0][r], ae1[r], b0);
                fma4(acc[1][1][r], ae1[r], b1);
            }
        }

        // ---- epilogue for this chunk ----
        int base = c * BN;
#pragma unroll
        for (int i = 0; i < 2; ++i)
#pragma unroll
            for (int r = 0; r < 4; ++r) {
                int gr = m0 + ar + 32 * i + r;
                if (gr >= M) continue;
#pragma unroll
                for (int j = 0; j < 2; ++j) {
                    int gc = base + bc + 32 * j;
                    float4 v = acc[i][j][r];
                    if (gc + 3 < N) {
                        v.x += bias[gc + 0];
                        v.y += bias[gc + 1];
                        v.z += bias[gc + 2];
                        v.w += bias[gc + 3];
                        *(float4*)(C + (size_t)gr * N + gc) = v;
                    } else {
                        float vv[4] = {v.x, v.y, v.z, v.w};
#pragma unroll
                        for (int e = 0; e < 4; ++e)
                            if (gc + e < N)
                                C[(size_t)gr * N + gc + e] = vv[e] + bias[gc + e];
                    }
                }
            }
    }
}

// ---------------- launch ----------------
// Harness passes integer inputs as int32. d_out (400 MB) doubles as scratch:
//   O0 h[N,128] | O1 h1[N,128] | O2 h2pre[N,64] | csr_src[E] | offs[N]
//   cursor[N] | deg_cnt[N] | bsums[128]          (all dead before final GEMM)
// d_ws: [dinv 0.5MB][h2 25.6MB] — h2 must survive the final GEMM's d_out writes.

extern "C" void kernel_launch(void* const* d_in, const int* in_sizes, int n_in,
                              void* d_out, int out_size, void* d_ws, size_t ws_size,
                              hipStream_t stream)
{
    const float* x   = (const float*)d_in[0];
    const float* W1  = (const float*)d_in[1];
    const float* b1  = (const float*)d_in[2];
    const float* W2  = (const float*)d_in[3];
    const float* b2  = (const float*)d_in[4];
    const float* Wfc = (const float*)d_in[5];
    const float* bfc = (const float*)d_in[6];
    const int*   ei  = (const int*)d_in[7];     // int32 in the harness

    const int Nn = in_sizes[0] / 128;      // 100000 nodes
    const int E  = in_sizes[7] / 2;        // 1600000 edges
    const int* src = ei;
    const int* dst = ei + E;

    char* ws = (char*)d_ws;
    float* dinv = (float*)(ws);                        // Nn floats
    float* h2   = (float*)(ws + 512 * 1024);           // Nn*64 floats (25.6 MB)

    float* out = (float*)d_out;
    float* O0      = out;                              // h [Nn,128]
    float* O1      = out + (size_t)Nn * 128;           // h1 [Nn,128]
    float* O2      = out + (size_t)Nn * 256;           // h2pre [Nn,64]
    int*   csr_src = (int*)(out + (size_t)Nn * 320);   // E ints
    int*   offs    = (int*)((char*)csr_src + (size_t)E * 4);
    int*   cursor  = (int*)((char*)offs + (size_t)Nn * 4);
    int*   deg_cnt = (int*)((char*)cursor + (size_t)Nn * 4);
    int*   bsums   = (int*)((char*)deg_cnt + (size_t)Nn * 4);

    const int nScanBlocks = (Nn + SCAN_B - 1) / SCAN_B;   // 98 <= 128

    // ---- degree, dinv, offsets, cursor ----
    k_zero_i<<<128, 256, 0, stream>>>(deg_cnt, Nn);
    k_deg_i<<<(E + 255) / 256, 256, 0, stream>>>(dst, deg_cnt, E);
    k_dinv<<<(Nn + 255) / 256, 256, 0, stream>>>(deg_cnt, dinv, Nn);
    k_scan1<<<nScanBlocks, SCAN_B, 0, stream>>>(deg_cnt, offs, bsums, Nn);
    k_scan2<<<1, 128, 0, stream>>>(bsums, nScanBlocks);
    k_scan3<<<nScanBlocks, SCAN_B, 0, stream>>>(offs, cursor, bsums, Nn);

    // ---- CSR fill ----
    k_fill<<<(E + 255) / 256, 256, 0, stream>>>(src, dst, cursor, csr_src, E);

    // ---- layer 1 ----
    // h = x @ W1 -> O0   (BM=256, BN=128, K=128, pipelined)
    gemm_wt<2, 2, 32, 4, 2><<<dim3((Nn + 255) / 256, 1), 256, 0, stream>>>(
        x, W1, nullptr, O0, Nn, 128, 128);
    // h1 = relu(gather(h) + self + b1) -> O1
    k_gather<128><<<(Nn + 3) / 4, 256, 0, stream>>>(O0, csr_src, offs, dinv, b1, O1, Nn, E);

    // ---- layer 2 ----
    // h2pre = h1 @ W2 -> O2   (BM=256, BN=64, K=128, pipelined)
    gemm_wt<2, 2, 32, 4, 1><<<dim3((Nn + 255) / 256, 1), 256, 0, stream>>>(
        O1, W2, nullptr, O2, Nn, 64, 128);
    // h2 = relu(gather(h2pre) + self + b2) -> ws
    k_gather<64><<<(Nn + 3) / 4, 256, 0, stream>>>(O2, csr_src, offs, dinv, b2, h2, Nn, E);

    // ---- output layer: out = h2 @ Wfc + bfc (A staged once, B chunks looped) ----
    gemm_out<<<dim3((Nn + 127) / 128, 1), 256, 0, stream>>>(
        h2, Wfc, bfc, out, Nn, 1000);
}

// Round 9
// 693.699 us; speedup vs baseline: 1.0859x; 1.0859x over previous
//
#include <hip/hip_runtime.h>
#include <hip/hip_bf16.h>
#include <cstddef>

typedef __attribute__((ext_vector_type(8))) short bf16x8;
typedef __attribute__((ext_vector_type(4))) float f32x4;

__device__ __forceinline__ unsigned short f2bf(float f) {
    __hip_bfloat16 h = __float2bfloat16(f);
    return __builtin_bit_cast(unsigned short, h);
}
__device__ __forceinline__ float bf2f(unsigned short u) {
    return __bfloat162float(__builtin_bit_cast(__hip_bfloat16, u));
}

// ---------------- zero fill ----------------

__global__ void k_zero_i(int* __restrict__ p, int total) {
    int i = blockIdx.x * blockDim.x + threadIdx.x;
    int stride = gridDim.x * blockDim.x;
    for (; i < total; i += stride) p[i] = 0;
}

// ---------------- degree / norm ----------------

__global__ void k_deg_i(const int* __restrict__ dst, int* __restrict__ deg, int E) {
    int e = blockIdx.x * blockDim.x + threadIdx.x;
    if (e < E) atomicAdd(&deg[dst[e]], 1);
}

__global__ void k_dinv(const int* __restrict__ deg, float* __restrict__ dinv, int N) {
    int i = blockIdx.x * blockDim.x + threadIdx.x;
    if (i < N) dinv[i] = rsqrtf((float)deg[i] + 1.0f);
}

// ---------------- exclusive scan ----------------

#define SCAN_B 1024

__global__ void k_scan1(const int* __restrict__ in, int* __restrict__ out,
                        int* __restrict__ sums, int n) {
    __shared__ int tmp[SCAN_B];
    int tid = threadIdx.x;
    int gid = blockIdx.x * SCAN_B + tid;
    int v = (gid < n) ? in[gid] : 0;
    tmp[tid] = v;
    __syncthreads();
    for (int off = 1; off < SCAN_B; off <<= 1) {
        int t = (tid >= off) ? tmp[tid - off] : 0;
        __syncthreads();
        tmp[tid] += t;
        __syncthreads();
    }
    if (gid < n) out[gid] = tmp[tid] - v;
    if (tid == SCAN_B - 1) sums[blockIdx.x] = tmp[tid];
}

__global__ void k_scan2(int* __restrict__ sums, int nb) {
    __shared__ int tmp[128];
    int tid = threadIdx.x;
    int v = (tid < nb) ? sums[tid] : 0;
    tmp[tid] = v;
    __syncthreads();
    for (int off = 1; off < 128; off <<= 1) {
        int t = (tid >= off) ? tmp[tid - off] : 0;
        __syncthreads();
        tmp[tid] += t;
        __syncthreads();
    }
    if (tid < nb) sums[tid] = tmp[tid] - v;
}

__global__ void k_scan3(int* __restrict__ out, int* __restrict__ cursor,
                        const int* __restrict__ sums, int n) {
    int gid = blockIdx.x * SCAN_B + threadIdx.x;
    if (gid < n) {
        int v = out[gid] + sums[blockIdx.x];
        out[gid] = v;
        cursor[gid] = v;
    }
}

// ---------------- CSR fill ----------------

__global__ void k_fill(const int* __restrict__ src, const int* __restrict__ dst,
                       int* __restrict__ cursor, int* __restrict__ csr_src, int E) {
    int e = blockIdx.x * blockDim.x + threadIdx.x;
    if (e < E) {
        int pos = atomicAdd(&cursor[dst[e]], 1);
        csr_src[pos] = src[e];
    }
}

// ---------------- fused gather (F=128, fp32 out) ----------------

__device__ __forceinline__ float4 shfl_xor4(float4 v, int m) {
    return make_float4(__shfl_xor(v.x, m), __shfl_xor(v.y, m),
                       __shfl_xor(v.z, m), __shfl_xor(v.w, m));
}

__device__ __forceinline__ void fmaa4(float4& c, float w, const float4& v) {
    c.x = fmaf(w, v.x, c.x);
    c.y = fmaf(w, v.y, c.y);
    c.z = fmaf(w, v.z, c.z);
    c.w = fmaf(w, v.w, c.w);
}

__launch_bounds__(256)
__global__ void k_gather128(const float* __restrict__ h, const int* __restrict__ csr_src,
                            const int* __restrict__ off, const float* __restrict__ dinv,
                            const float* __restrict__ bias, float* __restrict__ out,
                            int N, int E)
{
    int node = blockIdx.x * 4 + (threadIdx.x >> 6);
    int lane = threadIdx.x & 63;
    if (node >= N) return;
    float dn = dinv[node];
    int beg = off[node];
    int end = (node + 1 < N) ? off[node + 1] : E;

    const int grp = lane >> 5;          // 2 edges in parallel, 32 lanes each
    const int sub = lane & 31;

    float4 acc = make_float4(0.f, 0.f, 0.f, 0.f);
    int i = beg + grp;
    for (; i + 2 < end; i += 4) {
        int s0 = csr_src[i];
        int s1 = csr_src[i + 2];
        float w0 = dinv[s0] * dn;
        float w1 = dinv[s1] * dn;
        float4 v0 = *(const float4*)(h + (size_t)s0 * 128 + sub * 4);
        float4 v1 = *(const float4*)(h + (size_t)s1 * 128 + sub * 4);
        fmaa4(acc, w0, v0);
        fmaa4(acc, w1, v1);
    }
    if (i < end) {
        int s = csr_src[i];
        float w = dinv[s] * dn;
        float4 v = *(const float4*)(h + (size_t)s * 128 + sub * 4);
        fmaa4(acc, w, v);
    }
    {
        float4 o = shfl_xor4(acc, 32);
        acc.x += o.x; acc.y += o.y; acc.z += o.z; acc.w += o.w;
    }
    if (grp == 0) {
        float4 hv = *(const float4*)(h + (size_t)node * 128 + sub * 4);
        float4 bv = *(const float4*)(bias + sub * 4);
        float w = dn * dn;
        acc.x = fmaxf(fmaf(hv.x, w, acc.x) + bv.x, 0.f);
        acc.y = fmaxf(fmaf(hv.y, w, acc.y) + bv.y, 0.f);
        acc.z = fmaxf(fmaf(hv.z, w, acc.z) + bv.z, 0.f);
        acc.w = fmaxf(fmaf(hv.w, w, acc.w) + bv.w, 0.f);
        *(float4*)(out + (size_t)node * 128 + sub * 4) = acc;
    }
}

// ---------------- fused gather (F=64) -> split bf16 hi/lo output -------------
// Output feeds the MFMA GEMM: h2hi/h2lo [N][64] bf16 row-major.

__launch_bounds__(256)
__global__ void k_gather64(const float* __restrict__ h, const int* __restrict__ csr_src,
                           const int* __restrict__ off, const float* __restrict__ dinv,
                           const float* __restrict__ bias,
                           unsigned short* __restrict__ hhi, unsigned short* __restrict__ hlo,
                           int N, int E)
{
    int node = blockIdx.x * 4 + (threadIdx.x >> 6);
    int lane = threadIdx.x & 63;
    if (node >= N) return;
    float dn = dinv[node];
    int beg = off[node];
    int end = (node + 1 < N) ? off[node + 1] : E;

    const int grp = lane >> 4;          // 4 edges in parallel, 16 lanes each
    const int sub = lane & 15;

    float4 acc = make_float4(0.f, 0.f, 0.f, 0.f);
    int i = beg + grp;
    for (; i + 4 < end; i += 8) {
        int s0 = csr_src[i];
        int s1 = csr_src[i + 4];
        float w0 = dinv[s0] * dn;
        float w1 = dinv[s1] * dn;
        float4 v0 = *(const float4*)(h + (size_t)s0 * 64 + sub * 4);
        float4 v1 = *(const float4*)(h + (size_t)s1 * 64 + sub * 4);
        fmaa4(acc, w0, v0);
        fmaa4(acc, w1, v1);
    }
    if (i < end) {
        int s = csr_src[i];
        float w = dinv[s] * dn;
        float4 v = *(const float4*)(h + (size_t)s * 64 + sub * 4);
        fmaa4(acc, w, v);
    }
    acc = make_float4(acc.x + __shfl_xor(acc.x, 16),
                      acc.y + __shfl_xor(acc.y, 16),
                      acc.z + __shfl_xor(acc.z, 16),
                      acc.w + __shfl_xor(acc.w, 16));
    {
        float4 o = shfl_xor4(acc, 32);
        acc.x += o.x; acc.y += o.y; acc.z += o.z; acc.w += o.w;
    }
    if (grp == 0) {
        float4 hv = *(const float4*)(h + (size_t)node * 64 + sub * 4);
        float4 bv = *(const float4*)(bias + sub * 4);
        float w = dn * dn;
        float f0 = fmaxf(fmaf(hv.x, w, acc.x) + bv.x, 0.f);
        float f1 = fmaxf(fmaf(hv.y, w, acc.y) + bv.y, 0.f);
        float f2 = fmaxf(fmaf(hv.z, w, acc.z) + bv.z, 0.f);
        float f3 = fmaxf(fmaf(hv.w, w, acc.w) + bv.w, 0.f);
        ushort4 hi, lo;
        hi.x = f2bf(f0); lo.x = f2bf(f0 - bf2f(hi.x));
        hi.y = f2bf(f1); lo.y = f2bf(f1 - bf2f(hi.y));
        hi.z = f2bf(f2); lo.z = f2bf(f2 - bf2f(hi.z));
        hi.w = f2bf(f3); lo.w = f2bf(f3 - bf2f(hi.w));
        *(ushort4*)(hhi + (size_t)node * 64 + sub * 4) = hi;
        *(ushort4*)(hlo + (size_t)node * 64 + sub * 4) = lo;
    }
}

// ---------------- Wfc -> transposed split-bf16 [col][k] ----------------

__global__ void k_conv_wfc(const float* __restrict__ W, unsigned short* __restrict__ Bh,
                           unsigned short* __restrict__ Bl, int K, int N)
{
    int n = blockIdx.x;
    int k = threadIdx.x;                 // 64 threads
    float v = W[(size_t)k * N + n];
    unsigned short hi = f2bf(v);
    unsigned short lo = f2bf(v - bf2f(hi));
    Bh[(size_t)n * 64 + k] = hi;
    Bl[(size_t)n * 64 + k] = lo;
}

// ---------------- wave-tile fp32 GEMM (reg-prefetch pipelined) ---------------

__device__ __forceinline__ void fma4(float4& c, float a, const float4& b) {
    c.x = fmaf(a, b.x, c.x);
    c.y = fmaf(a, b.y, c.y);
    c.z = fmaf(a, b.z, c.z);
    c.w = fmaf(a, b.w, c.w);
}

template<int WR, int WC, int BK, int RM, int RN>
__launch_bounds__(256, 2)
__global__ void gemm_wt(const float* __restrict__ A, const float* __restrict__ B,
                        const float* __restrict__ bias, float* __restrict__ C,
                        int M, int N, int K)
{
    constexpr int TMW = 32 * RM;
    constexpr int TNW = 32 * RN;
    constexpr int BM = WR * TMW;
    constexpr int BN = WC * TNW;
    constexpr int LDA = BM + 4;
    __shared__ float As[BK * LDA];
    __shared__ float Bs[BK * BN];

    const int tid  = threadIdx.x;
    const int wave = tid >> 6, lane = tid & 63;
    const int wr = wave / WC, wc = wave % WC;
    const int ar = wr * TMW + (lane & 7) * 4;
    const int bc = wc * TNW + (lane >> 3) * 4;
    const int m0 = blockIdx.x * BM;
    const int n0 = blockIdx.y * BN;

    constexpr int AC4   = BK / 4;
    constexpr int AROWS = 256 / AC4;
    constexpr int PA    = BM / AROWS;
    const int a_c4 = tid % AC4;
    const int a_m  = tid / AC4;
    constexpr int BC4   = BN / 4;
    constexpr int BROWS = 256 / BC4;
    constexpr int PB    = BK / BROWS;
    const int b_c4 = tid % BC4;
    const int b_r  = tid / BC4;

    float4 aR[PA], bR[PB];
    auto load_tile = [&](int k0) {
#pragma unroll
        for (int p = 0; p < PA; ++p) {
            int gr = m0 + a_m + p * AROWS;
            float4 v = make_float4(0.f, 0.f, 0.f, 0.f);
            if (gr < M) v = *(const float4*)(A + (size_t)gr * K + k0 + 4 * a_c4);
            aR[p] = v;
        }
#pragma unroll
        for (int p = 0; p < PB; ++p) {
            int r = b_r + p * BROWS;
            int gc = n0 + 4 * b_c4;
            const float* Brow = B + (size_t)(k0 + r) * N;
            float4 v = make_float4(0.f, 0.f, 0.f, 0.f);
            if (gc + 3 < N) {
                v = *(const float4*)(Brow + gc);
            } else {
                if (gc + 0 < N) v.x = Brow[gc + 0];
                if (gc + 1 < N) v.y = Brow[gc + 1];
                if (gc + 2 < N) v.z = Brow[gc + 2];
            }
            bR[p] = v;
        }
    };

    float4 acc[RM][RN][4];
#pragma unroll
    for (int i = 0; i < RM; ++i)
#pragma unroll
        for (int j = 0; j < RN; ++j)
#pragma unroll
            for (int r = 0; r < 4; ++r) acc[i][j][r] = make_float4(0.f, 0.f, 0.f, 0.f);

    load_tile(0);

    for (int k0 = 0; k0 < K; k0 += BK) {
        __syncthreads();
#pragma unroll
        for (int p = 0; p < PA; ++p) {
            int m = a_m + p * AROWS;
            As[(4 * a_c4 + 0) * LDA + m] = aR[p].x;
            As[(4 * a_c4 + 1) * LDA + m] = aR[p].y;
            As[(4 * a_c4 + 2) * LDA + m] = aR[p].z;
            As[(4 * a_c4 + 3) * LDA + m] = aR[p].w;
        }
#pragma unroll
        for (int p = 0; p < PB; ++p) {
            int r = b_r + p * BROWS;
            *(float4*)&Bs[r * BN + 4 * b_c4] = bR[p];
        }
        if (k0 + BK < K) load_tile(k0 + BK);
        __syncthreads();

#pragma unroll 8
        for (int kk = 0; kk < BK; ++kk) {
            const float* as = &As[kk * LDA];
            const float* bs = &Bs[kk * BN];
            float4 af[RM], bf[RN];
#pragma unroll
            for (int i = 0; i < RM; ++i) af[i] = *(const float4*)(as + ar + 32 * i);
#pragma unroll
            for (int j = 0; j < RN; ++j) bf[j] = *(const float4*)(bs + bc + 32 * j);
#pragma unroll
            for (int i = 0; i < RM; ++i) {
                float ae[4] = {af[i].x, af[i].y, af[i].z, af[i].w};
#pragma unroll
                for (int r = 0; r < 4; ++r)
#pragma unroll
                    for (int j = 0; j < RN; ++j)
                        fma4(acc[i][j][r], ae[r], bf[j]);
            }
        }
    }

#pragma unroll
    for (int i = 0; i < RM; ++i)
#pragma unroll
        for (int r = 0; r < 4; ++r) {
            int gr = m0 + ar + 32 * i + r;
            if (gr >= M) continue;
#pragma unroll
            for (int j = 0; j < RN; ++j) {
                int gc = n0 + bc + 32 * j;
                float4 v = acc[i][j][r];
                if (gc + 3 < N) {
                    if (bias) {
                        v.x += bias[gc + 0];
                        v.y += bias[gc + 1];
                        v.z += bias[gc + 2];
                        v.w += bias[gc + 3];
                    }
                    *(float4*)(C + (size_t)gr * N + gc) = v;
                } else {
                    float vv[4] = {v.x, v.y, v.z, v.w};
#pragma unroll
                    for (int e = 0; e < 4; ++e)
                        if (gc + e < N)
                            C[(size_t)gr * N + gc + e] = vv[e] + (bias ? bias[gc + e] : 0.f);
                }
            }
        }
}

// ---------------- split-bf16 MFMA output GEMM ----------------
// C[M,N] = (Ahi+Alo)[M,64] @ (Bhi+Blo)^T-stored[N,64] + bias, dropping Alo*Blo.
// Block 128x128, 4 waves 2x2, wave 64x64 = 4x4 MFMA tiles of 16x16x32.
// LDS [row][64k] bf16 rows (128 B), XOR-swizzled (byte ^= (row&7)<<4) so both
// the staging writes and the 16-rows-per-lane-group fragment reads are
// conflict-free. Single K-phase (K=64): stage once, one barrier, 96 MFMA/wave.
// Fragment maps (guide §3): A row=l&15, k=(l>>4)*8+e; B col=l&15, same k;
// C/D col=lane&15, row=(lane>>4)*4+reg (m89-verified).

__launch_bounds__(256, 2)
__global__ void gemm_mfma_out(const unsigned short* __restrict__ Ahi,
                              const unsigned short* __restrict__ Alo,
                              const unsigned short* __restrict__ Bhi,
                              const unsigned short* __restrict__ Blo,
                              const float* __restrict__ bias, float* __restrict__ C,
                              int M, int N)
{
    __shared__ unsigned short Ah[128 * 64], Al[128 * 64];   // 16 KB each
    __shared__ unsigned short Bh[128 * 64], Bl[128 * 64];   // total 64 KB

    const int tid = threadIdx.x;
    const int m0 = blockIdx.x * 128;
    const int n0 = blockIdx.y * 128;

    // ---- stage: thread -> 16B chunk c of row r, rows r+32p ----
    const int c = tid & 7, r0 = tid >> 3;
#pragma unroll
    for (int p = 0; p < 4; ++p) {
        int row = r0 + p * 32;
        int swz = (c * 16) ^ ((row & 7) << 4);
        {
            int gr = m0 + row;
            uint4 v = make_uint4(0, 0, 0, 0), w = make_uint4(0, 0, 0, 0);
            if (gr < M) {
                v = *(const uint4*)(Ahi + (size_t)gr * 64 + c * 8);
                w = *(const uint4*)(Alo + (size_t)gr * 64 + c * 8);
            }
            *(uint4*)((char*)Ah + row * 128 + swz) = v;
            *(uint4*)((char*)Al + row * 128 + swz) = w;
        }
        {
            int gc = n0 + row;
            uint4 v = make_uint4(0, 0, 0, 0), w = make_uint4(0, 0, 0, 0);
            if (gc < N) {
                v = *(const uint4*)(Bhi + (size_t)gc * 64 + c * 8);
                w = *(const uint4*)(Blo + (size_t)gc * 64 + c * 8);
            }
            *(uint4*)((char*)Bh + row * 128 + swz) = v;
            *(uint4*)((char*)Bl + row * 128 + swz) = w;
        }
    }
    __syncthreads();

    const int lane = tid & 63, wave = tid >> 6;
    const int wr = wave >> 1, wc = wave & 1;
    const int lrow = lane & 15;
    const int kgrp = lane >> 4;

    f32x4 acc[4][4] = {};

#pragma unroll
    for (int ks = 0; ks < 2; ++ks) {
        const int cIdx = kgrp + ks * 4;            // 16B chunk within row
        bf16x8 ah[4], al[4], bh[4], bl[4];
#pragma unroll
        for (int i = 0; i < 4; ++i) {
            int row = wr * 64 + i * 16 + lrow;
            int off = row * 128 + ((cIdx * 16) ^ ((row & 7) << 4));
            ah[i] = *(const bf16x8*)((const char*)Ah + off);
            al[i] = *(const bf16x8*)((const char*)Al + off);
        }
#pragma unroll
        for (int j = 0; j < 4; ++j) {
            int col = wc * 64 + j * 16 + lrow;
            int off = col * 128 + ((cIdx * 16) ^ ((col & 7) << 4));
            bh[j] = *(const bf16x8*)((const char*)Bh + off);
            bl[j] = *(const bf16x8*)((const char*)Bl + off);
        }
#pragma unroll
        for (int i = 0; i < 4; ++i)
#pragma unroll
            for (int j = 0; j < 4; ++j) {
                acc[i][j] = __builtin_amdgcn_mfma_f32_16x16x32_bf16(ah[i], bh[j], acc[i][j], 0, 0, 0);
                acc[i][j] = __builtin_amdgcn_mfma_f32_16x16x32_bf16(ah[i], bl[j], acc[i][j], 0, 0, 0);
                acc[i][j] = __builtin_amdgcn_mfma_f32_16x16x32_bf16(al[i], bh[j], acc[i][j], 0, 0, 0);
            }
    }

    // ---- epilogue: C col=lane&15, row=(lane>>4)*4+r ----
#pragma unroll
    for (int j = 0; j < 4; ++j) {
        int gcol = n0 + wc * 64 + j * 16 + lrow;
        if (gcol >= N) continue;
        float bv = bias[gcol];
#pragma unroll
        for (int i = 0; i < 4; ++i) {
            int rbase = m0 + wr * 64 + i * 16 + kgrp * 4;
#pragma unroll
            for (int r = 0; r < 4; ++r) {
                int grow = rbase + r;
                if (grow < M) C[(size_t)grow * N + gcol] = acc[i][j][r] + bv;
            }
        }
    }
}

// ---------------- launch ----------------
// d_out (400 MB) doubles as scratch for everything dead before the final GEMM:
//   O0 h[N,128] | O1 h1[N,128] | O2 h2pre[N,64] | csr_src[E] | offs | cursor
//   | deg_cnt | bsums
// d_ws (<=26.7 MB used, same budget as evidenced passing):
//   dinv 0.5MB | Bt_hi 128KB | Bt_lo 128KB | h2hi 12.8MB | h2lo 12.8MB

extern "C" void kernel_launch(void* const* d_in, const int* in_sizes, int n_in,
                              void* d_out, int out_size, void* d_ws, size_t ws_size,
                              hipStream_t stream)
{
    const float* x   = (const float*)d_in[0];
    const float* W1  = (const float*)d_in[1];
    const float* b1  = (const float*)d_in[2];
    const float* W2  = (const float*)d_in[3];
    const float* b2  = (const float*)d_in[4];
    const float* Wfc = (const float*)d_in[5];
    const float* bfc = (const float*)d_in[6];
    const int*   ei  = (const int*)d_in[7];     // int32 in the harness

    const int Nn = in_sizes[0] / 128;      // 100000 nodes
    const int E  = in_sizes[7] / 2;        // 1600000 edges
    const int* src = ei;
    const int* dst = ei + E;

    char* ws = (char*)d_ws;
    float*          dinv  = (float*)(ws);
    unsigned short* Bt_hi = (unsigned short*)(ws + 512 * 1024);
    unsigned short* Bt_lo = (unsigned short*)(ws + 768 * 1024);
    unsigned short* h2hi  = (unsigned short*)(ws + 1024 * 1024);
    unsigned short* h2lo  = (unsigned short*)(ws + 1024 * 1024 + (size_t)Nn * 64 * 2);

    float* out = (float*)d_out;
    float* O0      = out;                              // h [Nn,128]
    float* O1      = out + (size_t)Nn * 128;           // h1 [Nn,128]
    float* O2      = out + (size_t)Nn * 256;           // h2pre [Nn,64]
    int*   csr_src = (int*)(out + (size_t)Nn * 320);   // E ints
    int*   offs    = (int*)((char*)csr_src + (size_t)E * 4);
    int*   cursor  = (int*)((char*)offs + (size_t)Nn * 4);
    int*   deg_cnt = (int*)((char*)cursor + (size_t)Nn * 4);
    int*   bsums   = (int*)((char*)deg_cnt + (size_t)Nn * 4);

    const int nScanBlocks = (Nn + SCAN_B - 1) / SCAN_B;

    // ---- degree, dinv, offsets, cursor, CSR, Wfc conversion ----
    k_zero_i<<<128, 256, 0, stream>>>(deg_cnt, Nn);
    k_deg_i<<<(E + 255) / 256, 256, 0, stream>>>(dst, deg_cnt, E);
    k_dinv<<<(Nn + 255) / 256, 256, 0, stream>>>(deg_cnt, dinv, Nn);
    k_scan1<<<nScanBlocks, SCAN_B, 0, stream>>>(deg_cnt, offs, bsums, Nn);
    k_scan2<<<1, 128, 0, stream>>>(bsums, nScanBlocks);
    k_scan3<<<nScanBlocks, SCAN_B, 0, stream>>>(offs, cursor, bsums, Nn);
    k_fill<<<(E + 255) / 256, 256, 0, stream>>>(src, dst, cursor, csr_src, E);
    k_conv_wfc<<<1000, 64, 0, stream>>>(Wfc, Bt_hi, Bt_lo, 64, 1000);

    // ---- layer 1 ----
    gemm_wt<2, 2, 32, 4, 2><<<dim3((Nn + 255) / 256, 1), 256, 0, stream>>>(
        x, W1, nullptr, O0, Nn, 128, 128);
    k_gather128<<<(Nn + 3) / 4, 256, 0, stream>>>(O0, csr_src, offs, dinv, b1, O1, Nn, E);

    // ---- layer 2 ----
    gemm_wt<2, 2, 32, 4, 1><<<dim3((Nn + 255) / 256, 1), 256, 0, stream>>>(
        O1, W2, nullptr, O2, Nn, 64, 128);
    k_gather64<<<(Nn + 3) / 4, 256, 0, stream>>>(O2, csr_src, offs, dinv, b2,
                                                 h2hi, h2lo, Nn, E);

    // ---- output layer: split-bf16 MFMA ----
    gemm_mfma_out<<<dim3((Nn + 127) / 128, (1000 + 127) / 128), 256, 0, stream>>>(
        h2hi, h2lo, Bt_hi, Bt_lo, bfc, out, Nn, 1000);
}

// Round 10
// 638.611 us; speedup vs baseline: 1.1795x; 1.0863x over previous
//
#include <hip/hip_runtime.h>
#include <hip/hip_bf16.h>
#include <cstddef>

typedef __attribute__((ext_vector_type(8))) short bf16x8;
typedef __attribute__((ext_vector_type(4))) float f32x4;

__device__ __forceinline__ unsigned short f2bf(float f) {
    __hip_bfloat16 h = __float2bfloat16(f);
    return __builtin_bit_cast(unsigned short, h);
}
__device__ __forceinline__ float bf2f(unsigned short u) {
    return __bfloat162float(__builtin_bit_cast(__hip_bfloat16, u));
}

// ---------------- zero fill ----------------

__global__ void k_zero_i(int* __restrict__ p, int total) {
    int i = blockIdx.x * blockDim.x + threadIdx.x;
    int stride = gridDim.x * blockDim.x;
    for (; i < total; i += stride) p[i] = 0;
}

// ---------------- degree / norm ----------------

__global__ void k_deg_i(const int* __restrict__ dst, int* __restrict__ deg, int E) {
    int e = blockIdx.x * blockDim.x + threadIdx.x;
    if (e < E) atomicAdd(&deg[dst[e]], 1);
}

__global__ void k_dinv(const int* __restrict__ deg, float* __restrict__ dinv, int N) {
    int i = blockIdx.x * blockDim.x + threadIdx.x;
    if (i < N) dinv[i] = rsqrtf((float)deg[i] + 1.0f);
}

// ---------------- exclusive scan ----------------

#define SCAN_B 1024

__global__ void k_scan1(const int* __restrict__ in, int* __restrict__ out,
                        int* __restrict__ sums, int n) {
    __shared__ int tmp[SCAN_B];
    int tid = threadIdx.x;
    int gid = blockIdx.x * SCAN_B + tid;
    int v = (gid < n) ? in[gid] : 0;
    tmp[tid] = v;
    __syncthreads();
    for (int off = 1; off < SCAN_B; off <<= 1) {
        int t = (tid >= off) ? tmp[tid - off] : 0;
        __syncthreads();
        tmp[tid] += t;
        __syncthreads();
    }
    if (gid < n) out[gid] = tmp[tid] - v;
    if (tid == SCAN_B - 1) sums[blockIdx.x] = tmp[tid];
}

__global__ void k_scan2(int* __restrict__ sums, int nb) {
    __shared__ int tmp[128];
    int tid = threadIdx.x;
    int v = (tid < nb) ? sums[tid] : 0;
    tmp[tid] = v;
    __syncthreads();
    for (int off = 1; off < 128; off <<= 1) {
        int t = (tid >= off) ? tmp[tid - off] : 0;
        __syncthreads();
        tmp[tid] += t;
        __syncthreads();
    }
    if (tid < nb) sums[tid] = tmp[tid] - v;
}

__global__ void k_scan3(int* __restrict__ out, int* __restrict__ cursor,
                        const int* __restrict__ sums, int n) {
    int gid = blockIdx.x * SCAN_B + threadIdx.x;
    if (gid < n) {
        int v = out[gid] + sums[blockIdx.x];
        out[gid] = v;
        cursor[gid] = v;
    }
}

// ---------------- CSR fill ----------------

__global__ void k_fill(const int* __restrict__ src, const int* __restrict__ dst,
                       int* __restrict__ cursor, int* __restrict__ csr_src, int E) {
    int e = blockIdx.x * blockDim.x + threadIdx.x;
    if (e < E) {
        int pos = atomicAdd(&cursor[dst[e]], 1);
        csr_src[pos] = src[e];
    }
}

// ---------------- W [K,N] fp32 -> transposed split-bf16 [n][K] ----------------

__global__ void k_conv_w(const float* __restrict__ W, unsigned short* __restrict__ Bh,
                         unsigned short* __restrict__ Bl, int K, int N)
{
    int n = blockIdx.x;
    int k = threadIdx.x;                 // blockDim = K
    float v = W[(size_t)k * N + n];
    unsigned short hi = f2bf(v);
    unsigned short lo = f2bf(v - bf2f(hi));
    Bh[(size_t)n * K + k] = hi;
    Bl[(size_t)n * K + k] = lo;
}

// ---------------- gather helpers ----------------

__device__ __forceinline__ float4 shfl_xor4(float4 v, int m) {
    return make_float4(__shfl_xor(v.x, m), __shfl_xor(v.y, m),
                       __shfl_xor(v.z, m), __shfl_xor(v.w, m));
}

__device__ __forceinline__ void fmaa4(float4& c, float w, const float4& v) {
    c.x = fmaf(w, v.x, c.x);
    c.y = fmaf(w, v.y, c.y);
    c.z = fmaf(w, v.z, c.z);
    c.w = fmaf(w, v.w, c.w);
}

// ---------------- gather F=128 -> split-bf16 hi/lo output ----------------
// h1 = relu(gather(h)+self+b1), written directly as hi/lo bf16 for the MFMA
// layer-2 GEMM. One wave/node, 2 edge-groups x 32 lanes, 4-unrolled (8 edges
// in flight — L3-latency-bound loop).

__launch_bounds__(256)
__global__ void k_gather128(const float* __restrict__ h, const int* __restrict__ csr_src,
                            const int* __restrict__ off, const float* __restrict__ dinv,
                            const float* __restrict__ bias,
                            unsigned short* __restrict__ ohi, unsigned short* __restrict__ olo,
                            int N, int E)
{
    int node = blockIdx.x * 4 + (threadIdx.x >> 6);
    int lane = threadIdx.x & 63;
    if (node >= N) return;
    float dn = dinv[node];
    int beg = off[node];
    int end = (node + 1 < N) ? off[node + 1] : E;

    const int grp = lane >> 5;
    const int sub = lane & 31;

    float4 acc = make_float4(0.f, 0.f, 0.f, 0.f);
    int i = beg + grp;
    for (; i + 6 < end; i += 8) {
        int s0 = csr_src[i];
        int s1 = csr_src[i + 2];
        int s2 = csr_src[i + 4];
        int s3 = csr_src[i + 6];
        float w0 = dinv[s0] * dn;
        float w1 = dinv[s1] * dn;
        float w2 = dinv[s2] * dn;
        float w3 = dinv[s3] * dn;
        float4 v0 = *(const float4*)(h + (size_t)s0 * 128 + sub * 4);
        float4 v1 = *(const float4*)(h + (size_t)s1 * 128 + sub * 4);
        float4 v2 = *(const float4*)(h + (size_t)s2 * 128 + sub * 4);
        float4 v3 = *(const float4*)(h + (size_t)s3 * 128 + sub * 4);
        fmaa4(acc, w0, v0);
        fmaa4(acc, w1, v1);
        fmaa4(acc, w2, v2);
        fmaa4(acc, w3, v3);
    }
    for (; i < end; i += 2) {
        int s = csr_src[i];
        float w = dinv[s] * dn;
        float4 v = *(const float4*)(h + (size_t)s * 128 + sub * 4);
        fmaa4(acc, w, v);
    }
    {
        float4 o = shfl_xor4(acc, 32);
        acc.x += o.x; acc.y += o.y; acc.z += o.z; acc.w += o.w;
    }
    if (grp == 0) {
        float4 hv = *(const float4*)(h + (size_t)node * 128 + sub * 4);
        float4 bv = *(const float4*)(bias + sub * 4);
        float w = dn * dn;
        float f0 = fmaxf(fmaf(hv.x, w, acc.x) + bv.x, 0.f);
        float f1 = fmaxf(fmaf(hv.y, w, acc.y) + bv.y, 0.f);
        float f2 = fmaxf(fmaf(hv.z, w, acc.z) + bv.z, 0.f);
        float f3 = fmaxf(fmaf(hv.w, w, acc.w) + bv.w, 0.f);
        ushort4 hi, lo;
        hi.x = f2bf(f0); lo.x = f2bf(f0 - bf2f(hi.x));
        hi.y = f2bf(f1); lo.y = f2bf(f1 - bf2f(hi.y));
        hi.z = f2bf(f2); lo.z = f2bf(f2 - bf2f(hi.z));
        hi.w = f2bf(f3); lo.w = f2bf(f3 - bf2f(hi.w));
        *(ushort4*)(ohi + (size_t)node * 128 + sub * 4) = hi;
        *(ushort4*)(olo + (size_t)node * 128 + sub * 4) = lo;
    }
}

// ---------------- gather F=64 -> split-bf16 hi/lo output ----------------

__launch_bounds__(256)
__global__ void k_gather64(const float* __restrict__ h, const int* __restrict__ csr_src,
                           const int* __restrict__ off, const float* __restrict__ dinv,
                           const float* __restrict__ bias,
                           unsigned short* __restrict__ hhi, unsigned short* __restrict__ hlo,
                           int N, int E)
{
    int node = blockIdx.x * 4 + (threadIdx.x >> 6);
    int lane = threadIdx.x & 63;
    if (node >= N) return;
    float dn = dinv[node];
    int beg = off[node];
    int end = (node + 1 < N) ? off[node + 1] : E;

    const int grp = lane >> 4;
    const int sub = lane & 15;

    float4 acc = make_float4(0.f, 0.f, 0.f, 0.f);
    int i = beg + grp;
    for (; i + 4 < end; i += 8) {
        int s0 = csr_src[i];
        int s1 = csr_src[i + 4];
        float w0 = dinv[s0] * dn;
        float w1 = dinv[s1] * dn;
        float4 v0 = *(const float4*)(h + (size_t)s0 * 64 + sub * 4);
        float4 v1 = *(const float4*)(h + (size_t)s1 * 64 + sub * 4);
        fmaa4(acc, w0, v0);
        fmaa4(acc, w1, v1);
    }
    if (i < end) {
        int s = csr_src[i];
        float w = dinv[s] * dn;
        float4 v = *(const float4*)(h + (size_t)s * 64 + sub * 4);
        fmaa4(acc, w, v);
    }
    acc = make_float4(acc.x + __shfl_xor(acc.x, 16),
                      acc.y + __shfl_xor(acc.y, 16),
                      acc.z + __shfl_xor(acc.z, 16),
                      acc.w + __shfl_xor(acc.w, 16));
    {
        float4 o = shfl_xor4(acc, 32);
        acc.x += o.x; acc.y += o.y; acc.z += o.z; acc.w += o.w;
    }
    if (grp == 0) {
        float4 hv = *(const float4*)(h + (size_t)node * 64 + sub * 4);
        float4 bv = *(const float4*)(bias + sub * 4);
        float w = dn * dn;
        float f0 = fmaxf(fmaf(hv.x, w, acc.x) + bv.x, 0.f);
        float f1 = fmaxf(fmaf(hv.y, w, acc.y) + bv.y, 0.f);
        float f2 = fmaxf(fmaf(hv.z, w, acc.z) + bv.z, 0.f);
        float f3 = fmaxf(fmaf(hv.w, w, acc.w) + bv.w, 0.f);
        ushort4 hi, lo;
        hi.x = f2bf(f0); lo.x = f2bf(f0 - bf2f(hi.x));
        hi.y = f2bf(f1); lo.y = f2bf(f1 - bf2f(hi.y));
        hi.z = f2bf(f2); lo.z = f2bf(f2 - bf2f(hi.z));
        hi.w = f2bf(f3); lo.w = f2bf(f3 - bf2f(hi.w));
        *(ushort4*)(hhi + (size_t)node * 64 + sub * 4) = hi;
        *(ushort4*)(hlo + (size_t)node * 64 + sub * 4) = lo;
    }
}

// ---------------- layer-1 MFMA GEMM: C[M,128] = x[M,128] @ W1 ----------------
// A fp32, converted to hi/lo bf16 during LDS staging. B pre-split [col][128k].
// Block 128x128, waves 2x2 (wave 64x64), K=128 in 2 phases of 64.
// LDS XOR-swizzle byte^=((row&7)<<4): staging writes and 16-row fragment
// reads both conflict-free (verified structure from R9's gemm_mfma_out).

__launch_bounds__(256, 2)
__global__ void gemm_mfma_l1(const float* __restrict__ A,
                             const unsigned short* __restrict__ Bth,
                             const unsigned short* __restrict__ Btl,
                             float* __restrict__ C, int M)
{
    __shared__ unsigned short Ah[128 * 64], Al[128 * 64];   // 16 KB each
    __shared__ unsigned short Bh[128 * 64], Bl[128 * 64];

    const int tid = threadIdx.x;
    const int m0 = blockIdx.x * 128;
    const int lane = tid & 63, wave = tid >> 6;
    const int wr = wave >> 1, wc = wave & 1;
    const int lrow = lane & 15, kgrp = lane >> 4;

    f32x4 acc[4][4] = {};

    for (int ph = 0; ph < 2; ++ph) {
        const int k0 = ph * 64;
        __syncthreads();
        // ---- stage A with fp32->hi/lo conversion ----
        {
            const int c4 = tid & 15, r0 = tid >> 4;
#pragma unroll
            for (int p = 0; p < 8; ++p) {
                int row = r0 + p * 16;
                int gr = m0 + row; if (gr >= M) gr = M - 1;
                float4 v = *(const float4*)(A + (size_t)gr * 128 + k0 + c4 * 4);
                ushort4 hi, lo;
                hi.x = f2bf(v.x); lo.x = f2bf(v.x - bf2f(hi.x));
                hi.y = f2bf(v.y); lo.y = f2bf(v.y - bf2f(hi.y));
                hi.z = f2bf(v.z); lo.z = f2bf(v.z - bf2f(hi.z));
                hi.w = f2bf(v.w); lo.w = f2bf(v.w - bf2f(hi.w));
                int off = row * 128 + ((c4 * 8) ^ ((row & 7) << 4));
                *(ushort4*)((char*)Ah + off) = hi;
                *(ushort4*)((char*)Al + off) = lo;
            }
        }
        // ---- stage B (direct copy of pre-split Wt) ----
        {
            const int c = tid & 7, col0 = tid >> 3;
#pragma unroll
            for (int p = 0; p < 4; ++p) {
                int col = col0 + p * 32;
                uint4 v = *(const uint4*)(Bth + (size_t)col * 128 + k0 + c * 8);
                uint4 w = *(const uint4*)(Btl + (size_t)col * 128 + k0 + c * 8);
                int off = col * 128 + ((c * 16) ^ ((col & 7) << 4));
                *(uint4*)((char*)Bh + off) = v;
                *(uint4*)((char*)Bl + off) = w;
            }
        }
        __syncthreads();

#pragma unroll
        for (int ks = 0; ks < 2; ++ks) {
            const int cIdx = kgrp + ks * 4;
            bf16x8 ah[4], al[4], bh[4], bl[4];
#pragma unroll
            for (int i = 0; i < 4; ++i) {
                int row = wr * 64 + i * 16 + lrow;
                int off = row * 128 + ((cIdx * 16) ^ ((row & 7) << 4));
                ah[i] = *(const bf16x8*)((const char*)Ah + off);
                al[i] = *(const bf16x8*)((const char*)Al + off);
            }
#pragma unroll
            for (int j = 0; j < 4; ++j) {
                int col = wc * 64 + j * 16 + lrow;
                int off = col * 128 + ((cIdx * 16) ^ ((col & 7) << 4));
                bh[j] = *(const bf16x8*)((const char*)Bh + off);
                bl[j] = *(const bf16x8*)((const char*)Bl + off);
            }
#pragma unroll
            for (int i = 0; i < 4; ++i)
#pragma unroll
                for (int j = 0; j < 4; ++j) {
                    acc[i][j] = __builtin_amdgcn_mfma_f32_16x16x32_bf16(ah[i], bh[j], acc[i][j], 0, 0, 0);
                    acc[i][j] = __builtin_amdgcn_mfma_f32_16x16x32_bf16(ah[i], bl[j], acc[i][j], 0, 0, 0);
                    acc[i][j] = __builtin_amdgcn_mfma_f32_16x16x32_bf16(al[i], bh[j], acc[i][j], 0, 0, 0);
                }
        }
    }

    // ---- epilogue: C col=lane&15, row=(lane>>4)*4+r ----
#pragma unroll
    for (int j = 0; j < 4; ++j) {
        int gcol = wc * 64 + j * 16 + lrow;
#pragma unroll
        for (int i = 0; i < 4; ++i) {
            int rbase = m0 + wr * 64 + i * 16 + kgrp * 4;
#pragma unroll
            for (int r = 0; r < 4; ++r) {
                int grow = rbase + r;
                if (grow < M) C[(size_t)grow * 128 + gcol] = acc[i][j][r];
            }
        }
    }
}

// ---------------- layer-2 MFMA GEMM: C[M,64] = h1[M,128] @ W2 ----------------
// A pre-split hi/lo bf16 (from k_gather128). Block 128x64, waves 2x2
// (wave 64x32), K=128 in 2 phases. LDS 48 KB -> 3 blocks/CU.

__launch_bounds__(256, 3)
__global__ void gemm_mfma_l2(const unsigned short* __restrict__ Ahi_g,
                             const unsigned short* __restrict__ Alo_g,
                             const unsigned short* __restrict__ Bth,
                             const unsigned short* __restrict__ Btl,
                             float* __restrict__ C, int M)
{
    __shared__ unsigned short Ah[128 * 64], Al[128 * 64];   // 16 KB each
    __shared__ unsigned short Bh[64 * 64],  Bl[64 * 64];    // 8 KB each

    const int tid = threadIdx.x;
    const int m0 = blockIdx.x * 128;
    const int lane = tid & 63, wave = tid >> 6;
    const int wr = wave >> 1, wc = wave & 1;
    const int lrow = lane & 15, kgrp = lane >> 4;

    f32x4 acc[4][2] = {};

    for (int ph = 0; ph < 2; ++ph) {
        const int k0 = ph * 64;
        __syncthreads();
        // ---- stage A (direct copy of pre-split h1) ----
        {
            const int c = tid & 7, r0 = tid >> 3;
#pragma unroll
            for (int p = 0; p < 4; ++p) {
                int row = r0 + p * 32;
                int gr = m0 + row; if (gr >= M) gr = M - 1;
                uint4 v = *(const uint4*)(Ahi_g + (size_t)gr * 128 + k0 + c * 8);
                uint4 w = *(const uint4*)(Alo_g + (size_t)gr * 128 + k0 + c * 8);
                int off = row * 128 + ((c * 16) ^ ((row & 7) << 4));
                *(uint4*)((char*)Ah + off) = v;
                *(uint4*)((char*)Al + off) = w;
            }
        }
        // ---- stage B ----
        {
            const int c = tid & 7, col0 = tid >> 3;
#pragma unroll
            for (int p = 0; p < 2; ++p) {
                int col = col0 + p * 32;
                uint4 v = *(const uint4*)(Bth + (size_t)col * 128 + k0 + c * 8);
                uint4 w = *(const uint4*)(Btl + (size_t)col * 128 + k0 + c * 8);
                int off = col * 128 + ((c * 16) ^ ((col & 7) << 4));
                *(uint4*)((char*)Bh + off) = v;
                *(uint4*)((char*)Bl + off) = w;
            }
        }
        __syncthreads();

#pragma unroll
        for (int ks = 0; ks < 2; ++ks) {
            const int cIdx = kgrp + ks * 4;
            bf16x8 ah[4], al[4], bh[2], bl[2];
#pragma unroll
            for (int i = 0; i < 4; ++i) {
                int row = wr * 64 + i * 16 + lrow;
                int off = row * 128 + ((cIdx * 16) ^ ((row & 7) << 4));
                ah[i] = *(const bf16x8*)((const char*)Ah + off);
                al[i] = *(const bf16x8*)((const char*)Al + off);
            }
#pragma unroll
            for (int j = 0; j < 2; ++j) {
                int col = wc * 32 + j * 16 + lrow;
                int off = col * 128 + ((cIdx * 16) ^ ((col & 7) << 4));
                bh[j] = *(const bf16x8*)((const char*)Bh + off);
                bl[j] = *(const bf16x8*)((const char*)Bl + off);
            }
#pragma unroll
            for (int i = 0; i < 4; ++i)
#pragma unroll
                for (int j = 0; j < 2; ++j) {
                    acc[i][j] = __builtin_amdgcn_mfma_f32_16x16x32_bf16(ah[i], bh[j], acc[i][j], 0, 0, 0);
                    acc[i][j] = __builtin_amdgcn_mfma_f32_16x16x32_bf16(ah[i], bl[j], acc[i][j], 0, 0, 0);
                    acc[i][j] = __builtin_amdgcn_mfma_f32_16x16x32_bf16(al[i], bh[j], acc[i][j], 0, 0, 0);
                }
        }
    }

#pragma unroll
    for (int j = 0; j < 2; ++j) {
        int gcol = wc * 32 + j * 16 + lrow;
#pragma unroll
        for (int i = 0; i < 4; ++i) {
            int rbase = m0 + wr * 64 + i * 16 + kgrp * 4;
#pragma unroll
            for (int r = 0; r < 4; ++r) {
                int grow = rbase + r;
                if (grow < M) C[(size_t)grow * 64 + gcol] = acc[i][j][r];
            }
        }
    }
}

// ---------------- output MFMA GEMM, no LDS ----------------
// C[M,1000] = (Ahi+Alo)[M,64] @ Bt[N,64] + bias, dropping Alo*Blo.
// Fragments load DIRECT from global (16B/lane, 16-row x 64B segments,
// L2/L3-served; A re-reads across col-blocks are L3-absorbed). No barrier,
// no LDS -> waves fully independent; removes R8/R9's stage-barrier stall.
// Block 128x128 = 4 waves 2x2, wave 64x64.

__launch_bounds__(256, 2)
__global__ void gemm_mfma_out(const unsigned short* __restrict__ Ahi,
                              const unsigned short* __restrict__ Alo,
                              const unsigned short* __restrict__ Bhi,
                              const unsigned short* __restrict__ Blo,
                              const float* __restrict__ bias, float* __restrict__ C,
                              int M, int N)
{
    const int tid = threadIdx.x;
    const int lane = tid & 63, wave = tid >> 6;
    const int wr = wave >> 1, wc = wave & 1;
    const int m0 = blockIdx.x * 128 + wr * 64;
    const int n0 = blockIdx.y * 128 + wc * 64;
    const int lrow = lane & 15, kgrp = lane >> 4;

    f32x4 acc[4][4] = {};

#pragma unroll
    for (int ks = 0; ks < 2; ++ks) {
        const int koff = (kgrp + ks * 4) * 8;      // element offset within 64-k row
        bf16x8 ah[4], al[4], bh[4], bl[4];
#pragma unroll
        for (int i = 0; i < 4; ++i) {
            int row = m0 + i * 16 + lrow; if (row >= M) row = M - 1;
            ah[i] = *(const bf16x8*)(Ahi + (size_t)row * 64 + koff);
            al[i] = *(const bf16x8*)(Alo + (size_t)row * 64 + koff);
        }
#pragma unroll
        for (int j = 0; j < 4; ++j) {
            int col = n0 + j * 16 + lrow; if (col >= N) col = N - 1;
            bh[j] = *(const bf16x8*)(Bhi + (size_t)col * 64 + koff);
            bl[j] = *(const bf16x8*)(Blo + (size_t)col * 64 + koff);
        }
#pragma unroll
        for (int i = 0; i < 4; ++i)
#pragma unroll
            for (int j = 0; j < 4; ++j) {
                acc[i][j] = __builtin_amdgcn_mfma_f32_16x16x32_bf16(ah[i], bh[j], acc[i][j], 0, 0, 0);
                acc[i][j] = __builtin_amdgcn_mfma_f32_16x16x32_bf16(ah[i], bl[j], acc[i][j], 0, 0, 0);
                acc[i][j] = __builtin_amdgcn_mfma_f32_16x16x32_bf16(al[i], bh[j], acc[i][j], 0, 0, 0);
            }
    }

#pragma unroll
    for (int j = 0; j < 4; ++j) {
        int gcol = n0 + j * 16 + lrow;
        if (gcol >= N) continue;
        float bv = bias[gcol];
#pragma unroll
        for (int i = 0; i < 4; ++i) {
            int rbase = m0 + i * 16 + kgrp * 4;
#pragma unroll
            for (int r = 0; r < 4; ++r) {
                int grow = rbase + r;
                if (grow < M) C[(size_t)grow * N + gcol] = acc[i][j][r] + bv;
            }
        }
    }
}

// ---------------- launch ----------------
// d_out (400 MB) doubles as scratch (all dead before the final GEMM):
//   O0 h[N,128] fp32 | h1hi[N,128] bf16 | h1lo[N,128] bf16 | O2 h2pre[N,64]
//   | csr_src[E] | offs | cursor | deg_cnt | bsums
// d_ws (~27 MB): dinv | WfcT hi/lo | W1T hi/lo | W2T hi/lo | h2hi | h2lo
// (h2 must survive the final GEMM's d_out writes.)

extern "C" void kernel_launch(void* const* d_in, const int* in_sizes, int n_in,
                              void* d_out, int out_size, void* d_ws, size_t ws_size,
                              hipStream_t stream)
{
    const float* x   = (const float*)d_in[0];
    const float* W1  = (const float*)d_in[1];
    const float* b1  = (const float*)d_in[2];
    const float* W2  = (const float*)d_in[3];
    const float* b2  = (const float*)d_in[4];
    const float* Wfc = (const float*)d_in[5];
    const float* bfc = (const float*)d_in[6];
    const int*   ei  = (const int*)d_in[7];     // int32 in the harness

    const int Nn = in_sizes[0] / 128;      // 100000 nodes
    const int E  = in_sizes[7] / 2;        // 1600000 edges
    const int* src = ei;
    const int* dst = ei + E;

    char* ws = (char*)d_ws;
    float*          dinv   = (float*)(ws);
    unsigned short* Wfc_hi = (unsigned short*)(ws + 512 * 1024);
    unsigned short* Wfc_lo = (unsigned short*)(ws + 768 * 1024);
    unsigned short* W1_hi  = (unsigned short*)(ws + 1024 * 1024);
    unsigned short* W1_lo  = (unsigned short*)(ws + 1088 * 1024);
    unsigned short* W2_hi  = (unsigned short*)(ws + 1152 * 1024);
    unsigned short* W2_lo  = (unsigned short*)(ws + 1216 * 1024);
    unsigned short* h2hi   = (unsigned short*)(ws + 1280 * 1024);
    unsigned short* h2lo   = (unsigned short*)(ws + 1280 * 1024 + (size_t)Nn * 64 * 2);

    float* out = (float*)d_out;
    float*          O0      = out;                                   // h [Nn,128] fp32
    unsigned short* h1hi    = (unsigned short*)(out + (size_t)Nn * 128);
    unsigned short* h1lo    = (unsigned short*)(out + (size_t)Nn * 192);
    float*          O2      = out + (size_t)Nn * 256;                // h2pre [Nn,64]
    int*            csr_src = (int*)(out + (size_t)Nn * 320);        // E ints
    int*            offs    = (int*)((char*)csr_src + (size_t)E * 4);
    int*            cursor  = (int*)((char*)offs + (size_t)Nn * 4);
    int*            deg_cnt = (int*)((char*)cursor + (size_t)Nn * 4);
    int*            bsums   = (int*)((char*)deg_cnt + (size_t)Nn * 4);

    const int nScanBlocks = (Nn + SCAN_B - 1) / SCAN_B;

    // ---- setup: degree, dinv, CSR, weight conversion ----
    k_zero_i<<<128, 256, 0, stream>>>(deg_cnt, Nn);
    k_deg_i<<<(E + 255) / 256, 256, 0, stream>>>(dst, deg_cnt, E);
    k_dinv<<<(Nn + 255) / 256, 256, 0, stream>>>(deg_cnt, dinv, Nn);
    k_scan1<<<nScanBlocks, SCAN_B, 0, stream>>>(deg_cnt, offs, bsums, Nn);
    k_scan2<<<1, 128, 0, stream>>>(bsums, nScanBlocks);
    k_scan3<<<nScanBlocks, SCAN_B, 0, stream>>>(offs, cursor, bsums, Nn);
    k_fill<<<(E + 255) / 256, 256, 0, stream>>>(src, dst, cursor, csr_src, E);
    k_conv_w<<<128, 128, 0, stream>>>(W1, W1_hi, W1_lo, 128, 128);
    k_conv_w<<<64, 128, 0, stream>>>(W2, W2_hi, W2_lo, 128, 64);
    k_conv_w<<<1000, 64, 0, stream>>>(Wfc, Wfc_hi, Wfc_lo, 64, 1000);

    // ---- layer 1: h = x @ W1 (MFMA, fp32->split staging) ----
    gemm_mfma_l1<<<dim3((Nn + 127) / 128, 1), 256, 0, stream>>>(x, W1_hi, W1_lo, O0, Nn);
    // h1 = relu(gather(h)+self+b1) -> split hi/lo
    k_gather128<<<(Nn + 3) / 4, 256, 0, stream>>>(O0, csr_src, offs, dinv, b1,
                                                  h1hi, h1lo, Nn, E);

    // ---- layer 2: h2pre = h1 @ W2 (MFMA, pre-split A) ----
    gemm_mfma_l2<<<dim3((Nn + 127) / 128, 1), 256, 0, stream>>>(h1hi, h1lo, W2_hi, W2_lo, O2, Nn);
    // h2 = relu(gather(h2pre)+self+b2) -> split hi/lo (ws)
    k_gather64<<<(Nn + 3) / 4, 256, 0, stream>>>(O2, csr_src, offs, dinv, b2,
                                                 h2hi, h2lo, Nn, E);

    // ---- output layer: out = h2 @ Wfc + bfc (MFMA, no LDS) ----
    gemm_mfma_out<<<dim3((Nn + 127) / 128, (1000 + 127) / 128), 256, 0, stream>>>(
        h2hi, h2lo, Wfc_hi, Wfc_lo, bfc, out, Nn, 1000);
}

// Round 11
// 605.982 us; speedup vs baseline: 1.2430x; 1.0538x over previous
//
#include <hip/hip_runtime.h>
#include <hip/hip_bf16.h>
#include <cstddef>

typedef __attribute__((ext_vector_type(8))) short bf16x8;
typedef __attribute__((ext_vector_type(4))) float f32x4;

__device__ __forceinline__ unsigned short f2bf(float f) {
    __hip_bfloat16 h = __float2bfloat16(f);
    return __builtin_bit_cast(unsigned short, h);
}
__device__ __forceinline__ float bf2f(unsigned short u) {
    return __bfloat162float(__builtin_bit_cast(__hip_bfloat16, u));
}

// ---------------- zero fill ----------------

__global__ void k_zero_i(int* __restrict__ p, int total) {
    int i = blockIdx.x * blockDim.x + threadIdx.x;
    int stride = gridDim.x * blockDim.x;
    for (; i < total; i += stride) p[i] = 0;
}

// ---------------- degree / norm ----------------

__global__ void k_deg_i(const int* __restrict__ dst, int* __restrict__ deg, int E) {
    int e = blockIdx.x * blockDim.x + threadIdx.x;
    if (e < E) atomicAdd(&deg[dst[e]], 1);
}

__global__ void k_dinv(const int* __restrict__ deg, float* __restrict__ dinv, int N) {
    int i = blockIdx.x * blockDim.x + threadIdx.x;
    if (i < N) dinv[i] = rsqrtf((float)deg[i] + 1.0f);
}

// ---------------- exclusive scan ----------------

#define SCAN_B 1024

__global__ void k_scan1(const int* __restrict__ in, int* __restrict__ out,
                        int* __restrict__ sums, int n) {
    __shared__ int tmp[SCAN_B];
    int tid = threadIdx.x;
    int gid = blockIdx.x * SCAN_B + tid;
    int v = (gid < n) ? in[gid] : 0;
    tmp[tid] = v;
    __syncthreads();
    for (int off = 1; off < SCAN_B; off <<= 1) {
        int t = (tid >= off) ? tmp[tid - off] : 0;
        __syncthreads();
        tmp[tid] += t;
        __syncthreads();
    }
    if (gid < n) out[gid] = tmp[tid] - v;
    if (tid == SCAN_B - 1) sums[blockIdx.x] = tmp[tid];
}

__global__ void k_scan2(int* __restrict__ sums, int nb) {
    __shared__ int tmp[128];
    int tid = threadIdx.x;
    int v = (tid < nb) ? sums[tid] : 0;
    tmp[tid] = v;
    __syncthreads();
    for (int off = 1; off < 128; off <<= 1) {
        int t = (tid >= off) ? tmp[tid - off] : 0;
        __syncthreads();
        tmp[tid] += t;
        __syncthreads();
    }
    if (tid < nb) sums[tid] = tmp[tid] - v;
}

__global__ void k_scan3(int* __restrict__ out, int* __restrict__ cursor,
                        const int* __restrict__ sums, int n) {
    int gid = blockIdx.x * SCAN_B + threadIdx.x;
    if (gid < n) {
        int v = out[gid] + sums[blockIdx.x];
        out[gid] = v;
        cursor[gid] = v;
    }
}

// ---------------- CSR fill ----------------

__global__ void k_fill(const int* __restrict__ src, const int* __restrict__ dst,
                       int* __restrict__ cursor, int* __restrict__ csr_src, int E) {
    int e = blockIdx.x * blockDim.x + threadIdx.x;
    if (e < E) {
        int pos = atomicAdd(&cursor[dst[e]], 1);
        csr_src[pos] = src[e];
    }
}

// ---------------- W [K,N] fp32 -> transposed split-bf16 [n][K] ----------------

__global__ void k_conv_w(const float* __restrict__ W, unsigned short* __restrict__ Bh,
                         unsigned short* __restrict__ Bl, int K, int N)
{
    int n = blockIdx.x;
    int k = threadIdx.x;                 // blockDim = K
    float v = W[(size_t)k * N + n];
    unsigned short hi = f2bf(v);
    unsigned short lo = f2bf(v - bf2f(hi));
    Bh[(size_t)n * K + k] = hi;
    Bl[(size_t)n * K + k] = lo;
}

// ---------------- gather helpers ----------------

__device__ __forceinline__ float4 shfl_xor4(float4 v, int m) {
    return make_float4(__shfl_xor(v.x, m), __shfl_xor(v.y, m),
                       __shfl_xor(v.z, m), __shfl_xor(v.w, m));
}

__device__ __forceinline__ void fmaa4(float4& c, float w, const float4& v) {
    c.x = fmaf(w, v.x, c.x);
    c.y = fmaf(w, v.y, c.y);
    c.z = fmaf(w, v.z, c.z);
    c.w = fmaf(w, v.w, c.w);
}

// ---------------- gather F=128 -> split-bf16 hi/lo output ----------------

__launch_bounds__(256)
__global__ void k_gather128(const float* __restrict__ h, const int* __restrict__ csr_src,
                            const int* __restrict__ off, const float* __restrict__ dinv,
                            const float* __restrict__ bias,
                            unsigned short* __restrict__ ohi, unsigned short* __restrict__ olo,
                            int N, int E)
{
    int node = blockIdx.x * 4 + (threadIdx.x >> 6);
    int lane = threadIdx.x & 63;
    if (node >= N) return;
    float dn = dinv[node];
    int beg = off[node];
    int end = (node + 1 < N) ? off[node + 1] : E;

    const int grp = lane >> 5;
    const int sub = lane & 31;

    float4 acc = make_float4(0.f, 0.f, 0.f, 0.f);
    int i = beg + grp;
    for (; i + 6 < end; i += 8) {
        int s0 = csr_src[i];
        int s1 = csr_src[i + 2];
        int s2 = csr_src[i + 4];
        int s3 = csr_src[i + 6];
        float w0 = dinv[s0] * dn;
        float w1 = dinv[s1] * dn;
        float w2 = dinv[s2] * dn;
        float w3 = dinv[s3] * dn;
        float4 v0 = *(const float4*)(h + (size_t)s0 * 128 + sub * 4);
        float4 v1 = *(const float4*)(h + (size_t)s1 * 128 + sub * 4);
        float4 v2 = *(const float4*)(h + (size_t)s2 * 128 + sub * 4);
        float4 v3 = *(const float4*)(h + (size_t)s3 * 128 + sub * 4);
        fmaa4(acc, w0, v0);
        fmaa4(acc, w1, v1);
        fmaa4(acc, w2, v2);
        fmaa4(acc, w3, v3);
    }
    for (; i < end; i += 2) {
        int s = csr_src[i];
        float w = dinv[s] * dn;
        float4 v = *(const float4*)(h + (size_t)s * 128 + sub * 4);
        fmaa4(acc, w, v);
    }
    {
        float4 o = shfl_xor4(acc, 32);
        acc.x += o.x; acc.y += o.y; acc.z += o.z; acc.w += o.w;
    }
    if (grp == 0) {
        float4 hv = *(const float4*)(h + (size_t)node * 128 + sub * 4);
        float4 bv = *(const float4*)(bias + sub * 4);
        float w = dn * dn;
        float f0 = fmaxf(fmaf(hv.x, w, acc.x) + bv.x, 0.f);
        float f1 = fmaxf(fmaf(hv.y, w, acc.y) + bv.y, 0.f);
        float f2 = fmaxf(fmaf(hv.z, w, acc.z) + bv.z, 0.f);
        float f3 = fmaxf(fmaf(hv.w, w, acc.w) + bv.w, 0.f);
        ushort4 hi, lo;
        hi.x = f2bf(f0); lo.x = f2bf(f0 - bf2f(hi.x));
        hi.y = f2bf(f1); lo.y = f2bf(f1 - bf2f(hi.y));
        hi.z = f2bf(f2); lo.z = f2bf(f2 - bf2f(hi.z));
        hi.w = f2bf(f3); lo.w = f2bf(f3 - bf2f(hi.w));
        *(ushort4*)(ohi + (size_t)node * 128 + sub * 4) = hi;
        *(ushort4*)(olo + (size_t)node * 128 + sub * 4) = lo;
    }
}

// ---------------- gather F=64 -> split-bf16 hi/lo output ----------------

__launch_bounds__(256)
__global__ void k_gather64(const float* __restrict__ h, const int* __restrict__ csr_src,
                           const int* __restrict__ off, const float* __restrict__ dinv,
                           const float* __restrict__ bias,
                           unsigned short* __restrict__ hhi, unsigned short* __restrict__ hlo,
                           int N, int E)
{
    int node = blockIdx.x * 4 + (threadIdx.x >> 6);
    int lane = threadIdx.x & 63;
    if (node >= N) return;
    float dn = dinv[node];
    int beg = off[node];
    int end = (node + 1 < N) ? off[node + 1] : E;

    const int grp = lane >> 4;
    const int sub = lane & 15;

    float4 acc = make_float4(0.f, 0.f, 0.f, 0.f);
    int i = beg + grp;
    for (; i + 4 < end; i += 8) {
        int s0 = csr_src[i];
        int s1 = csr_src[i + 4];
        float w0 = dinv[s0] * dn;
        float w1 = dinv[s1] * dn;
        float4 v0 = *(const float4*)(h + (size_t)s0 * 64 + sub * 4);
        float4 v1 = *(const float4*)(h + (size_t)s1 * 64 + sub * 4);
        fmaa4(acc, w0, v0);
        fmaa4(acc, w1, v1);
    }
    if (i < end) {
        int s = csr_src[i];
        float w = dinv[s] * dn;
        float4 v = *(const float4*)(h + (size_t)s * 64 + sub * 4);
        fmaa4(acc, w, v);
    }
    acc = make_float4(acc.x + __shfl_xor(acc.x, 16),
                      acc.y + __shfl_xor(acc.y, 16),
                      acc.z + __shfl_xor(acc.z, 16),
                      acc.w + __shfl_xor(acc.w, 16));
    {
        float4 o = shfl_xor4(acc, 32);
        acc.x += o.x; acc.y += o.y; acc.z += o.z; acc.w += o.w;
    }
    if (grp == 0) {
        float4 hv = *(const float4*)(h + (size_t)node * 64 + sub * 4);
        float4 bv = *(const float4*)(bias + sub * 4);
        float w = dn * dn;
        float f0 = fmaxf(fmaf(hv.x, w, acc.x) + bv.x, 0.f);
        float f1 = fmaxf(fmaf(hv.y, w, acc.y) + bv.y, 0.f);
        float f2 = fmaxf(fmaf(hv.z, w, acc.z) + bv.z, 0.f);
        float f3 = fmaxf(fmaf(hv.w, w, acc.w) + bv.w, 0.f);
        ushort4 hi, lo;
        hi.x = f2bf(f0); lo.x = f2bf(f0 - bf2f(hi.x));
        hi.y = f2bf(f1); lo.y = f2bf(f1 - bf2f(hi.y));
        hi.z = f2bf(f2); lo.z = f2bf(f2 - bf2f(hi.z));
        hi.w = f2bf(f3); lo.w = f2bf(f3 - bf2f(hi.w));
        *(ushort4*)(hhi + (size_t)node * 64 + sub * 4) = hi;
        *(ushort4*)(hlo + (size_t)node * 64 + sub * 4) = lo;
    }
}

// ---------------- layer-1 MFMA GEMM: C[M,128] = x[M,128] @ W1 ----------------
// OPERAND-SWAPPED mfma(b,a): D = C^T fragment -> lane holds one C row x 4
// consecutive cols -> float4 stores (R10 epilogue was scalar-store-issue-bound).

__launch_bounds__(256, 2)
__global__ void gemm_mfma_l1(const float* __restrict__ A,
                             const unsigned short* __restrict__ Bth,
                             const unsigned short* __restrict__ Btl,
                             float* __restrict__ C, int M)
{
    __shared__ unsigned short Ah[128 * 64], Al[128 * 64];   // 16 KB each
    __shared__ unsigned short Bh[128 * 64], Bl[128 * 64];

    const int tid = threadIdx.x;
    const int m0 = blockIdx.x * 128;
    const int lane = tid & 63, wave = tid >> 6;
    const int wr = wave >> 1, wc = wave & 1;
    const int lrow = lane & 15, kgrp = lane >> 4;

    f32x4 acc[4][4] = {};

    for (int ph = 0; ph < 2; ++ph) {
        const int k0 = ph * 64;
        __syncthreads();
        // ---- stage A with fp32->hi/lo conversion ----
        {
            const int c4 = tid & 15, r0 = tid >> 4;
#pragma unroll
            for (int p = 0; p < 8; ++p) {
                int row = r0 + p * 16;
                int gr = m0 + row; if (gr >= M) gr = M - 1;
                float4 v = *(const float4*)(A + (size_t)gr * 128 + k0 + c4 * 4);
                ushort4 hi, lo;
                hi.x = f2bf(v.x); lo.x = f2bf(v.x - bf2f(hi.x));
                hi.y = f2bf(v.y); lo.y = f2bf(v.y - bf2f(hi.y));
                hi.z = f2bf(v.z); lo.z = f2bf(v.z - bf2f(hi.z));
                hi.w = f2bf(v.w); lo.w = f2bf(v.w - bf2f(hi.w));
                int off = row * 128 + ((c4 * 8) ^ ((row & 7) << 4));
                *(ushort4*)((char*)Ah + off) = hi;
                *(ushort4*)((char*)Al + off) = lo;
            }
        }
        // ---- stage B (direct copy of pre-split Wt) ----
        {
            const int c = tid & 7, col0 = tid >> 3;
#pragma unroll
            for (int p = 0; p < 4; ++p) {
                int col = col0 + p * 32;
                uint4 v = *(const uint4*)(Bth + (size_t)col * 128 + k0 + c * 8);
                uint4 w = *(const uint4*)(Btl + (size_t)col * 128 + k0 + c * 8);
                int off = col * 128 + ((c * 16) ^ ((col & 7) << 4));
                *(uint4*)((char*)Bh + off) = v;
                *(uint4*)((char*)Bl + off) = w;
            }
        }
        __syncthreads();

#pragma unroll
        for (int ks = 0; ks < 2; ++ks) {
            const int cIdx = kgrp + ks * 4;
            bf16x8 ah[4], al[4], bh[4], bl[4];
#pragma unroll
            for (int i = 0; i < 4; ++i) {
                int row = wr * 64 + i * 16 + lrow;
                int off = row * 128 + ((cIdx * 16) ^ ((row & 7) << 4));
                ah[i] = *(const bf16x8*)((const char*)Ah + off);
                al[i] = *(const bf16x8*)((const char*)Al + off);
            }
#pragma unroll
            for (int j = 0; j < 4; ++j) {
                int col = wc * 64 + j * 16 + lrow;
                int off = col * 128 + ((cIdx * 16) ^ ((col & 7) << 4));
                bh[j] = *(const bf16x8*)((const char*)Bh + off);
                bl[j] = *(const bf16x8*)((const char*)Bl + off);
            }
#pragma unroll
            for (int i = 0; i < 4; ++i)
#pragma unroll
                for (int j = 0; j < 4; ++j) {
                    acc[i][j] = __builtin_amdgcn_mfma_f32_16x16x32_bf16(bh[j], ah[i], acc[i][j], 0, 0, 0);
                    acc[i][j] = __builtin_amdgcn_mfma_f32_16x16x32_bf16(bl[j], ah[i], acc[i][j], 0, 0, 0);
                    acc[i][j] = __builtin_amdgcn_mfma_f32_16x16x32_bf16(bh[j], al[i], acc[i][j], 0, 0, 0);
                }
        }
    }

    // ---- epilogue (transposed frag): row = m-blk + lrow, cols = n-blk + kgrp*4 ----
#pragma unroll
    for (int i = 0; i < 4; ++i) {
        int grow = m0 + wr * 64 + i * 16 + lrow;
        if (grow >= M) continue;
        float* crow = C + (size_t)grow * 128;
#pragma unroll
        for (int j = 0; j < 4; ++j) {
            int gc = wc * 64 + j * 16 + kgrp * 4;
            *(float4*)(crow + gc) = make_float4(acc[i][j][0], acc[i][j][1],
                                                acc[i][j][2], acc[i][j][3]);
        }
    }
}

// ---------------- layer-2 MFMA GEMM: C[M,64] = h1[M,128] @ W2 ----------------

__launch_bounds__(256, 3)
__global__ void gemm_mfma_l2(const unsigned short* __restrict__ Ahi_g,
                             const unsigned short* __restrict__ Alo_g,
                             const unsigned short* __restrict__ Bth,
                             const unsigned short* __restrict__ Btl,
                             float* __restrict__ C, int M)
{
    __shared__ unsigned short Ah[128 * 64], Al[128 * 64];   // 16 KB each
    __shared__ unsigned short Bh[64 * 64],  Bl[64 * 64];    // 8 KB each

    const int tid = threadIdx.x;
    const int m0 = blockIdx.x * 128;
    const int lane = tid & 63, wave = tid >> 6;
    const int wr = wave >> 1, wc = wave & 1;
    const int lrow = lane & 15, kgrp = lane >> 4;

    f32x4 acc[4][2] = {};

    for (int ph = 0; ph < 2; ++ph) {
        const int k0 = ph * 64;
        __syncthreads();
        // ---- stage A (direct copy of pre-split h1) ----
        {
            const int c = tid & 7, r0 = tid >> 3;
#pragma unroll
            for (int p = 0; p < 4; ++p) {
                int row = r0 + p * 32;
                int gr = m0 + row; if (gr >= M) gr = M - 1;
                uint4 v = *(const uint4*)(Ahi_g + (size_t)gr * 128 + k0 + c * 8);
                uint4 w = *(const uint4*)(Alo_g + (size_t)gr * 128 + k0 + c * 8);
                int off = row * 128 + ((c * 16) ^ ((row & 7) << 4));
                *(uint4*)((char*)Ah + off) = v;
                *(uint4*)((char*)Al + off) = w;
            }
        }
        // ---- stage B ----
        {
            const int c = tid & 7, col0 = tid >> 3;
#pragma unroll
            for (int p = 0; p < 2; ++p) {
                int col = col0 + p * 32;
                uint4 v = *(const uint4*)(Bth + (size_t)col * 128 + k0 + c * 8);
                uint4 w = *(const uint4*)(Btl + (size_t)col * 128 + k0 + c * 8);
                int off = col * 128 + ((c * 16) ^ ((col & 7) << 4));
                *(uint4*)((char*)Bh + off) = v;
                *(uint4*)((char*)Bl + off) = w;
            }
        }
        __syncthreads();

#pragma unroll
        for (int ks = 0; ks < 2; ++ks) {
            const int cIdx = kgrp + ks * 4;
            bf16x8 ah[4], al[4], bh[2], bl[2];
#pragma unroll
            for (int i = 0; i < 4; ++i) {
                int row = wr * 64 + i * 16 + lrow;
                int off = row * 128 + ((cIdx * 16) ^ ((row & 7) << 4));
                ah[i] = *(const bf16x8*)((const char*)Ah + off);
                al[i] = *(const bf16x8*)((const char*)Al + off);
            }
#pragma unroll
            for (int j = 0; j < 2; ++j) {
                int col = wc * 32 + j * 16 + lrow;
                int off = col * 128 + ((cIdx * 16) ^ ((col & 7) << 4));
                bh[j] = *(const bf16x8*)((const char*)Bh + off);
                bl[j] = *(const bf16x8*)((const char*)Bl + off);
            }
#pragma unroll
            for (int i = 0; i < 4; ++i)
#pragma unroll
                for (int j = 0; j < 2; ++j) {
                    acc[i][j] = __builtin_amdgcn_mfma_f32_16x16x32_bf16(bh[j], ah[i], acc[i][j], 0, 0, 0);
                    acc[i][j] = __builtin_amdgcn_mfma_f32_16x16x32_bf16(bl[j], ah[i], acc[i][j], 0, 0, 0);
                    acc[i][j] = __builtin_amdgcn_mfma_f32_16x16x32_bf16(bh[j], al[i], acc[i][j], 0, 0, 0);
                }
        }
    }

#pragma unroll
    for (int i = 0; i < 4; ++i) {
        int grow = m0 + wr * 64 + i * 16 + lrow;
        if (grow >= M) continue;
        float* crow = C + (size_t)grow * 64;
#pragma unroll
        for (int j = 0; j < 2; ++j) {
            int gc = wc * 32 + j * 16 + kgrp * 4;
            *(float4*)(crow + gc) = make_float4(acc[i][j][0], acc[i][j][1],
                                                acc[i][j][2], acc[i][j][3]);
        }
    }
}

// ---------------- output MFMA GEMM, no LDS, swapped operands ----------------
// C[M,1000] = (Ahi+Alo)[M,64] @ Bt[N,64] + bias, dropping Alo*Blo.
// Fragments direct from global; no barrier. Transposed-fragment epilogue:
// float4 stores (N=1000 is 4-aligned: a 4-col group is all-in or all-out).

__launch_bounds__(256, 2)
__global__ void gemm_mfma_out(const unsigned short* __restrict__ Ahi,
                              const unsigned short* __restrict__ Alo,
                              const unsigned short* __restrict__ Bhi,
                              const unsigned short* __restrict__ Blo,
                              const float* __restrict__ bias, float* __restrict__ C,
                              int M, int N)
{
    const int tid = threadIdx.x;
    const int lane = tid & 63, wave = tid >> 6;
    const int wr = wave >> 1, wc = wave & 1;
    const int m0 = blockIdx.x * 128 + wr * 64;
    const int n0 = blockIdx.y * 128 + wc * 64;
    const int lrow = lane & 15, kgrp = lane >> 4;

    f32x4 acc[4][4] = {};

#pragma unroll
    for (int ks = 0; ks < 2; ++ks) {
        const int koff = (kgrp + ks * 4) * 8;
        bf16x8 ah[4], al[4], bh[4], bl[4];
#pragma unroll
        for (int i = 0; i < 4; ++i) {
            int row = m0 + i * 16 + lrow; if (row >= M) row = M - 1;
            ah[i] = *(const bf16x8*)(Ahi + (size_t)row * 64 + koff);
            al[i] = *(const bf16x8*)(Alo + (size_t)row * 64 + koff);
        }
#pragma unroll
        for (int j = 0; j < 4; ++j) {
            int col = n0 + j * 16 + lrow; if (col >= N) col = N - 1;
            bh[j] = *(const bf16x8*)(Bhi + (size_t)col * 64 + koff);
            bl[j] = *(const bf16x8*)(Blo + (size_t)col * 64 + koff);
        }
#pragma unroll
        for (int i = 0; i < 4; ++i)
#pragma unroll
            for (int j = 0; j < 4; ++j) {
                acc[i][j] = __builtin_amdgcn_mfma_f32_16x16x32_bf16(bh[j], ah[i], acc[i][j], 0, 0, 0);
                acc[i][j] = __builtin_amdgcn_mfma_f32_16x16x32_bf16(bl[j], ah[i], acc[i][j], 0, 0, 0);
                acc[i][j] = __builtin_amdgcn_mfma_f32_16x16x32_bf16(bh[j], al[i], acc[i][j], 0, 0, 0);
            }
    }

    // ---- epilogue: lane -> C row (m0+i*16+lrow), 4 cols (n0+j*16+kgrp*4) ----
#pragma unroll
    for (int i = 0; i < 4; ++i) {
        int grow = m0 + i * 16 + lrow;
        if (grow >= M) continue;
        float* crow = C + (size_t)grow * N;
#pragma unroll
        for (int j = 0; j < 4; ++j) {
            int gc = n0 + j * 16 + kgrp * 4;
            if (gc + 4 <= N) {
                float4 bv = *(const float4*)(bias + gc);
                *(float4*)(crow + gc) = make_float4(acc[i][j][0] + bv.x,
                                                    acc[i][j][1] + bv.y,
                                                    acc[i][j][2] + bv.z,
                                                    acc[i][j][3] + bv.w);
            }
        }
    }
}

// ---------------- launch ----------------
// d_out (400 MB) doubles as scratch (all dead before the final GEMM):
//   O0 h[N,128] fp32 | h1hi[N,128] bf16 | h1lo[N,128] bf16 | O2 h2pre[N,64]
//   | csr_src[E] | offs | cursor | deg_cnt | bsums
// d_ws (~27 MB): dinv | WfcT hi/lo | W1T hi/lo | W2T hi/lo | h2hi | h2lo

extern "C" void kernel_launch(void* const* d_in, const int* in_sizes, int n_in,
                              void* d_out, int out_size, void* d_ws, size_t ws_size,
                              hipStream_t stream)
{
    const float* x   = (const float*)d_in[0];
    const float* W1  = (const float*)d_in[1];
    const float* b1  = (const float*)d_in[2];
    const float* W2  = (const float*)d_in[3];
    const float* b2  = (const float*)d_in[4];
    const float* Wfc = (const float*)d_in[5];
    const float* bfc = (const float*)d_in[6];
    const int*   ei  = (const int*)d_in[7];     // int32 in the harness

    const int Nn = in_sizes[0] / 128;      // 100000 nodes
    const int E  = in_sizes[7] / 2;        // 1600000 edges
    const int* src = ei;
    const int* dst = ei + E;

    char* ws = (char*)d_ws;
    float*          dinv   = (float*)(ws);
    unsigned short* Wfc_hi = (unsigned short*)(ws + 512 * 1024);
    unsigned short* Wfc_lo = (unsigned short*)(ws + 768 * 1024);
    unsigned short* W1_hi  = (unsigned short*)(ws + 1024 * 1024);
    unsigned short* W1_lo  = (unsigned short*)(ws + 1088 * 1024);
    unsigned short* W2_hi  = (unsigned short*)(ws + 1152 * 1024);
    unsigned short* W2_lo  = (unsigned short*)(ws + 1216 * 1024);
    unsigned short* h2hi   = (unsigned short*)(ws + 1280 * 1024);
    unsigned short* h2lo   = (unsigned short*)(ws + 1280 * 1024 + (size_t)Nn * 64 * 2);

    float* out = (float*)d_out;
    float*          O0      = out;                                   // h [Nn,128] fp32
    unsigned short* h1hi    = (unsigned short*)(out + (size_t)Nn * 128);
    unsigned short* h1lo    = (unsigned short*)(out + (size_t)Nn * 192);
    float*          O2      = out + (size_t)Nn * 256;                // h2pre [Nn,64]
    int*            csr_src = (int*)(out + (size_t)Nn * 320);        // E ints
    int*            offs    = (int*)((char*)csr_src + (size_t)E * 4);
    int*            cursor  = (int*)((char*)offs + (size_t)Nn * 4);
    int*            deg_cnt = (int*)((char*)cursor + (size_t)Nn * 4);
    int*            bsums   = (int*)((char*)deg_cnt + (size_t)Nn * 4);

    const int nScanBlocks = (Nn + SCAN_B - 1) / SCAN_B;

    // ---- setup: degree, dinv, CSR, weight conversion ----
    k_zero_i<<<128, 256, 0, stream>>>(deg_cnt, Nn);
    k_deg_i<<<(E + 255) / 256, 256, 0, stream>>>(dst, deg_cnt, E);
    k_dinv<<<(Nn + 255) / 256, 256, 0, stream>>>(deg_cnt, dinv, Nn);
    k_scan1<<<nScanBlocks, SCAN_B, 0, stream>>>(deg_cnt, offs, bsums, Nn);
    k_scan2<<<1, 128, 0, stream>>>(bsums, nScanBlocks);
    k_scan3<<<nScanBlocks, SCAN_B, 0, stream>>>(offs, cursor, bsums, Nn);
    k_fill<<<(E + 255) / 256, 256, 0, stream>>>(src, dst, cursor, csr_src, E);
    k_conv_w<<<128, 128, 0, stream>>>(W1, W1_hi, W1_lo, 128, 128);
    k_conv_w<<<64, 128, 0, stream>>>(W2, W2_hi, W2_lo, 128, 64);
    k_conv_w<<<1000, 64, 0, stream>>>(Wfc, Wfc_hi, Wfc_lo, 64, 1000);

    // ---- layer 1: h = x @ W1 (MFMA, fp32->split staging) ----
    gemm_mfma_l1<<<dim3((Nn + 127) / 128, 1), 256, 0, stream>>>(x, W1_hi, W1_lo, O0, Nn);
    k_gather128<<<(Nn + 3) / 4, 256, 0, stream>>>(O0, csr_src, offs, dinv, b1,
                                                  h1hi, h1lo, Nn, E);

    // ---- layer 2: h2pre = h1 @ W2 (MFMA, pre-split A) ----
    gemm_mfma_l2<<<dim3((Nn + 127) / 128, 1), 256, 0, stream>>>(h1hi, h1lo, W2_hi, W2_lo, O2, Nn);
    k_gather64<<<(Nn + 3) / 4, 256, 0, stream>>>(O2, csr_src, offs, dinv, b2,
                                                 h2hi, h2lo, Nn, E);

    // ---- output layer: out = h2 @ Wfc + bfc (MFMA, no LDS, float4 stores) ----
    gemm_mfma_out<<<dim3((Nn + 127) / 128, (1000 + 127) / 128), 256, 0, stream>>>(
        h2hi, h2lo, Wfc_hi, Wfc_lo, bfc, out, Nn, 1000);
}

// Round 12
// 530.999 us; speedup vs baseline: 1.4186x; 1.1412x over previous
//
#include <hip/hip_runtime.h>
#include <hip/hip_bf16.h>
#include <cstddef>

typedef __attribute__((ext_vector_type(8))) short bf16x8;
typedef __attribute__((ext_vector_type(4))) float f32x4;

__device__ __forceinline__ unsigned short f2bf(float f) {
    __hip_bfloat16 h = __float2bfloat16(f);
    return __builtin_bit_cast(unsigned short, h);
}
__device__ __forceinline__ float bf2f(unsigned short u) {
    return __bfloat162float(__builtin_bit_cast(__hip_bfloat16, u));
}
__device__ __forceinline__ float bflo(unsigned u) {
    return __builtin_bit_cast(float, u << 16);
}
__device__ __forceinline__ float bfhi(unsigned u) {
    return __builtin_bit_cast(float, u & 0xffff0000u);
}

// ---------------- zero fill ----------------

__global__ void k_zero_i(int* __restrict__ p, int total) {
    int i = blockIdx.x * blockDim.x + threadIdx.x;
    int stride = gridDim.x * blockDim.x;
    for (; i < total; i += stride) p[i] = 0;
}

// ---------------- degree / norm ----------------

__global__ void k_deg_i(const int* __restrict__ dst, int* __restrict__ deg, int E) {
    int e = blockIdx.x * blockDim.x + threadIdx.x;
    if (e < E) atomicAdd(&deg[dst[e]], 1);
}

__global__ void k_dinv(const int* __restrict__ deg, float* __restrict__ dinv, int N) {
    int i = blockIdx.x * blockDim.x + threadIdx.x;
    if (i < N) dinv[i] = rsqrtf((float)deg[i] + 1.0f);
}

// ---------------- exclusive scan ----------------

#define SCAN_B 1024

__global__ void k_scan1(const int* __restrict__ in, int* __restrict__ out,
                        int* __restrict__ sums, int n) {
    __shared__ int tmp[SCAN_B];
    int tid = threadIdx.x;
    int gid = blockIdx.x * SCAN_B + tid;
    int v = (gid < n) ? in[gid] : 0;
    tmp[tid] = v;
    __syncthreads();
    for (int off = 1; off < SCAN_B; off <<= 1) {
        int t = (tid >= off) ? tmp[tid - off] : 0;
        __syncthreads();
        tmp[tid] += t;
        __syncthreads();
    }
    if (gid < n) out[gid] = tmp[tid] - v;
    if (tid == SCAN_B - 1) sums[blockIdx.x] = tmp[tid];
}

__global__ void k_scan2(int* __restrict__ sums, int nb) {
    __shared__ int tmp[128];
    int tid = threadIdx.x;
    int v = (tid < nb) ? sums[tid] : 0;
    tmp[tid] = v;
    __syncthreads();
    for (int off = 1; off < 128; off <<= 1) {
        int t = (tid >= off) ? tmp[tid - off] : 0;
        __syncthreads();
        tmp[tid] += t;
        __syncthreads();
    }
    if (tid < nb) sums[tid] = tmp[tid] - v;
}

__global__ void k_scan3(int* __restrict__ out, int* __restrict__ cursor,
                        const int* __restrict__ sums, int n) {
    int gid = blockIdx.x * SCAN_B + threadIdx.x;
    if (gid < n) {
        int v = out[gid] + sums[blockIdx.x];
        out[gid] = v;
        cursor[gid] = v;
    }
}

// ---------------- CSR fill ----------------

__global__ void k_fill(const int* __restrict__ src, const int* __restrict__ dst,
                       int* __restrict__ cursor, int* __restrict__ csr_src, int E) {
    int e = blockIdx.x * blockDim.x + threadIdx.x;
    if (e < E) {
        int pos = atomicAdd(&cursor[dst[e]], 1);
        csr_src[pos] = src[e];
    }
}

// ---------------- W [K,N] fp32 -> transposed split-bf16 [n][K] ----------------

__global__ void k_conv_w(const float* __restrict__ W, unsigned short* __restrict__ Bh,
                         unsigned short* __restrict__ Bl, int K, int N)
{
    int n = blockIdx.x;
    int k = threadIdx.x;                 // blockDim = K
    float v = W[(size_t)k * N + n];
    unsigned short hi = f2bf(v);
    unsigned short lo = f2bf(v - bf2f(hi));
    Bh[(size_t)n * K + k] = hi;
    Bl[(size_t)n * K + k] = lo;
}

// ---------------- gather F=128, bf16 input -> split hi/lo output --------------
// h rows stored bf16 [N][128] (256 B/row). 16 lanes/edge x uint4 (8 bf16 each)
// -> 4 edge-groups per wave, 2-unrolled = 8 edges in flight at HALF the bytes
// of the fp32 version (R11's gather was L3-BW-bound).

__device__ __forceinline__ void unpack_fma(float* a, float w, uint4 v) {
    a[0] = fmaf(w, bflo(v.x), a[0]);
    a[1] = fmaf(w, bfhi(v.x), a[1]);
    a[2] = fmaf(w, bflo(v.y), a[2]);
    a[3] = fmaf(w, bfhi(v.y), a[3]);
    a[4] = fmaf(w, bflo(v.z), a[4]);
    a[5] = fmaf(w, bfhi(v.z), a[5]);
    a[6] = fmaf(w, bflo(v.w), a[6]);
    a[7] = fmaf(w, bfhi(v.w), a[7]);
}

__launch_bounds__(256)
__global__ void k_gather128(const unsigned short* __restrict__ hbf,
                            const int* __restrict__ csr_src, const int* __restrict__ off,
                            const float* __restrict__ dinv, const float* __restrict__ bias,
                            unsigned short* __restrict__ ohi, unsigned short* __restrict__ olo,
                            int N, int E)
{
    int node = blockIdx.x * 4 + (threadIdx.x >> 6);
    int lane = threadIdx.x & 63;
    if (node >= N) return;
    float dn = dinv[node];
    int beg = off[node];
    int end = (node + 1 < N) ? off[node + 1] : E;

    const int grp = lane >> 4;          // 4 groups
    const int sub = lane & 15;          // 16 lanes x 8 bf16 = 128 elems

    float a[8] = {0.f, 0.f, 0.f, 0.f, 0.f, 0.f, 0.f, 0.f};
    int i = beg + grp;
    for (; i + 4 < end; i += 8) {
        int s0 = csr_src[i];
        int s1 = csr_src[i + 4];
        float w0 = dinv[s0] * dn;
        float w1 = dinv[s1] * dn;
        uint4 v0 = *(const uint4*)(hbf + (size_t)s0 * 128 + sub * 8);
        uint4 v1 = *(const uint4*)(hbf + (size_t)s1 * 128 + sub * 8);
        unpack_fma(a, w0, v0);
        unpack_fma(a, w1, v1);
    }
    if (i < end) {
        int s = csr_src[i];
        float w = dinv[s] * dn;
        uint4 v = *(const uint4*)(hbf + (size_t)s * 128 + sub * 8);
        unpack_fma(a, w, v);
    }

    // cross-group reduce (xor 16, 32)
#pragma unroll
    for (int k = 0; k < 8; ++k) {
        a[k] += __shfl_xor(a[k], 16);
        a[k] += __shfl_xor(a[k], 32);
    }

    if (grp == 0) {
        uint4 sv = *(const uint4*)(hbf + (size_t)node * 128 + sub * 8);
        float s[8] = {bflo(sv.x), bfhi(sv.x), bflo(sv.y), bfhi(sv.y),
                      bflo(sv.z), bfhi(sv.z), bflo(sv.w), bfhi(sv.w)};
        float4 b0 = *(const float4*)(bias + sub * 8);
        float4 b1 = *(const float4*)(bias + sub * 8 + 4);
        float bv[8] = {b0.x, b0.y, b0.z, b0.w, b1.x, b1.y, b1.z, b1.w};
        float w = dn * dn;
        unsigned short hi[8], lo[8];
#pragma unroll
        for (int k = 0; k < 8; ++k) {
            float f = fmaxf(fmaf(s[k], w, a[k]) + bv[k], 0.f);
            hi[k] = f2bf(f);
            lo[k] = f2bf(f - bf2f(hi[k]));
        }
        uint4 vh, vl;
        vh.x = (unsigned)hi[0] | ((unsigned)hi[1] << 16);
        vh.y = (unsigned)hi[2] | ((unsigned)hi[3] << 16);
        vh.z = (unsigned)hi[4] | ((unsigned)hi[5] << 16);
        vh.w = (unsigned)hi[6] | ((unsigned)hi[7] << 16);
        vl.x = (unsigned)lo[0] | ((unsigned)lo[1] << 16);
        vl.y = (unsigned)lo[2] | ((unsigned)lo[3] << 16);
        vl.z = (unsigned)lo[4] | ((unsigned)lo[5] << 16);
        vl.w = (unsigned)lo[6] | ((unsigned)lo[7] << 16);
        *(uint4*)(ohi + (size_t)node * 128 + sub * 8) = vh;
        *(uint4*)(olo + (size_t)node * 128 + sub * 8) = vl;
    }
}

// ---------------- gather F=64, bf16 input -> split hi/lo output ---------------
// h2pre bf16 [N][64] (128 B/row). 8 lanes/edge -> 8 edge-groups, 2-unrolled
// = 16 edges in flight per wave.

__launch_bounds__(256)
__global__ void k_gather64(const unsigned short* __restrict__ hbf,
                           const int* __restrict__ csr_src, const int* __restrict__ off,
                           const float* __restrict__ dinv, const float* __restrict__ bias,
                           unsigned short* __restrict__ hhi, unsigned short* __restrict__ hlo,
                           int N, int E)
{
    int node = blockIdx.x * 4 + (threadIdx.x >> 6);
    int lane = threadIdx.x & 63;
    if (node >= N) return;
    float dn = dinv[node];
    int beg = off[node];
    int end = (node + 1 < N) ? off[node + 1] : E;

    const int grp = lane >> 3;          // 8 groups
    const int sub = lane & 7;           // 8 lanes x 8 bf16 = 64 elems

    float a[8] = {0.f, 0.f, 0.f, 0.f, 0.f, 0.f, 0.f, 0.f};
    int i = beg + grp;
    for (; i + 8 < end; i += 16) {
        int s0 = csr_src[i];
        int s1 = csr_src[i + 8];
        float w0 = dinv[s0] * dn;
        float w1 = dinv[s1] * dn;
        uint4 v0 = *(const uint4*)(hbf + (size_t)s0 * 64 + sub * 8);
        uint4 v1 = *(const uint4*)(hbf + (size_t)s1 * 64 + sub * 8);
        unpack_fma(a, w0, v0);
        unpack_fma(a, w1, v1);
    }
    if (i < end) {
        int s = csr_src[i];
        float w = dinv[s] * dn;
        uint4 v = *(const uint4*)(hbf + (size_t)s * 64 + sub * 8);
        unpack_fma(a, w, v);
    }

    // cross-group reduce (xor 8, 16, 32)
#pragma unroll
    for (int k = 0; k < 8; ++k) {
        a[k] += __shfl_xor(a[k], 8);
        a[k] += __shfl_xor(a[k], 16);
        a[k] += __shfl_xor(a[k], 32);
    }

    if (grp == 0) {
        uint4 sv = *(const uint4*)(hbf + (size_t)node * 64 + sub * 8);
        float s[8] = {bflo(sv.x), bfhi(sv.x), bflo(sv.y), bfhi(sv.y),
                      bflo(sv.z), bfhi(sv.z), bflo(sv.w), bfhi(sv.w)};
        float4 b0 = *(const float4*)(bias + sub * 8);
        float4 b1 = *(const float4*)(bias + sub * 8 + 4);
        float bv[8] = {b0.x, b0.y, b0.z, b0.w, b1.x, b1.y, b1.z, b1.w};
        float w = dn * dn;
        unsigned short hi[8], lo[8];
#pragma unroll
        for (int k = 0; k < 8; ++k) {
            float f = fmaxf(fmaf(s[k], w, a[k]) + bv[k], 0.f);
            hi[k] = f2bf(f);
            lo[k] = f2bf(f - bf2f(hi[k]));
        }
        uint4 vh, vl;
        vh.x = (unsigned)hi[0] | ((unsigned)hi[1] << 16);
        vh.y = (unsigned)hi[2] | ((unsigned)hi[3] << 16);
        vh.z = (unsigned)hi[4] | ((unsigned)hi[5] << 16);
        vh.w = (unsigned)hi[6] | ((unsigned)hi[7] << 16);
        vl.x = (unsigned)lo[0] | ((unsigned)lo[1] << 16);
        vl.y = (unsigned)lo[2] | ((unsigned)lo[3] << 16);
        vl.z = (unsigned)lo[4] | ((unsigned)lo[5] << 16);
        vl.w = (unsigned)lo[6] | ((unsigned)lo[7] << 16);
        *(uint4*)(hhi + (size_t)node * 64 + sub * 8) = vh;
        *(uint4*)(hlo + (size_t)node * 64 + sub * 8) = vl;
    }
}

// ---------------- layer-1 MFMA GEMM: hbf[M,128] = bf16(x @ W1) ----------------
// Swapped-operand mfma(b,a) -> lane holds one C row x 4 consecutive cols.
// Epilogue writes bf16 (ushort4) — halves write traffic; gather reads bf16.

__launch_bounds__(256, 2)
__global__ void gemm_mfma_l1(const float* __restrict__ A,
                             const unsigned short* __restrict__ Bth,
                             const unsigned short* __restrict__ Btl,
                             unsigned short* __restrict__ Cbf, int M)
{
    __shared__ unsigned short Ah[128 * 64], Al[128 * 64];   // 16 KB each
    __shared__ unsigned short Bh[128 * 64], Bl[128 * 64];

    const int tid = threadIdx.x;
    const int m0 = blockIdx.x * 128;
    const int lane = tid & 63, wave = tid >> 6;
    const int wr = wave >> 1, wc = wave & 1;
    const int lrow = lane & 15, kgrp = lane >> 4;

    f32x4 acc[4][4] = {};

    for (int ph = 0; ph < 2; ++ph) {
        const int k0 = ph * 64;
        __syncthreads();
        // ---- stage A with fp32->hi/lo conversion ----
        {
            const int c4 = tid & 15, r0 = tid >> 4;
#pragma unroll
            for (int p = 0; p < 8; ++p) {
                int row = r0 + p * 16;
                int gr = m0 + row; if (gr >= M) gr = M - 1;
                float4 v = *(const float4*)(A + (size_t)gr * 128 + k0 + c4 * 4);
                ushort4 hi, lo;
                hi.x = f2bf(v.x); lo.x = f2bf(v.x - bf2f(hi.x));
                hi.y = f2bf(v.y); lo.y = f2bf(v.y - bf2f(hi.y));
                hi.z = f2bf(v.z); lo.z = f2bf(v.z - bf2f(hi.z));
                hi.w = f2bf(v.w); lo.w = f2bf(v.w - bf2f(hi.w));
                int off = row * 128 + ((c4 * 8) ^ ((row & 7) << 4));
                *(ushort4*)((char*)Ah + off) = hi;
                *(ushort4*)((char*)Al + off) = lo;
            }
        }
        // ---- stage B ----
        {
            const int c = tid & 7, col0 = tid >> 3;
#pragma unroll
            for (int p = 0; p < 4; ++p) {
                int col = col0 + p * 32;
                uint4 v = *(const uint4*)(Bth + (size_t)col * 128 + k0 + c * 8);
                uint4 w = *(const uint4*)(Btl + (size_t)col * 128 + k0 + c * 8);
                int off = col * 128 + ((c * 16) ^ ((col & 7) << 4));
                *(uint4*)((char*)Bh + off) = v;
                *(uint4*)((char*)Bl + off) = w;
            }
        }
        __syncthreads();

#pragma unroll
        for (int ks = 0; ks < 2; ++ks) {
            const int cIdx = kgrp + ks * 4;
            bf16x8 ah[4], al[4], bh[4], bl[4];
#pragma unroll
            for (int i = 0; i < 4; ++i) {
                int row = wr * 64 + i * 16 + lrow;
                int off = row * 128 + ((cIdx * 16) ^ ((row & 7) << 4));
                ah[i] = *(const bf16x8*)((const char*)Ah + off);
                al[i] = *(const bf16x8*)((const char*)Al + off);
            }
#pragma unroll
            for (int j = 0; j < 4; ++j) {
                int col = wc * 64 + j * 16 + lrow;
                int off = col * 128 + ((cIdx * 16) ^ ((col & 7) << 4));
                bh[j] = *(const bf16x8*)((const char*)Bh + off);
                bl[j] = *(const bf16x8*)((const char*)Bl + off);
            }
#pragma unroll
            for (int i = 0; i < 4; ++i)
#pragma unroll
                for (int j = 0; j < 4; ++j) {
                    acc[i][j] = __builtin_amdgcn_mfma_f32_16x16x32_bf16(bh[j], ah[i], acc[i][j], 0, 0, 0);
                    acc[i][j] = __builtin_amdgcn_mfma_f32_16x16x32_bf16(bl[j], ah[i], acc[i][j], 0, 0, 0);
                    acc[i][j] = __builtin_amdgcn_mfma_f32_16x16x32_bf16(bh[j], al[i], acc[i][j], 0, 0, 0);
                }
        }
    }

    // ---- epilogue: bf16 store, row = m0+wr*64+i*16+lrow, cols = wc*64+j*16+kgrp*4 ----
#pragma unroll
    for (int i = 0; i < 4; ++i) {
        int grow = m0 + wr * 64 + i * 16 + lrow;
        if (grow >= M) continue;
        unsigned short* crow = Cbf + (size_t)grow * 128;
#pragma unroll
        for (int j = 0; j < 4; ++j) {
            int gc = wc * 64 + j * 16 + kgrp * 4;
            ushort4 o;
            o.x = f2bf(acc[i][j][0]);
            o.y = f2bf(acc[i][j][1]);
            o.z = f2bf(acc[i][j][2]);
            o.w = f2bf(acc[i][j][3]);
            *(ushort4*)(crow + gc) = o;
        }
    }
}

// ---------------- layer-2 MFMA GEMM: h2bf[M,64] = bf16(h1 @ W2) ---------------

__launch_bounds__(256, 3)
__global__ void gemm_mfma_l2(const unsigned short* __restrict__ Ahi_g,
                             const unsigned short* __restrict__ Alo_g,
                             const unsigned short* __restrict__ Bth,
                             const unsigned short* __restrict__ Btl,
                             unsigned short* __restrict__ Cbf, int M)
{
    __shared__ unsigned short Ah[128 * 64], Al[128 * 64];   // 16 KB each
    __shared__ unsigned short Bh[64 * 64],  Bl[64 * 64];    // 8 KB each

    const int tid = threadIdx.x;
    const int m0 = blockIdx.x * 128;
    const int lane = tid & 63, wave = tid >> 6;
    const int wr = wave >> 1, wc = wave & 1;
    const int lrow = lane & 15, kgrp = lane >> 4;

    f32x4 acc[4][2] = {};

    for (int ph = 0; ph < 2; ++ph) {
        const int k0 = ph * 64;
        __syncthreads();
        // ---- stage A (direct copy of pre-split h1) ----
        {
            const int c = tid & 7, r0 = tid >> 3;
#pragma unroll
            for (int p = 0; p < 4; ++p) {
                int row = r0 + p * 32;
                int gr = m0 + row; if (gr >= M) gr = M - 1;
                uint4 v = *(const uint4*)(Ahi_g + (size_t)gr * 128 + k0 + c * 8);
                uint4 w = *(const uint4*)(Alo_g + (size_t)gr * 128 + k0 + c * 8);
                int off = row * 128 + ((c * 16) ^ ((row & 7) << 4));
                *(uint4*)((char*)Ah + off) = v;
                *(uint4*)((char*)Al + off) = w;
            }
        }
        // ---- stage B ----
        {
            const int c = tid & 7, col0 = tid >> 3;
#pragma unroll
            for (int p = 0; p < 2; ++p) {
                int col = col0 + p * 32;
                uint4 v = *(const uint4*)(Bth + (size_t)col * 128 + k0 + c * 8);
                uint4 w = *(const uint4*)(Btl + (size_t)col * 128 + k0 + c * 8);
                int off = col * 128 + ((c * 16) ^ ((col & 7) << 4));
                *(uint4*)((char*)Bh + off) = v;
                *(uint4*)((char*)Bl + off) = w;
            }
        }
        __syncthreads();

#pragma unroll
        for (int ks = 0; ks < 2; ++ks) {
            const int cIdx = kgrp + ks * 4;
            bf16x8 ah[4], al[4], bh[2], bl[2];
#pragma unroll
            for (int i = 0; i < 4; ++i) {
                int row = wr * 64 + i * 16 + lrow;
                int off = row * 128 + ((cIdx * 16) ^ ((row & 7) << 4));
                ah[i] = *(const bf16x8*)((const char*)Ah + off);
                al[i] = *(const bf16x8*)((const char*)Al + off);
            }
#pragma unroll
            for (int j = 0; j < 2; ++j) {
                int col = wc * 32 + j * 16 + lrow;
                int off = col * 128 + ((cIdx * 16) ^ ((col & 7) << 4));
                bh[j] = *(const bf16x8*)((const char*)Bh + off);
                bl[j] = *(const bf16x8*)((const char*)Bl + off);
            }
#pragma unroll
            for (int i = 0; i < 4; ++i)
#pragma unroll
                for (int j = 0; j < 2; ++j) {
                    acc[i][j] = __builtin_amdgcn_mfma_f32_16x16x32_bf16(bh[j], ah[i], acc[i][j], 0, 0, 0);
                    acc[i][j] = __builtin_amdgcn_mfma_f32_16x16x32_bf16(bl[j], ah[i], acc[i][j], 0, 0, 0);
                    acc[i][j] = __builtin_amdgcn_mfma_f32_16x16x32_bf16(bh[j], al[i], acc[i][j], 0, 0, 0);
                }
        }
    }

#pragma unroll
    for (int i = 0; i < 4; ++i) {
        int grow = m0 + wr * 64 + i * 16 + lrow;
        if (grow >= M) continue;
        unsigned short* crow = Cbf + (size_t)grow * 64;
#pragma unroll
        for (int j = 0; j < 2; ++j) {
            int gc = wc * 32 + j * 16 + kgrp * 4;
            ushort4 o;
            o.x = f2bf(acc[i][j][0]);
            o.y = f2bf(acc[i][j][1]);
            o.z = f2bf(acc[i][j][2]);
            o.w = f2bf(acc[i][j][3]);
            *(ushort4*)(crow + gc) = o;
        }
    }
}

// ---------------- output MFMA GEMM, no LDS, swapped operands ----------------

__launch_bounds__(256, 2)
__global__ void gemm_mfma_out(const unsigned short* __restrict__ Ahi,
                              const unsigned short* __restrict__ Alo,
                              const unsigned short* __restrict__ Bhi,
                              const unsigned short* __restrict__ Blo,
                              const float* __restrict__ bias, float* __restrict__ C,
                              int M, int N)
{
    const int tid = threadIdx.x;
    const int lane = tid & 63, wave = tid >> 6;
    const int wr = wave >> 1, wc = wave & 1;
    const int m0 = blockIdx.x * 128 + wr * 64;
    const int n0 = blockIdx.y * 128 + wc * 64;
    const int lrow = lane & 15, kgrp = lane >> 4;

    f32x4 acc[4][4] = {};

#pragma unroll
    for (int ks = 0; ks < 2; ++ks) {
        const int koff = (kgrp + ks * 4) * 8;
        bf16x8 ah[4], al[4], bh[4], bl[4];
#pragma unroll
        for (int i = 0; i < 4; ++i) {
            int row = m0 + i * 16 + lrow; if (row >= M) row = M - 1;
            ah[i] = *(const bf16x8*)(Ahi + (size_t)row * 64 + koff);
            al[i] = *(const bf16x8*)(Alo + (size_t)row * 64 + koff);
        }
#pragma unroll
        for (int j = 0; j < 4; ++j) {
            int col = n0 + j * 16 + lrow; if (col >= N) col = N - 1;
            bh[j] = *(const bf16x8*)(Bhi + (size_t)col * 64 + koff);
            bl[j] = *(const bf16x8*)(Blo + (size_t)col * 64 + koff);
        }
#pragma unroll
        for (int i = 0; i < 4; ++i)
#pragma unroll
            for (int j = 0; j < 4; ++j) {
                acc[i][j] = __builtin_amdgcn_mfma_f32_16x16x32_bf16(bh[j], ah[i], acc[i][j], 0, 0, 0);
                acc[i][j] = __builtin_amdgcn_mfma_f32_16x16x32_bf16(bl[j], ah[i], acc[i][j], 0, 0, 0);
                acc[i][j] = __builtin_amdgcn_mfma_f32_16x16x32_bf16(bh[j], al[i], acc[i][j], 0, 0, 0);
            }
    }

#pragma unroll
    for (int i = 0; i < 4; ++i) {
        int grow = m0 + i * 16 + lrow;
        if (grow >= M) continue;
        float* crow = C + (size_t)grow * N;
#pragma unroll
        for (int j = 0; j < 4; ++j) {
            int gc = n0 + j * 16 + kgrp * 4;
            if (gc + 4 <= N) {
                float4 bv = *(const float4*)(bias + gc);
                *(float4*)(crow + gc) = make_float4(acc[i][j][0] + bv.x,
                                                    acc[i][j][1] + bv.y,
                                                    acc[i][j][2] + bv.z,
                                                    acc[i][j][3] + bv.w);
            }
        }
    }
}

// ---------------- launch ----------------
// d_out (400 MB) scratch (all dead before final GEMM):
//   hbf[N,128]bf16 25.6MB | h1hi 25.6 | h1lo 25.6 | h2bf[N,64]bf16 12.8
//   | csr_src[E] | offs | cursor | deg_cnt | bsums           (~96 MB)
// d_ws (~27 MB): dinv | Wfc hi/lo | W1 hi/lo | W2 hi/lo | h2hi | h2lo
// (h2hi/h2lo must survive the final GEMM's d_out writes.)

extern "C" void kernel_launch(void* const* d_in, const int* in_sizes, int n_in,
                              void* d_out, int out_size, void* d_ws, size_t ws_size,
                              hipStream_t stream)
{
    const float* x   = (const float*)d_in[0];
    const float* W1  = (const float*)d_in[1];
    const float* b1  = (const float*)d_in[2];
    const float* W2  = (const float*)d_in[3];
    const float* b2  = (const float*)d_in[4];
    const float* Wfc = (const float*)d_in[5];
    const float* bfc = (const float*)d_in[6];
    const int*   ei  = (const int*)d_in[7];     // int32 in the harness

    const int Nn = in_sizes[0] / 128;      // 100000 nodes
    const int E  = in_sizes[7] / 2;        // 1600000 edges
    const int* src = ei;
    const int* dst = ei + E;

    char* ws = (char*)d_ws;
    float*          dinv   = (float*)(ws);
    unsigned short* Wfc_hi = (unsigned short*)(ws + 512 * 1024);
    unsigned short* Wfc_lo = (unsigned short*)(ws + 768 * 1024);
    unsigned short* W1_hi  = (unsigned short*)(ws + 1024 * 1024);
    unsigned short* W1_lo  = (unsigned short*)(ws + 1088 * 1024);
    unsigned short* W2_hi  = (unsigned short*)(ws + 1152 * 1024);
    unsigned short* W2_lo  = (unsigned short*)(ws + 1216 * 1024);
    unsigned short* h2hi   = (unsigned short*)(ws + 1280 * 1024);
    unsigned short* h2lo   = (unsigned short*)(ws + 1280 * 1024 + (size_t)Nn * 64 * 2);

    char* ob = (char*)d_out;
    unsigned short* hbf     = (unsigned short*)ob;                       // Nn*128 bf16
    unsigned short* h1hi    = (unsigned short*)(ob + (size_t)Nn * 256);  // Nn*128 bf16
    unsigned short* h1lo    = (unsigned short*)(ob + (size_t)Nn * 512);
    unsigned short* h2bf    = (unsigned short*)(ob + (size_t)Nn * 768);  // Nn*64 bf16
    int*            csr_src = (int*)(ob + (size_t)Nn * 896);             // E ints
    int*            offs    = (int*)((char*)csr_src + (size_t)E * 4);
    int*            cursor  = (int*)((char*)offs + (size_t)Nn * 4);
    int*            deg_cnt = (int*)((char*)cursor + (size_t)Nn * 4);
    int*            bsums   = (int*)((char*)deg_cnt + (size_t)Nn * 4);

    const int nScanBlocks = (Nn + SCAN_B - 1) / SCAN_B;

    // ---- setup: degree, dinv, CSR, weight conversion ----
    k_zero_i<<<128, 256, 0, stream>>>(deg_cnt, Nn);
    k_deg_i<<<(E + 255) / 256, 256, 0, stream>>>(dst, deg_cnt, E);
    k_dinv<<<(Nn + 255) / 256, 256, 0, stream>>>(deg_cnt, dinv, Nn);
    k_scan1<<<nScanBlocks, SCAN_B, 0, stream>>>(deg_cnt, offs, bsums, Nn);
    k_scan2<<<1, 128, 0, stream>>>(bsums, nScanBlocks);
    k_scan3<<<nScanBlocks, SCAN_B, 0, stream>>>(offs, cursor, bsums, Nn);
    k_fill<<<(E + 255) / 256, 256, 0, stream>>>(src, dst, cursor, csr_src, E);
    k_conv_w<<<128, 128, 0, stream>>>(W1, W1_hi, W1_lo, 128, 128);
    k_conv_w<<<64, 128, 0, stream>>>(W2, W2_hi, W2_lo, 128, 64);
    k_conv_w<<<1000, 64, 0, stream>>>(Wfc, Wfc_hi, Wfc_lo, 64, 1000);

    // ---- layer 1: hbf = bf16(x @ W1) ----
    gemm_mfma_l1<<<dim3((Nn + 127) / 128, 1), 256, 0, stream>>>(x, W1_hi, W1_lo, hbf, Nn);
    // h1 = relu(gather(hbf)+self+b1) -> split hi/lo
    k_gather128<<<(Nn + 3) / 4, 256, 0, stream>>>(hbf, csr_src, offs, dinv, b1,
                                                  h1hi, h1lo, Nn, E);

    // ---- layer 2: h2bf = bf16(h1 @ W2) ----
    gemm_mfma_l2<<<dim3((Nn + 127) / 128, 1), 256, 0, stream>>>(h1hi, h1lo, W2_hi, W2_lo, h2bf, Nn);
    // h2 = relu(gather(h2bf)+self+b2) -> split hi/lo (ws)
    k_gather64<<<(Nn + 3) / 4, 256, 0, stream>>>(h2bf, csr_src, offs, dinv, b2,
                                                 h2hi, h2lo, Nn, E);

    // ---- output layer: out = h2 @ Wfc + bfc ----
    gemm_mfma_out<<<dim3((Nn + 127) / 128, (1000 + 127) / 128), 256, 0, stream>>>(
        h2hi, h2lo, Wfc_hi, Wfc_lo, bfc, out_size ? (float*)d_out : (float*)d_out, Nn, 1000);
}

// Round 13
// 529.068 us; speedup vs baseline: 1.4238x; 1.0036x over previous
//
#include <hip/hip_runtime.h>
#include <hip/hip_bf16.h>
#include <cstddef>

typedef __attribute__((ext_vector_type(8))) short bf16x8;
typedef __attribute__((ext_vector_type(4))) float f32x4;

__device__ __forceinline__ unsigned short f2bf(float f) {
    __hip_bfloat16 h = __float2bfloat16(f);
    return __builtin_bit_cast(unsigned short, h);
}
__device__ __forceinline__ float bf2f(unsigned short u) {
    return __bfloat162float(__builtin_bit_cast(__hip_bfloat16, u));
}
__device__ __forceinline__ float bflo(unsigned u) {
    return __builtin_bit_cast(float, u << 16);
}
__device__ __forceinline__ float bfhi(unsigned u) {
    return __builtin_bit_cast(float, u & 0xffff0000u);
}

// ---------------- zero fill ----------------

__global__ void k_zero_i(int* __restrict__ p, int total) {
    int i = blockIdx.x * blockDim.x + threadIdx.x;
    int stride = gridDim.x * blockDim.x;
    for (; i < total; i += stride) p[i] = 0;
}

// ---------------- degree / norm ----------------

__global__ void k_deg_i(const int* __restrict__ dst, int* __restrict__ deg, int E) {
    int e = blockIdx.x * blockDim.x + threadIdx.x;
    if (e < E) atomicAdd(&deg[dst[e]], 1);
}

__global__ void k_dinv(const int* __restrict__ deg, float* __restrict__ dinv, int N) {
    int i = blockIdx.x * blockDim.x + threadIdx.x;
    if (i < N) dinv[i] = rsqrtf((float)deg[i] + 1.0f);
}

// ---------------- exclusive scan ----------------

#define SCAN_B 1024

__global__ void k_scan1(const int* __restrict__ in, int* __restrict__ out,
                        int* __restrict__ sums, int n) {
    __shared__ int tmp[SCAN_B];
    int tid = threadIdx.x;
    int gid = blockIdx.x * SCAN_B + tid;
    int v = (gid < n) ? in[gid] : 0;
    tmp[tid] = v;
    __syncthreads();
    for (int off = 1; off < SCAN_B; off <<= 1) {
        int t = (tid >= off) ? tmp[tid - off] : 0;
        __syncthreads();
        tmp[tid] += t;
        __syncthreads();
    }
    if (gid < n) out[gid] = tmp[tid] - v;
    if (tid == SCAN_B - 1) sums[blockIdx.x] = tmp[tid];
}

__global__ void k_scan2(int* __restrict__ sums, int nb) {
    __shared__ int tmp[128];
    int tid = threadIdx.x;
    int v = (tid < nb) ? sums[tid] : 0;
    tmp[tid] = v;
    __syncthreads();
    for (int off = 1; off < 128; off <<= 1) {
        int t = (tid >= off) ? tmp[tid - off] : 0;
        __syncthreads();
        tmp[tid] += t;
        __syncthreads();
    }
    if (tid < nb) sums[tid] = tmp[tid] - v;
}

__global__ void k_scan3(int* __restrict__ out, int* __restrict__ cursor,
                        const int* __restrict__ sums, int n) {
    int gid = blockIdx.x * SCAN_B + threadIdx.x;
    if (gid < n) {
        int v = out[gid] + sums[blockIdx.x];
        out[gid] = v;
        cursor[gid] = v;
    }
}

// ---------------- CSR fill ----------------

__global__ void k_fill(const int* __restrict__ src, const int* __restrict__ dst,
                       int* __restrict__ cursor, int* __restrict__ csr_src, int E) {
    int e = blockIdx.x * blockDim.x + threadIdx.x;
    if (e < E) {
        int pos = atomicAdd(&cursor[dst[e]], 1);
        csr_src[pos] = src[e];
    }
}

// ---------------- W [K,N] fp32 -> transposed bf16 [n][K] (single / split) -----

__global__ void k_conv_w_bf(const float* __restrict__ W, unsigned short* __restrict__ Bh,
                            int K, int N)
{
    int n = blockIdx.x;
    int k = threadIdx.x;                 // blockDim = K
    Bh[(size_t)n * K + k] = f2bf(W[(size_t)k * N + n]);
}

__global__ void k_conv_w(const float* __restrict__ W, unsigned short* __restrict__ Bh,
                         unsigned short* __restrict__ Bl, int K, int N)
{
    int n = blockIdx.x;
    int k = threadIdx.x;
    float v = W[(size_t)k * N + n];
    unsigned short hi = f2bf(v);
    unsigned short lo = f2bf(v - bf2f(hi));
    Bh[(size_t)n * K + k] = hi;
    Bl[(size_t)n * K + k] = lo;
}

// ---------------- gather F=128, bf16 in -> bf16 out --------------------------
// h rows bf16 [N][128] (256 B/row). 16 lanes/edge x uint4, 4 edge-groups/wave,
// 2-unrolled = 8 edges in flight. Output single bf16 (error attenuated x0.096
// downstream — measured absmax floor gives headroom).

__device__ __forceinline__ void unpack_fma(float* a, float w, uint4 v) {
    a[0] = fmaf(w, bflo(v.x), a[0]);
    a[1] = fmaf(w, bfhi(v.x), a[1]);
    a[2] = fmaf(w, bflo(v.y), a[2]);
    a[3] = fmaf(w, bfhi(v.y), a[3]);
    a[4] = fmaf(w, bflo(v.z), a[4]);
    a[5] = fmaf(w, bfhi(v.z), a[5]);
    a[6] = fmaf(w, bflo(v.w), a[6]);
    a[7] = fmaf(w, bfhi(v.w), a[7]);
}

__launch_bounds__(256)
__global__ void k_gather128(const unsigned short* __restrict__ hbf,
                            const int* __restrict__ csr_src, const int* __restrict__ off,
                            const float* __restrict__ dinv, const float* __restrict__ bias,
                            unsigned short* __restrict__ obf, int N, int E)
{
    int node = blockIdx.x * 4 + (threadIdx.x >> 6);
    int lane = threadIdx.x & 63;
    if (node >= N) return;
    float dn = dinv[node];
    int beg = off[node];
    int end = (node + 1 < N) ? off[node + 1] : E;

    const int grp = lane >> 4;          // 4 groups
    const int sub = lane & 15;          // 16 lanes x 8 bf16 = 128 elems

    float a[8] = {0.f, 0.f, 0.f, 0.f, 0.f, 0.f, 0.f, 0.f};
    int i = beg + grp;
    for (; i + 4 < end; i += 8) {
        int s0 = csr_src[i];
        int s1 = csr_src[i + 4];
        float w0 = dinv[s0] * dn;
        float w1 = dinv[s1] * dn;
        uint4 v0 = *(const uint4*)(hbf + (size_t)s0 * 128 + sub * 8);
        uint4 v1 = *(const uint4*)(hbf + (size_t)s1 * 128 + sub * 8);
        unpack_fma(a, w0, v0);
        unpack_fma(a, w1, v1);
    }
    if (i < end) {
        int s = csr_src[i];
        float w = dinv[s] * dn;
        uint4 v = *(const uint4*)(hbf + (size_t)s * 128 + sub * 8);
        unpack_fma(a, w, v);
    }

#pragma unroll
    for (int k = 0; k < 8; ++k) {
        a[k] += __shfl_xor(a[k], 16);
        a[k] += __shfl_xor(a[k], 32);
    }

    if (grp == 0) {
        uint4 sv = *(const uint4*)(hbf + (size_t)node * 128 + sub * 8);
        float s[8] = {bflo(sv.x), bfhi(sv.x), bflo(sv.y), bfhi(sv.y),
                      bflo(sv.z), bfhi(sv.z), bflo(sv.w), bfhi(sv.w)};
        float4 b0 = *(const float4*)(bias + sub * 8);
        float4 b1 = *(const float4*)(bias + sub * 8 + 4);
        float bv[8] = {b0.x, b0.y, b0.z, b0.w, b1.x, b1.y, b1.z, b1.w};
        float w = dn * dn;
        unsigned short o[8];
#pragma unroll
        for (int k = 0; k < 8; ++k)
            o[k] = f2bf(fmaxf(fmaf(s[k], w, a[k]) + bv[k], 0.f));
        uint4 vo;
        vo.x = (unsigned)o[0] | ((unsigned)o[1] << 16);
        vo.y = (unsigned)o[2] | ((unsigned)o[3] << 16);
        vo.z = (unsigned)o[4] | ((unsigned)o[5] << 16);
        vo.w = (unsigned)o[6] | ((unsigned)o[7] << 16);
        *(uint4*)(obf + (size_t)node * 128 + sub * 8) = vo;
    }
}

// ---------------- gather F=64, bf16 in -> split hi/lo out ---------------------
// Feeds the FINAL GEMM (errors unattenuated) -> keep split output.

__launch_bounds__(256)
__global__ void k_gather64(const unsigned short* __restrict__ hbf,
                           const int* __restrict__ csr_src, const int* __restrict__ off,
                           const float* __restrict__ dinv, const float* __restrict__ bias,
                           unsigned short* __restrict__ hhi, unsigned short* __restrict__ hlo,
                           int N, int E)
{
    int node = blockIdx.x * 4 + (threadIdx.x >> 6);
    int lane = threadIdx.x & 63;
    if (node >= N) return;
    float dn = dinv[node];
    int beg = off[node];
    int end = (node + 1 < N) ? off[node + 1] : E;

    const int grp = lane >> 3;          // 8 groups
    const int sub = lane & 7;           // 8 lanes x 8 bf16 = 64 elems

    float a[8] = {0.f, 0.f, 0.f, 0.f, 0.f, 0.f, 0.f, 0.f};
    int i = beg + grp;
    for (; i + 8 < end; i += 16) {
        int s0 = csr_src[i];
        int s1 = csr_src[i + 8];
        float w0 = dinv[s0] * dn;
        float w1 = dinv[s1] * dn;
        uint4 v0 = *(const uint4*)(hbf + (size_t)s0 * 64 + sub * 8);
        uint4 v1 = *(const uint4*)(hbf + (size_t)s1 * 64 + sub * 8);
        unpack_fma(a, w0, v0);
        unpack_fma(a, w1, v1);
    }
    if (i < end) {
        int s = csr_src[i];
        float w = dinv[s] * dn;
        uint4 v = *(const uint4*)(hbf + (size_t)s * 64 + sub * 8);
        unpack_fma(a, w, v);
    }

#pragma unroll
    for (int k = 0; k < 8; ++k) {
        a[k] += __shfl_xor(a[k], 8);
        a[k] += __shfl_xor(a[k], 16);
        a[k] += __shfl_xor(a[k], 32);
    }

    if (grp == 0) {
        uint4 sv = *(const uint4*)(hbf + (size_t)node * 64 + sub * 8);
        float s[8] = {bflo(sv.x), bfhi(sv.x), bflo(sv.y), bfhi(sv.y),
                      bflo(sv.z), bfhi(sv.z), bflo(sv.w), bfhi(sv.w)};
        float4 b0 = *(const float4*)(bias + sub * 8);
        float4 b1 = *(const float4*)(bias + sub * 8 + 4);
        float bv[8] = {b0.x, b0.y, b0.z, b0.w, b1.x, b1.y, b1.z, b1.w};
        float w = dn * dn;
        unsigned short hi[8], lo[8];
#pragma unroll
        for (int k = 0; k < 8; ++k) {
            float f = fmaxf(fmaf(s[k], w, a[k]) + bv[k], 0.f);
            hi[k] = f2bf(f);
            lo[k] = f2bf(f - bf2f(hi[k]));
        }
        uint4 vh, vl;
        vh.x = (unsigned)hi[0] | ((unsigned)hi[1] << 16);
        vh.y = (unsigned)hi[2] | ((unsigned)hi[3] << 16);
        vh.z = (unsigned)hi[4] | ((unsigned)hi[5] << 16);
        vh.w = (unsigned)hi[6] | ((unsigned)hi[7] << 16);
        vl.x = (unsigned)lo[0] | ((unsigned)lo[1] << 16);
        vl.y = (unsigned)lo[2] | ((unsigned)lo[3] << 16);
        vl.z = (unsigned)lo[4] | ((unsigned)lo[5] << 16);
        vl.w = (unsigned)lo[6] | ((unsigned)lo[7] << 16);
        *(uint4*)(hhi + (size_t)node * 64 + sub * 8) = vh;
        *(uint4*)(hlo + (size_t)node * 64 + sub * 8) = vl;
    }
}

// ---------------- layer-1 GEMM, PURE bf16: hbf[M,128] = bf16(x_bf @ W1_bf) ----
// Error introduced here is attenuated x0.008 to the output (gather x0.24,
// W2 x0.57, gather x0.24, Wfc x0.4) — pure bf16 is safe. 1 MFMA per tile-pair.

__launch_bounds__(256, 2)
__global__ void gemm_mfma_l1(const float* __restrict__ A,
                             const unsigned short* __restrict__ Bt,
                             unsigned short* __restrict__ Cbf, int M)
{
    __shared__ unsigned short Ah[128 * 64];   // 16 KB
    __shared__ unsigned short Bh[128 * 64];   // 16 KB

    const int tid = threadIdx.x;
    const int m0 = blockIdx.x * 128;
    const int lane = tid & 63, wave = tid >> 6;
    const int wr = wave >> 1, wc = wave & 1;
    const int lrow = lane & 15, kgrp = lane >> 4;

    f32x4 acc[4][4] = {};

    for (int ph = 0; ph < 2; ++ph) {
        const int k0 = ph * 64;
        __syncthreads();
        // ---- stage A with fp32->bf16 conversion ----
        {
            const int c4 = tid & 15, r0 = tid >> 4;
#pragma unroll
            for (int p = 0; p < 8; ++p) {
                int row = r0 + p * 16;
                int gr = m0 + row; if (gr >= M) gr = M - 1;
                float4 v = *(const float4*)(A + (size_t)gr * 128 + k0 + c4 * 4);
                ushort4 hv;
                hv.x = f2bf(v.x); hv.y = f2bf(v.y); hv.z = f2bf(v.z); hv.w = f2bf(v.w);
                *(ushort4*)((char*)Ah + row * 128 + ((c4 * 8) ^ ((row & 7) << 4))) = hv;
            }
        }
        // ---- stage B ----
        {
            const int c = tid & 7, col0 = tid >> 3;
#pragma unroll
            for (int p = 0; p < 4; ++p) {
                int col = col0 + p * 32;
                uint4 v = *(const uint4*)(Bt + (size_t)col * 128 + k0 + c * 8);
                *(uint4*)((char*)Bh + col * 128 + ((c * 16) ^ ((col & 7) << 4))) = v;
            }
        }
        __syncthreads();

#pragma unroll
        for (int ks = 0; ks < 2; ++ks) {
            const int cIdx = kgrp + ks * 4;
            bf16x8 ah[4], bh[4];
#pragma unroll
            for (int i = 0; i < 4; ++i) {
                int row = wr * 64 + i * 16 + lrow;
                ah[i] = *(const bf16x8*)((const char*)Ah + row * 128 + ((cIdx * 16) ^ ((row & 7) << 4)));
            }
#pragma unroll
            for (int j = 0; j < 4; ++j) {
                int col = wc * 64 + j * 16 + lrow;
                bh[j] = *(const bf16x8*)((const char*)Bh + col * 128 + ((cIdx * 16) ^ ((col & 7) << 4)));
            }
#pragma unroll
            for (int i = 0; i < 4; ++i)
#pragma unroll
                for (int j = 0; j < 4; ++j)
                    acc[i][j] = __builtin_amdgcn_mfma_f32_16x16x32_bf16(bh[j], ah[i], acc[i][j], 0, 0, 0);
        }
    }

    // ---- epilogue: bf16 store; lane -> row m0+wr*64+i*16+lrow, cols wc*64+j*16+kgrp*4 ----
#pragma unroll
    for (int i = 0; i < 4; ++i) {
        int grow = m0 + wr * 64 + i * 16 + lrow;
        if (grow >= M) continue;
        unsigned short* crow = Cbf + (size_t)grow * 128;
#pragma unroll
        for (int j = 0; j < 4; ++j) {
            int gc = wc * 64 + j * 16 + kgrp * 4;
            ushort4 o;
            o.x = f2bf(acc[i][j][0]);
            o.y = f2bf(acc[i][j][1]);
            o.z = f2bf(acc[i][j][2]);
            o.w = f2bf(acc[i][j][3]);
            *(ushort4*)(crow + gc) = o;
        }
    }
}

// ---------------- layer-2 GEMM, PURE bf16: h2bf[M,64] = bf16(h1bf @ W2_bf) ----

__launch_bounds__(256, 3)
__global__ void gemm_mfma_l2(const unsigned short* __restrict__ Abf,
                             const unsigned short* __restrict__ Bt,
                             unsigned short* __restrict__ Cbf, int M)
{
    __shared__ unsigned short Ah[128 * 64];   // 16 KB
    __shared__ unsigned short Bh[64 * 64];    // 8 KB

    const int tid = threadIdx.x;
    const int m0 = blockIdx.x * 128;
    const int lane = tid & 63, wave = tid >> 6;
    const int wr = wave >> 1, wc = wave & 1;
    const int lrow = lane & 15, kgrp = lane >> 4;

    f32x4 acc[4][2] = {};

    for (int ph = 0; ph < 2; ++ph) {
        const int k0 = ph * 64;
        __syncthreads();
        // ---- stage A (copy of h1 bf16) ----
        {
            const int c = tid & 7, r0 = tid >> 3;
#pragma unroll
            for (int p = 0; p < 4; ++p) {
                int row = r0 + p * 32;
                int gr = m0 + row; if (gr >= M) gr = M - 1;
                uint4 v = *(const uint4*)(Abf + (size_t)gr * 128 + k0 + c * 8);
                *(uint4*)((char*)Ah + row * 128 + ((c * 16) ^ ((row & 7) << 4))) = v;
            }
        }
        // ---- stage B (64 cols) ----
        {
            const int c = tid & 7, col0 = tid >> 3;
#pragma unroll
            for (int p = 0; p < 2; ++p) {
                int col = col0 + p * 32;
                uint4 v = *(const uint4*)(Bt + (size_t)col * 128 + k0 + c * 8);
                *(uint4*)((char*)Bh + col * 128 + ((c * 16) ^ ((col & 7) << 4))) = v;
            }
        }
        __syncthreads();

#pragma unroll
        for (int ks = 0; ks < 2; ++ks) {
            const int cIdx = kgrp + ks * 4;
            bf16x8 ah[4], bh[2];
#pragma unroll
            for (int i = 0; i < 4; ++i) {
                int row = wr * 64 + i * 16 + lrow;
                ah[i] = *(const bf16x8*)((const char*)Ah + row * 128 + ((cIdx * 16) ^ ((row & 7) << 4)));
            }
#pragma unroll
            for (int j = 0; j < 2; ++j) {
                int col = wc * 32 + j * 16 + lrow;
                bh[j] = *(const bf16x8*)((const char*)Bh + col * 128 + ((cIdx * 16) ^ ((col & 7) << 4)));
            }
#pragma unroll
            for (int i = 0; i < 4; ++i)
#pragma unroll
                for (int j = 0; j < 2; ++j)
                    acc[i][j] = __builtin_amdgcn_mfma_f32_16x16x32_bf16(bh[j], ah[i], acc[i][j], 0, 0, 0);
        }
    }

#pragma unroll
    for (int i = 0; i < 4; ++i) {
        int grow = m0 + wr * 64 + i * 16 + lrow;
        if (grow >= M) continue;
        unsigned short* crow = Cbf + (size_t)grow * 64;
#pragma unroll
        for (int j = 0; j < 2; ++j) {
            int gc = wc * 32 + j * 16 + kgrp * 4;
            ushort4 o;
            o.x = f2bf(acc[i][j][0]);
            o.y = f2bf(acc[i][j][1]);
            o.z = f2bf(acc[i][j][2]);
            o.w = f2bf(acc[i][j][3]);
            *(ushort4*)(crow + gc) = o;
        }
    }
}

// ---------------- output MFMA GEMM, no LDS, swapped operands, 3-term ----------
// GRID: x = N-blocks (8, fast dim), y = M-blocks -> the 8 blocks sharing an
// A-panel dispatch consecutively (A read once; was re-streamed 8x from L3).

__launch_bounds__(256, 2)
__global__ void gemm_mfma_out(const unsigned short* __restrict__ Ahi,
                              const unsigned short* __restrict__ Alo,
                              const unsigned short* __restrict__ Bhi,
                              const unsigned short* __restrict__ Blo,
                              const float* __restrict__ bias, float* __restrict__ C,
                              int M, int N)
{
    const int tid = threadIdx.x;
    const int lane = tid & 63, wave = tid >> 6;
    const int wr = wave >> 1, wc = wave & 1;
    const int m0 = blockIdx.y * 128 + wr * 64;
    const int n0 = blockIdx.x * 128 + wc * 64;
    const int lrow = lane & 15, kgrp = lane >> 4;

    f32x4 acc[4][4] = {};

#pragma unroll
    for (int ks = 0; ks < 2; ++ks) {
        const int koff = (kgrp + ks * 4) * 8;
        bf16x8 ah[4], al[4], bh[4], bl[4];
#pragma unroll
        for (int i = 0; i < 4; ++i) {
            int row = m0 + i * 16 + lrow; if (row >= M) row = M - 1;
            ah[i] = *(const bf16x8*)(Ahi + (size_t)row * 64 + koff);
            al[i] = *(const bf16x8*)(Alo + (size_t)row * 64 + koff);
        }
#pragma unroll
        for (int j = 0; j < 4; ++j) {
            int col = n0 + j * 16 + lrow; if (col >= N) col = N - 1;
            bh[j] = *(const bf16x8*)(Bhi + (size_t)col * 64 + koff);
            bl[j] = *(const bf16x8*)(Blo + (size_t)col * 64 + koff);
        }
#pragma unroll
        for (int i = 0; i < 4; ++i)
#pragma unroll
            for (int j = 0; j < 4; ++j) {
                acc[i][j] = __builtin_amdgcn_mfma_f32_16x16x32_bf16(bh[j], ah[i], acc[i][j], 0, 0, 0);
                acc[i][j] = __builtin_amdgcn_mfma_f32_16x16x32_bf16(bl[j], ah[i], acc[i][j], 0, 0, 0);
                acc[i][j] = __builtin_amdgcn_mfma_f32_16x16x32_bf16(bh[j], al[i], acc[i][j], 0, 0, 0);
            }
    }

#pragma unroll
    for (int i = 0; i < 4; ++i) {
        int grow = m0 + i * 16 + lrow;
        if (grow >= M) continue;
        float* crow = C + (size_t)grow * N;
#pragma unroll
        for (int j = 0; j < 4; ++j) {
            int gc = n0 + j * 16 + kgrp * 4;
            if (gc + 4 <= N) {
                float4 bv = *(const float4*)(bias + gc);
                *(float4*)(crow + gc) = make_float4(acc[i][j][0] + bv.x,
                                                    acc[i][j][1] + bv.y,
                                                    acc[i][j][2] + bv.z,
                                                    acc[i][j][3] + bv.w);
            }
        }
    }
}

// ---------------- launch ----------------
// d_out (400 MB) scratch (all dead before final GEMM):
//   hbf[N,128]bf16 | h1bf[N,128]bf16 | h2bf[N,64]bf16 | csr_src[E] | offs |
//   cursor | deg_cnt | bsums
// d_ws (~27 MB): dinv | Wfc hi/lo | W1bf | W2bf | h2hi | h2lo
// (h2hi/h2lo survive the final GEMM's d_out writes.)

extern "C" void kernel_launch(void* const* d_in, const int* in_sizes, int n_in,
                              void* d_out, int out_size, void* d_ws, size_t ws_size,
                              hipStream_t stream)
{
    const float* x   = (const float*)d_in[0];
    const float* W1  = (const float*)d_in[1];
    const float* b1  = (const float*)d_in[2];
    const float* W2  = (const float*)d_in[3];
    const float* b2  = (const float*)d_in[4];
    const float* Wfc = (const float*)d_in[5];
    const float* bfc = (const float*)d_in[6];
    const int*   ei  = (const int*)d_in[7];     // int32 in the harness

    const int Nn = in_sizes[0] / 128;      // 100000 nodes
    const int E  = in_sizes[7] / 2;        // 1600000 edges
    const int* src = ei;
    const int* dst = ei + E;

    char* ws = (char*)d_ws;
    float*          dinv   = (float*)(ws);
    unsigned short* Wfc_hi = (unsigned short*)(ws + 512 * 1024);
    unsigned short* Wfc_lo = (unsigned short*)(ws + 768 * 1024);
    unsigned short* W1_bf  = (unsigned short*)(ws + 1024 * 1024);   // 32 KB
    unsigned short* W2_bf  = (unsigned short*)(ws + 1088 * 1024);   // 16 KB
    unsigned short* h2hi   = (unsigned short*)(ws + 1152 * 1024);
    unsigned short* h2lo   = (unsigned short*)(ws + 1152 * 1024 + (size_t)Nn * 64 * 2);

    char* ob = (char*)d_out;
    unsigned short* hbf     = (unsigned short*)ob;                       // Nn*128 bf16
    unsigned short* h1bf    = (unsigned short*)(ob + (size_t)Nn * 256);  // Nn*128 bf16
    unsigned short* h2bf    = (unsigned short*)(ob + (size_t)Nn * 512);  // Nn*64 bf16
    int*            csr_src = (int*)(ob + (size_t)Nn * 640);             // E ints
    int*            offs    = (int*)((char*)csr_src + (size_t)E * 4);
    int*            cursor  = (int*)((char*)offs + (size_t)Nn * 4);
    int*            deg_cnt = (int*)((char*)cursor + (size_t)Nn * 4);
    int*            bsums   = (int*)((char*)deg_cnt + (size_t)Nn * 4);

    const int nScanBlocks = (Nn + SCAN_B - 1) / SCAN_B;

    // ---- setup: degree, dinv, CSR, weight conversion ----
    k_zero_i<<<128, 256, 0, stream>>>(deg_cnt, Nn);
    k_deg_i<<<(E + 255) / 256, 256, 0, stream>>>(dst, deg_cnt, E);
    k_dinv<<<(Nn + 255) / 256, 256, 0, stream>>>(deg_cnt, dinv, Nn);
    k_scan1<<<nScanBlocks, SCAN_B, 0, stream>>>(deg_cnt, offs, bsums, Nn);
    k_scan2<<<1, 128, 0, stream>>>(bsums, nScanBlocks);
    k_scan3<<<nScanBlocks, SCAN_B, 0, stream>>>(offs, cursor, bsums, Nn);
    k_fill<<<(E + 255) / 256, 256, 0, stream>>>(src, dst, cursor, csr_src, E);
    k_conv_w_bf<<<128, 128, 0, stream>>>(W1, W1_bf, 128, 128);
    k_conv_w_bf<<<64, 128, 0, stream>>>(W2, W2_bf, 128, 64);
    k_conv_w<<<1000, 64, 0, stream>>>(Wfc, Wfc_hi, Wfc_lo, 64, 1000);

    // ---- layer 1: hbf = bf16(x @ W1), pure bf16 ----
    gemm_mfma_l1<<<dim3((Nn + 127) / 128, 1), 256, 0, stream>>>(x, W1_bf, hbf, Nn);
    // h1bf = relu(gather(hbf)+self+b1), bf16 out
    k_gather128<<<(Nn + 3) / 4, 256, 0, stream>>>(hbf, csr_src, offs, dinv, b1,
                                                  h1bf, Nn, E);

    // ---- layer 2: h2bf = bf16(h1 @ W2), pure bf16 ----
    gemm_mfma_l2<<<dim3((Nn + 127) / 128, 1), 256, 0, stream>>>(h1bf, W2_bf, h2bf, Nn);
    // h2 = relu(gather(h2bf)+self+b2) -> split hi/lo (feeds final GEMM)
    k_gather64<<<(Nn + 3) / 4, 256, 0, stream>>>(h2bf, csr_src, offs, dinv, b2,
                                                 h2hi, h2lo, Nn, E);

    // ---- output layer: out = h2 @ Wfc + bfc (3-term split, grid N-fast) ----
    gemm_mfma_out<<<dim3((1000 + 127) / 128, (Nn + 127) / 128), 256, 0, stream>>>(
        h2hi, h2lo, Wfc_hi, Wfc_lo, bfc, (float*)d_out, Nn, 1000);
}

// Round 14
// 523.933 us; speedup vs baseline: 1.4377x; 1.0098x over previous
//
#include <hip/hip_runtime.h>
#include <hip/hip_bf16.h>
#include <cstddef>

typedef __attribute__((ext_vector_type(8))) short bf16x8;
typedef __attribute__((ext_vector_type(4))) float f32x4;

__device__ __forceinline__ unsigned short f2bf(float f) {
    __hip_bfloat16 h = __float2bfloat16(f);
    return __builtin_bit_cast(unsigned short, h);
}
__device__ __forceinline__ float bf2f(unsigned short u) {
    return __bfloat162float(__builtin_bit_cast(__hip_bfloat16, u));
}
__device__ __forceinline__ float bflo(unsigned u) {
    return __builtin_bit_cast(float, u << 16);
}
__device__ __forceinline__ float bfhi(unsigned u) {
    return __builtin_bit_cast(float, u & 0xffff0000u);
}

// ---------------- zero fill ----------------

__global__ void k_zero_i(int* __restrict__ p, int total) {
    int i = blockIdx.x * blockDim.x + threadIdx.x;
    int stride = gridDim.x * blockDim.x;
    for (; i < total; i += stride) p[i] = 0;
}

// ---------------- degree ----------------

__global__ void k_deg_i(const int* __restrict__ dst, int* __restrict__ deg, int E) {
    int e = blockIdx.x * blockDim.x + threadIdx.x;
    if (e < E) atomicAdd(&deg[dst[e]], 1);
}

// ---------------- exclusive scan (dinv fused into scan1) ----------------

#define SCAN_B 1024

__global__ void k_scan1(const int* __restrict__ in, int* __restrict__ out,
                        int* __restrict__ sums, float* __restrict__ dinv, int n) {
    __shared__ int tmp[SCAN_B];
    int tid = threadIdx.x;
    int gid = blockIdx.x * SCAN_B + tid;
    int v = (gid < n) ? in[gid] : 0;
    if (gid < n) dinv[gid] = rsqrtf((float)v + 1.0f);
    tmp[tid] = v;
    __syncthreads();
    for (int off = 1; off < SCAN_B; off <<= 1) {
        int t = (tid >= off) ? tmp[tid - off] : 0;
        __syncthreads();
        tmp[tid] += t;
        __syncthreads();
    }
    if (gid < n) out[gid] = tmp[tid] - v;
    if (tid == SCAN_B - 1) sums[blockIdx.x] = tmp[tid];
}

__global__ void k_scan2(int* __restrict__ sums, int nb) {
    __shared__ int tmp[128];
    int tid = threadIdx.x;
    int v = (tid < nb) ? sums[tid] : 0;
    tmp[tid] = v;
    __syncthreads();
    for (int off = 1; off < 128; off <<= 1) {
        int t = (tid >= off) ? tmp[tid - off] : 0;
        __syncthreads();
        tmp[tid] += t;
        __syncthreads();
    }
    if (tid < nb) sums[tid] = tmp[tid] - v;
}

__global__ void k_scan3(int* __restrict__ out, int* __restrict__ cursor,
                        const int* __restrict__ sums, int n) {
    int gid = blockIdx.x * SCAN_B + threadIdx.x;
    if (gid < n) {
        int v = out[gid] + sums[blockIdx.x];
        out[gid] = v;
        cursor[gid] = v;
    }
}

// ---------------- CSR fill ----------------

__global__ void k_fill(const int* __restrict__ src, const int* __restrict__ dst,
                       int* __restrict__ cursor, int* __restrict__ csr_src, int E) {
    int e = blockIdx.x * blockDim.x + threadIdx.x;
    if (e < E) {
        int pos = atomicAdd(&cursor[dst[e]], 1);
        csr_src[pos] = src[e];
    }
}

// ---------------- W [K,N] fp32 -> transposed bf16 [n][K] (single / split) -----

__global__ void k_conv_w_bf(const float* __restrict__ W, unsigned short* __restrict__ Bh,
                            int K, int N)
{
    int n = blockIdx.x;
    int k = threadIdx.x;
    Bh[(size_t)n * K + k] = f2bf(W[(size_t)k * N + n]);
}

__global__ void k_conv_w(const float* __restrict__ W, unsigned short* __restrict__ Bh,
                         unsigned short* __restrict__ Bl, int K, int N)
{
    int n = blockIdx.x;
    int k = threadIdx.x;
    float v = W[(size_t)k * N + n];
    unsigned short hi = f2bf(v);
    unsigned short lo = f2bf(v - bf2f(hi));
    Bh[(size_t)n * K + k] = hi;
    Bl[(size_t)n * K + k] = lo;
}

// ---------------- gather F=128, bf16 in -> bf16 out --------------------------
// 16 lanes/edge x uint4, 4 edge-groups/wave, 4-UNROLLED = 16 edges in flight
// (deg~16 -> typical node completes in ONE latency-chained iteration).
// Self-row + bias loads issued BEFORE the loop (latency hidden under it).

__device__ __forceinline__ void unpack_fma(float* a, float w, uint4 v) {
    a[0] = fmaf(w, bflo(v.x), a[0]);
    a[1] = fmaf(w, bfhi(v.x), a[1]);
    a[2] = fmaf(w, bflo(v.y), a[2]);
    a[3] = fmaf(w, bfhi(v.y), a[3]);
    a[4] = fmaf(w, bflo(v.z), a[4]);
    a[5] = fmaf(w, bfhi(v.z), a[5]);
    a[6] = fmaf(w, bflo(v.w), a[6]);
    a[7] = fmaf(w, bfhi(v.w), a[7]);
}

__launch_bounds__(256)
__global__ void k_gather128(const unsigned short* __restrict__ hbf,
                            const int* __restrict__ csr_src, const int* __restrict__ off,
                            const float* __restrict__ dinv, const float* __restrict__ bias,
                            unsigned short* __restrict__ obf, int N, int E)
{
    int node = blockIdx.x * 4 + (threadIdx.x >> 6);
    int lane = threadIdx.x & 63;
    if (node >= N) return;
    float dn = dinv[node];
    int beg = off[node];
    int end = (node + 1 < N) ? off[node + 1] : E;

    const int grp = lane >> 4;          // 4 groups
    const int sub = lane & 15;          // 16 lanes x 8 bf16 = 128 elems

    // early self/bias loads (used only by grp 0 at the end)
    uint4 sv = make_uint4(0, 0, 0, 0);
    float4 b0 = make_float4(0.f, 0.f, 0.f, 0.f), b1 = b0;
    if (grp == 0) {
        sv = *(const uint4*)(hbf + (size_t)node * 128 + sub * 8);
        b0 = *(const float4*)(bias + sub * 8);
        b1 = *(const float4*)(bias + sub * 8 + 4);
    }

    float a[8] = {0.f, 0.f, 0.f, 0.f, 0.f, 0.f, 0.f, 0.f};
    int i = beg + grp;
    for (; i + 12 < end; i += 16) {
        int s0 = csr_src[i];
        int s1 = csr_src[i + 4];
        int s2 = csr_src[i + 8];
        int s3 = csr_src[i + 12];
        float w0 = dinv[s0] * dn;
        float w1 = dinv[s1] * dn;
        float w2 = dinv[s2] * dn;
        float w3 = dinv[s3] * dn;
        uint4 v0 = *(const uint4*)(hbf + (size_t)s0 * 128 + sub * 8);
        uint4 v1 = *(const uint4*)(hbf + (size_t)s1 * 128 + sub * 8);
        uint4 v2 = *(const uint4*)(hbf + (size_t)s2 * 128 + sub * 8);
        uint4 v3 = *(const uint4*)(hbf + (size_t)s3 * 128 + sub * 8);
        unpack_fma(a, w0, v0);
        unpack_fma(a, w1, v1);
        unpack_fma(a, w2, v2);
        unpack_fma(a, w3, v3);
    }
    for (; i < end; i += 4) {
        int s = csr_src[i];
        float w = dinv[s] * dn;
        uint4 v = *(const uint4*)(hbf + (size_t)s * 128 + sub * 8);
        unpack_fma(a, w, v);
    }

#pragma unroll
    for (int k = 0; k < 8; ++k) {
        a[k] += __shfl_xor(a[k], 16);
        a[k] += __shfl_xor(a[k], 32);
    }

    if (grp == 0) {
        float s[8] = {bflo(sv.x), bfhi(sv.x), bflo(sv.y), bfhi(sv.y),
                      bflo(sv.z), bfhi(sv.z), bflo(sv.w), bfhi(sv.w)};
        float bv[8] = {b0.x, b0.y, b0.z, b0.w, b1.x, b1.y, b1.z, b1.w};
        float w = dn * dn;
        unsigned short o[8];
#pragma unroll
        for (int k = 0; k < 8; ++k)
            o[k] = f2bf(fmaxf(fmaf(s[k], w, a[k]) + bv[k], 0.f));
        uint4 vo;
        vo.x = (unsigned)o[0] | ((unsigned)o[1] << 16);
        vo.y = (unsigned)o[2] | ((unsigned)o[3] << 16);
        vo.z = (unsigned)o[4] | ((unsigned)o[5] << 16);
        vo.w = (unsigned)o[6] | ((unsigned)o[7] << 16);
        *(uint4*)(obf + (size_t)node * 128 + sub * 8) = vo;
    }
}

// ---------------- gather F=64, bf16 in -> split hi/lo out ---------------------
// 8 lanes/edge, 8 edge-groups, 2-unrolled = 16 edges in flight.

__launch_bounds__(256)
__global__ void k_gather64(const unsigned short* __restrict__ hbf,
                           const int* __restrict__ csr_src, const int* __restrict__ off,
                           const float* __restrict__ dinv, const float* __restrict__ bias,
                           unsigned short* __restrict__ hhi, unsigned short* __restrict__ hlo,
                           int N, int E)
{
    int node = blockIdx.x * 4 + (threadIdx.x >> 6);
    int lane = threadIdx.x & 63;
    if (node >= N) return;
    float dn = dinv[node];
    int beg = off[node];
    int end = (node + 1 < N) ? off[node + 1] : E;

    const int grp = lane >> 3;          // 8 groups
    const int sub = lane & 7;           // 8 lanes x 8 bf16 = 64 elems

    uint4 sv = make_uint4(0, 0, 0, 0);
    float4 b0 = make_float4(0.f, 0.f, 0.f, 0.f), b1 = b0;
    if (grp == 0) {
        sv = *(const uint4*)(hbf + (size_t)node * 64 + sub * 8);
        b0 = *(const float4*)(bias + sub * 8);
        b1 = *(const float4*)(bias + sub * 8 + 4);
    }

    float a[8] = {0.f, 0.f, 0.f, 0.f, 0.f, 0.f, 0.f, 0.f};
    int i = beg + grp;
    for (; i + 8 < end; i += 16) {
        int s0 = csr_src[i];
        int s1 = csr_src[i + 8];
        float w0 = dinv[s0] * dn;
        float w1 = dinv[s1] * dn;
        uint4 v0 = *(const uint4*)(hbf + (size_t)s0 * 64 + sub * 8);
        uint4 v1 = *(const uint4*)(hbf + (size_t)s1 * 64 + sub * 8);
        unpack_fma(a, w0, v0);
        unpack_fma(a, w1, v1);
    }
    if (i < end) {
        int s = csr_src[i];
        float w = dinv[s] * dn;
        uint4 v = *(const uint4*)(hbf + (size_t)s * 64 + sub * 8);
        unpack_fma(a, w, v);
    }

#pragma unroll
    for (int k = 0; k < 8; ++k) {
        a[k] += __shfl_xor(a[k], 8);
        a[k] += __shfl_xor(a[k], 16);
        a[k] += __shfl_xor(a[k], 32);
    }

    if (grp == 0) {
        float s[8] = {bflo(sv.x), bfhi(sv.x), bflo(sv.y), bfhi(sv.y),
                      bflo(sv.z), bfhi(sv.z), bflo(sv.w), bfhi(sv.w)};
        float bv[8] = {b0.x, b0.y, b0.z, b0.w, b1.x, b1.y, b1.z, b1.w};
        float w = dn * dn;
        unsigned short hi[8], lo[8];
#pragma unroll
        for (int k = 0; k < 8; ++k) {
            float f = fmaxf(fmaf(s[k], w, a[k]) + bv[k], 0.f);
            hi[k] = f2bf(f);
            lo[k] = f2bf(f - bf2f(hi[k]));
        }
        uint4 vh, vl;
        vh.x = (unsigned)hi[0] | ((unsigned)hi[1] << 16);
        vh.y = (unsigned)hi[2] | ((unsigned)hi[3] << 16);
        vh.z = (unsigned)hi[4] | ((unsigned)hi[5] << 16);
        vh.w = (unsigned)hi[6] | ((unsigned)hi[7] << 16);
        vl.x = (unsigned)lo[0] | ((unsigned)lo[1] << 16);
        vl.y = (unsigned)lo[2] | ((unsigned)lo[3] << 16);
        vl.z = (unsigned)lo[4] | ((unsigned)lo[5] << 16);
        vl.w = (unsigned)lo[6] | ((unsigned)lo[7] << 16);
        *(uint4*)(hhi + (size_t)node * 64 + sub * 8) = vh;
        *(uint4*)(hlo + (size_t)node * 64 + sub * 8) = vl;
    }
}

// ---------------- layer-1 GEMM, pure bf16 ----------------

__launch_bounds__(256, 2)
__global__ void gemm_mfma_l1(const float* __restrict__ A,
                             const unsigned short* __restrict__ Bt,
                             unsigned short* __restrict__ Cbf, int M)
{
    __shared__ unsigned short Ah[128 * 64];
    __shared__ unsigned short Bh[128 * 64];

    const int tid = threadIdx.x;
    const int m0 = blockIdx.x * 128;
    const int lane = tid & 63, wave = tid >> 6;
    const int wr = wave >> 1, wc = wave & 1;
    const int lrow = lane & 15, kgrp = lane >> 4;

    f32x4 acc[4][4] = {};

    for (int ph = 0; ph < 2; ++ph) {
        const int k0 = ph * 64;
        __syncthreads();
        {
            const int c4 = tid & 15, r0 = tid >> 4;
#pragma unroll
            for (int p = 0; p < 8; ++p) {
                int row = r0 + p * 16;
                int gr = m0 + row; if (gr >= M) gr = M - 1;
                float4 v = *(const float4*)(A + (size_t)gr * 128 + k0 + c4 * 4);
                ushort4 hv;
                hv.x = f2bf(v.x); hv.y = f2bf(v.y); hv.z = f2bf(v.z); hv.w = f2bf(v.w);
                *(ushort4*)((char*)Ah + row * 128 + ((c4 * 8) ^ ((row & 7) << 4))) = hv;
            }
        }
        {
            const int c = tid & 7, col0 = tid >> 3;
#pragma unroll
            for (int p = 0; p < 4; ++p) {
                int col = col0 + p * 32;
                uint4 v = *(const uint4*)(Bt + (size_t)col * 128 + k0 + c * 8);
                *(uint4*)((char*)Bh + col * 128 + ((c * 16) ^ ((col & 7) << 4))) = v;
            }
        }
        __syncthreads();

#pragma unroll
        for (int ks = 0; ks < 2; ++ks) {
            const int cIdx = kgrp + ks * 4;
            bf16x8 ah[4], bh[4];
#pragma unroll
            for (int i = 0; i < 4; ++i) {
                int row = wr * 64 + i * 16 + lrow;
                ah[i] = *(const bf16x8*)((const char*)Ah + row * 128 + ((cIdx * 16) ^ ((row & 7) << 4)));
            }
#pragma unroll
            for (int j = 0; j < 4; ++j) {
                int col = wc * 64 + j * 16 + lrow;
                bh[j] = *(const bf16x8*)((const char*)Bh + col * 128 + ((cIdx * 16) ^ ((col & 7) << 4)));
            }
#pragma unroll
            for (int i = 0; i < 4; ++i)
#pragma unroll
                for (int j = 0; j < 4; ++j)
                    acc[i][j] = __builtin_amdgcn_mfma_f32_16x16x32_bf16(bh[j], ah[i], acc[i][j], 0, 0, 0);
        }
    }

#pragma unroll
    for (int i = 0; i < 4; ++i) {
        int grow = m0 + wr * 64 + i * 16 + lrow;
        if (grow >= M) continue;
        unsigned short* crow = Cbf + (size_t)grow * 128;
#pragma unroll
        for (int j = 0; j < 4; ++j) {
            int gc = wc * 64 + j * 16 + kgrp * 4;
            ushort4 o;
            o.x = f2bf(acc[i][j][0]);
            o.y = f2bf(acc[i][j][1]);
            o.z = f2bf(acc[i][j][2]);
            o.w = f2bf(acc[i][j][3]);
            *(ushort4*)(crow + gc) = o;
        }
    }
}

// ---------------- layer-2 GEMM, pure bf16 ----------------

__launch_bounds__(256, 3)
__global__ void gemm_mfma_l2(const unsigned short* __restrict__ Abf,
                             const unsigned short* __restrict__ Bt,
                             unsigned short* __restrict__ Cbf, int M)
{
    __shared__ unsigned short Ah[128 * 64];
    __shared__ unsigned short Bh[64 * 64];

    const int tid = threadIdx.x;
    const int m0 = blockIdx.x * 128;
    const int lane = tid & 63, wave = tid >> 6;
    const int wr = wave >> 1, wc = wave & 1;
    const int lrow = lane & 15, kgrp = lane >> 4;

    f32x4 acc[4][2] = {};

    for (int ph = 0; ph < 2; ++ph) {
        const int k0 = ph * 64;
        __syncthreads();
        {
            const int c = tid & 7, r0 = tid >> 3;
#pragma unroll
            for (int p = 0; p < 4; ++p) {
                int row = r0 + p * 32;
                int gr = m0 + row; if (gr >= M) gr = M - 1;
                uint4 v = *(const uint4*)(Abf + (size_t)gr * 128 + k0 + c * 8);
                *(uint4*)((char*)Ah + row * 128 + ((c * 16) ^ ((row & 7) << 4))) = v;
            }
        }
        {
            const int c = tid & 7, col0 = tid >> 3;
#pragma unroll
            for (int p = 0; p < 2; ++p) {
                int col = col0 + p * 32;
                uint4 v = *(const uint4*)(Bt + (size_t)col * 128 + k0 + c * 8);
                *(uint4*)((char*)Bh + col * 128 + ((c * 16) ^ ((col & 7) << 4))) = v;
            }
        }
        __syncthreads();

#pragma unroll
        for (int ks = 0; ks < 2; ++ks) {
            const int cIdx = kgrp + ks * 4;
            bf16x8 ah[4], bh[2];
#pragma unroll
            for (int i = 0; i < 4; ++i) {
                int row = wr * 64 + i * 16 + lrow;
                ah[i] = *(const bf16x8*)((const char*)Ah + row * 128 + ((cIdx * 16) ^ ((row & 7) << 4)));
            }
#pragma unroll
            for (int j = 0; j < 2; ++j) {
                int col = wc * 32 + j * 16 + lrow;
                bh[j] = *(const bf16x8*)((const char*)Bh + col * 128 + ((cIdx * 16) ^ ((col & 7) << 4)));
            }
#pragma unroll
            for (int i = 0; i < 4; ++i)
#pragma unroll
                for (int j = 0; j < 2; ++j)
                    acc[i][j] = __builtin_amdgcn_mfma_f32_16x16x32_bf16(bh[j], ah[i], acc[i][j], 0, 0, 0);
        }
    }

#pragma unroll
    for (int i = 0; i < 4; ++i) {
        int grow = m0 + wr * 64 + i * 16 + lrow;
        if (grow >= M) continue;
        unsigned short* crow = Cbf + (size_t)grow * 64;
#pragma unroll
        for (int j = 0; j < 2; ++j) {
            int gc = wc * 32 + j * 16 + kgrp * 4;
            ushort4 o;
            o.x = f2bf(acc[i][j][0]);
            o.y = f2bf(acc[i][j][1]);
            o.z = f2bf(acc[i][j][2]);
            o.w = f2bf(acc[i][j][3]);
            *(ushort4*)(crow + gc) = o;
        }
    }
}

// ---------------- output MFMA GEMM, no LDS, 3-term, higher occupancy ----------

__launch_bounds__(256, 3)
__global__ void gemm_mfma_out(const unsigned short* __restrict__ Ahi,
                              const unsigned short* __restrict__ Alo,
                              const unsigned short* __restrict__ Bhi,
                              const unsigned short* __restrict__ Blo,
                              const float* __restrict__ bias, float* __restrict__ C,
                              int M, int N)
{
    const int tid = threadIdx.x;
    const int lane = tid & 63, wave = tid >> 6;
    const int wr = wave >> 1, wc = wave & 1;
    const int m0 = blockIdx.y * 128 + wr * 64;
    const int n0 = blockIdx.x * 128 + wc * 64;
    const int lrow = lane & 15, kgrp = lane >> 4;

    f32x4 acc[4][4] = {};

#pragma unroll
    for (int ks = 0; ks < 2; ++ks) {
        const int koff = (kgrp + ks * 4) * 8;
        bf16x8 ah[4], al[4], bh[4], bl[4];
#pragma unroll
        for (int i = 0; i < 4; ++i) {
            int row = m0 + i * 16 + lrow; if (row >= M) row = M - 1;
            ah[i] = *(const bf16x8*)(Ahi + (size_t)row * 64 + koff);
            al[i] = *(const bf16x8*)(Alo + (size_t)row * 64 + koff);
        }
#pragma unroll
        for (int j = 0; j < 4; ++j) {
            int col = n0 + j * 16 + lrow; if (col >= N) col = N - 1;
            bh[j] = *(const bf16x8*)(Bhi + (size_t)col * 64 + koff);
            bl[j] = *(const bf16x8*)(Blo + (size_t)col * 64 + koff);
        }
#pragma unroll
        for (int i = 0; i < 4; ++i)
#pragma unroll
            for (int j = 0; j < 4; ++j) {
                acc[i][j] = __builtin_amdgcn_mfma_f32_16x16x32_bf16(bh[j], ah[i], acc[i][j], 0, 0, 0);
                acc[i][j] = __builtin_amdgcn_mfma_f32_16x16x32_bf16(bl[j], ah[i], acc[i][j], 0, 0, 0);
                acc[i][j] = __builtin_amdgcn_mfma_f32_16x16x32_bf16(bh[j], al[i], acc[i][j], 0, 0, 0);
            }
    }

#pragma unroll
    for (int i = 0; i < 4; ++i) {
        int grow = m0 + i * 16 + lrow;
        if (grow >= M) continue;
        float* crow = C + (size_t)grow * N;
#pragma unroll
        for (int j = 0; j < 4; ++j) {
            int gc = n0 + j * 16 + kgrp * 4;
            if (gc + 4 <= N) {
                float4 bv = *(const float4*)(bias + gc);
                *(float4*)(crow + gc) = make_float4(acc[i][j][0] + bv.x,
                                                    acc[i][j][1] + bv.y,
                                                    acc[i][j][2] + bv.z,
                                                    acc[i][j][3] + bv.w);
            }
        }
    }
}

// ---------------- launch ----------------
// d_out (400 MB) scratch (all dead before final GEMM):
//   hbf[N,128]bf16 | h1bf[N,128]bf16 | h2bf[N,64]bf16 | csr_src[E] | offs |
//   cursor | deg_cnt | bsums
// d_ws (~27 MB): dinv | Wfc hi/lo | W1bf | W2bf | h2hi | h2lo

extern "C" void kernel_launch(void* const* d_in, const int* in_sizes, int n_in,
                              void* d_out, int out_size, void* d_ws, size_t ws_size,
                              hipStream_t stream)
{
    const float* x   = (const float*)d_in[0];
    const float* W1  = (const float*)d_in[1];
    const float* b1  = (const float*)d_in[2];
    const float* W2  = (const float*)d_in[3];
    const float* b2  = (const float*)d_in[4];
    const float* Wfc = (const float*)d_in[5];
    const float* bfc = (const float*)d_in[6];
    const int*   ei  = (const int*)d_in[7];     // int32 in the harness

    const int Nn = in_sizes[0] / 128;      // 100000 nodes
    const int E  = in_sizes[7] / 2;        // 1600000 edges
    const int* src = ei;
    const int* dst = ei + E;

    char* ws = (char*)d_ws;
    float*          dinv   = (float*)(ws);
    unsigned short* Wfc_hi = (unsigned short*)(ws + 512 * 1024);
    unsigned short* Wfc_lo = (unsigned short*)(ws + 768 * 1024);
    unsigned short* W1_bf  = (unsigned short*)(ws + 1024 * 1024);
    unsigned short* W2_bf  = (unsigned short*)(ws + 1088 * 1024);
    unsigned short* h2hi   = (unsigned short*)(ws + 1152 * 1024);
    unsigned short* h2lo   = (unsigned short*)(ws + 1152 * 1024 + (size_t)Nn * 64 * 2);

    char* ob = (char*)d_out;
    unsigned short* hbf     = (unsigned short*)ob;                       // Nn*128 bf16
    unsigned short* h1bf    = (unsigned short*)(ob + (size_t)Nn * 256);  // Nn*128 bf16
    unsigned short* h2bf    = (unsigned short*)(ob + (size_t)Nn * 512);  // Nn*64 bf16
    int*            csr_src = (int*)(ob + (size_t)Nn * 640);             // E ints
    int*            offs    = (int*)((char*)csr_src + (size_t)E * 4);
    int*            cursor  = (int*)((char*)offs + (size_t)Nn * 4);
    int*            deg_cnt = (int*)((char*)cursor + (size_t)Nn * 4);
    int*            bsums   = (int*)((char*)deg_cnt + (size_t)Nn * 4);

    const int nScanBlocks = (Nn + SCAN_B - 1) / SCAN_B;

    // ---- setup: degree, dinv(+scan1), CSR, weight conversion ----
    k_zero_i<<<128, 256, 0, stream>>>(deg_cnt, Nn);
    k_deg_i<<<(E + 255) / 256, 256, 0, stream>>>(dst, deg_cnt, E);
    k_scan1<<<nScanBlocks, SCAN_B, 0, stream>>>(deg_cnt, offs, bsums, dinv, Nn);
    k_scan2<<<1, 128, 0, stream>>>(bsums, nScanBlocks);
    k_scan3<<<nScanBlocks, SCAN_B, 0, stream>>>(offs, cursor, bsums, Nn);
    k_fill<<<(E + 255) / 256, 256, 0, stream>>>(src, dst, cursor, csr_src, E);
    k_conv_w_bf<<<128, 128, 0, stream>>>(W1, W1_bf, 128, 128);
    k_conv_w_bf<<<64, 128, 0, stream>>>(W2, W2_bf, 128, 64);
    k_conv_w<<<1000, 64, 0, stream>>>(Wfc, Wfc_hi, Wfc_lo, 64, 1000);

    // ---- layer 1: hbf = bf16(x @ W1) ----
    gemm_mfma_l1<<<dim3((Nn + 127) / 128, 1), 256, 0, stream>>>(x, W1_bf, hbf, Nn);
    k_gather128<<<(Nn + 3) / 4, 256, 0, stream>>>(hbf, csr_src, offs, dinv, b1,
                                                  h1bf, Nn, E);

    // ---- layer 2: h2bf = bf16(h1 @ W2) ----
    gemm_mfma_l2<<<dim3((Nn + 127) / 128, 1), 256, 0, stream>>>(h1bf, W2_bf, h2bf, Nn);
    k_gather64<<<(Nn + 3) / 4, 256, 0, stream>>>(h2bf, csr_src, offs, dinv, b2,
                                                 h2hi, h2lo, Nn, E);

    // ---- output layer: out = h2 @ Wfc + bfc ----
    gemm_mfma_out<<<dim3((1000 + 127) / 128, (Nn + 127) / 128), 256, 0, stream>>>(
        h2hi, h2lo, Wfc_hi, Wfc_lo, bfc, (float*)d_out, Nn, 1000);
}

// Round 15
// 505.468 us; speedup vs baseline: 1.4902x; 1.0365x over previous
//
#include <hip/hip_runtime.h>
#include <hip/hip_bf16.h>
#include <cstddef>

typedef __attribute__((ext_vector_type(8))) short bf16x8;
typedef __attribute__((ext_vector_type(4))) float f32x4;

__device__ __forceinline__ unsigned short f2bf(float f) {
    __hip_bfloat16 h = __float2bfloat16(f);
    return __builtin_bit_cast(unsigned short, h);
}
__device__ __forceinline__ float bf2f(unsigned short u) {
    return __bfloat162float(__builtin_bit_cast(__hip_bfloat16, u));
}
__device__ __forceinline__ float bflo(unsigned u) {
    return __builtin_bit_cast(float, u << 16);
}
__device__ __forceinline__ float bfhi(unsigned u) {
    return __builtin_bit_cast(float, u & 0xffff0000u);
}

// ---------------- zero fill ----------------

__global__ void k_zero_i(int* __restrict__ p, int total) {
    int i = blockIdx.x * blockDim.x + threadIdx.x;
    int stride = gridDim.x * blockDim.x;
    for (; i < total; i += stride) p[i] = 0;
}

// ---------------- degree ----------------

__global__ void k_deg_i(const int* __restrict__ dst, int* __restrict__ deg, int E) {
    int e = blockIdx.x * blockDim.x + threadIdx.x;
    if (e < E) atomicAdd(&deg[dst[e]], 1);
}

// ---------------- exclusive scan (dinv fused into scan1) ----------------

#define SCAN_B 1024

__global__ void k_scan1(const int* __restrict__ in, int* __restrict__ out,
                        int* __restrict__ sums, float* __restrict__ dinv, int n) {
    __shared__ int tmp[SCAN_B];
    int tid = threadIdx.x;
    int gid = blockIdx.x * SCAN_B + tid;
    int v = (gid < n) ? in[gid] : 0;
    if (gid < n) dinv[gid] = rsqrtf((float)v + 1.0f);
    tmp[tid] = v;
    __syncthreads();
    for (int off = 1; off < SCAN_B; off <<= 1) {
        int t = (tid >= off) ? tmp[tid - off] : 0;
        __syncthreads();
        tmp[tid] += t;
        __syncthreads();
    }
    if (gid < n) out[gid] = tmp[tid] - v;
    if (tid == SCAN_B - 1) sums[blockIdx.x] = tmp[tid];
}

__global__ void k_scan2(int* __restrict__ sums, int nb) {
    __shared__ int tmp[128];
    int tid = threadIdx.x;
    int v = (tid < nb) ? sums[tid] : 0;
    tmp[tid] = v;
    __syncthreads();
    for (int off = 1; off < 128; off <<= 1) {
        int t = (tid >= off) ? tmp[tid - off] : 0;
        __syncthreads();
        tmp[tid] += t;
        __syncthreads();
    }
    if (tid < nb) sums[tid] = tmp[tid] - v;
}

__global__ void k_scan3(int* __restrict__ out, int* __restrict__ cursor,
                        const int* __restrict__ sums, int n) {
    int gid = blockIdx.x * SCAN_B + threadIdx.x;
    if (gid < n) {
        int v = out[gid] + sums[blockIdx.x];
        out[gid] = v;
        cursor[gid] = v;
    }
}

// ---------------- CSR fill ----------------

__global__ void k_fill(const int* __restrict__ src, const int* __restrict__ dst,
                       int* __restrict__ cursor, int* __restrict__ csr_src, int E) {
    int e = blockIdx.x * blockDim.x + threadIdx.x;
    if (e < E) {
        int pos = atomicAdd(&cursor[dst[e]], 1);
        csr_src[pos] = src[e];
    }
}

// ---------------- all weight conversions in one launch ----------------
// b<128: W1 col b -> W1bf[b][128]; b<192: W2 col -> W2bf[n][128];
// else: Wfc col -> split hi/lo [n][64].

__global__ void k_conv_all(const float* __restrict__ W1, const float* __restrict__ W2,
                           const float* __restrict__ Wfc,
                           unsigned short* __restrict__ W1bf, unsigned short* __restrict__ W2bf,
                           unsigned short* __restrict__ Wfch, unsigned short* __restrict__ Wfcl)
{
    int b = blockIdx.x;
    int k = threadIdx.x;                 // 128 threads
    if (b < 128) {
        W1bf[(size_t)b * 128 + k] = f2bf(W1[(size_t)k * 128 + b]);
    } else if (b < 192) {
        int n = b - 128;
        W2bf[(size_t)n * 128 + k] = f2bf(W2[(size_t)k * 64 + n]);
    } else {
        int n = b - 192;                 // 0..999
        if (k < 64) {
            float v = Wfc[(size_t)k * 1000 + n];
            unsigned short hi = f2bf(v);
            Wfch[(size_t)n * 64 + k] = hi;
            Wfcl[(size_t)n * 64 + k] = f2bf(v - bf2f(hi));
        }
    }
}

// ---------------- gather F=128, bf16 in -> bf16 out --------------------------

__device__ __forceinline__ void unpack_fma(float* a, float w, uint4 v) {
    a[0] = fmaf(w, bflo(v.x), a[0]);
    a[1] = fmaf(w, bfhi(v.x), a[1]);
    a[2] = fmaf(w, bflo(v.y), a[2]);
    a[3] = fmaf(w, bfhi(v.y), a[3]);
    a[4] = fmaf(w, bflo(v.z), a[4]);
    a[5] = fmaf(w, bfhi(v.z), a[5]);
    a[6] = fmaf(w, bflo(v.w), a[6]);
    a[7] = fmaf(w, bfhi(v.w), a[7]);
}

__launch_bounds__(256)
__global__ void k_gather128(const unsigned short* __restrict__ hbf,
                            const int* __restrict__ csr_src, const int* __restrict__ off,
                            const float* __restrict__ dinv, const float* __restrict__ bias,
                            unsigned short* __restrict__ obf, int N, int E)
{
    int node = blockIdx.x * 4 + (threadIdx.x >> 6);
    int lane = threadIdx.x & 63;
    if (node >= N) return;
    float dn = dinv[node];
    int beg = off[node];
    int end = (node + 1 < N) ? off[node + 1] : E;

    const int grp = lane >> 4;
    const int sub = lane & 15;

    uint4 sv = make_uint4(0, 0, 0, 0);
    float4 b0 = make_float4(0.f, 0.f, 0.f, 0.f), b1 = b0;
    if (grp == 0) {
        sv = *(const uint4*)(hbf + (size_t)node * 128 + sub * 8);
        b0 = *(const float4*)(bias + sub * 8);
        b1 = *(const float4*)(bias + sub * 8 + 4);
    }

    float a[8] = {0.f, 0.f, 0.f, 0.f, 0.f, 0.f, 0.f, 0.f};
    int i = beg + grp;
    for (; i + 12 < end; i += 16) {
        int s0 = csr_src[i];
        int s1 = csr_src[i + 4];
        int s2 = csr_src[i + 8];
        int s3 = csr_src[i + 12];
        float w0 = dinv[s0] * dn;
        float w1 = dinv[s1] * dn;
        float w2 = dinv[s2] * dn;
        float w3 = dinv[s3] * dn;
        uint4 v0 = *(const uint4*)(hbf + (size_t)s0 * 128 + sub * 8);
        uint4 v1 = *(const uint4*)(hbf + (size_t)s1 * 128 + sub * 8);
        uint4 v2 = *(const uint4*)(hbf + (size_t)s2 * 128 + sub * 8);
        uint4 v3 = *(const uint4*)(hbf + (size_t)s3 * 128 + sub * 8);
        unpack_fma(a, w0, v0);
        unpack_fma(a, w1, v1);
        unpack_fma(a, w2, v2);
        unpack_fma(a, w3, v3);
    }
    for (; i < end; i += 4) {
        int s = csr_src[i];
        float w = dinv[s] * dn;
        uint4 v = *(const uint4*)(hbf + (size_t)s * 128 + sub * 8);
        unpack_fma(a, w, v);
    }

#pragma unroll
    for (int k = 0; k < 8; ++k) {
        a[k] += __shfl_xor(a[k], 16);
        a[k] += __shfl_xor(a[k], 32);
    }

    if (grp == 0) {
        float s[8] = {bflo(sv.x), bfhi(sv.x), bflo(sv.y), bfhi(sv.y),
                      bflo(sv.z), bfhi(sv.z), bflo(sv.w), bfhi(sv.w)};
        float bv[8] = {b0.x, b0.y, b0.z, b0.w, b1.x, b1.y, b1.z, b1.w};
        float w = dn * dn;
        unsigned short o[8];
#pragma unroll
        for (int k = 0; k < 8; ++k)
            o[k] = f2bf(fmaxf(fmaf(s[k], w, a[k]) + bv[k], 0.f));
        uint4 vo;
        vo.x = (unsigned)o[0] | ((unsigned)o[1] << 16);
        vo.y = (unsigned)o[2] | ((unsigned)o[3] << 16);
        vo.z = (unsigned)o[4] | ((unsigned)o[5] << 16);
        vo.w = (unsigned)o[6] | ((unsigned)o[7] << 16);
        *(uint4*)(obf + (size_t)node * 128 + sub * 8) = vo;
    }
}

// ---------------- gather F=64, bf16 in -> split hi/lo out ---------------------

__launch_bounds__(256)
__global__ void k_gather64(const unsigned short* __restrict__ hbf,
                           const int* __restrict__ csr_src, const int* __restrict__ off,
                           const float* __restrict__ dinv, const float* __restrict__ bias,
                           unsigned short* __restrict__ hhi, unsigned short* __restrict__ hlo,
                           int N, int E)
{
    int node = blockIdx.x * 4 + (threadIdx.x >> 6);
    int lane = threadIdx.x & 63;
    if (node >= N) return;
    float dn = dinv[node];
    int beg = off[node];
    int end = (node + 1 < N) ? off[node + 1] : E;

    const int grp = lane >> 3;
    const int sub = lane & 7;

    uint4 sv = make_uint4(0, 0, 0, 0);
    float4 b0 = make_float4(0.f, 0.f, 0.f, 0.f), b1 = b0;
    if (grp == 0) {
        sv = *(const uint4*)(hbf + (size_t)node * 64 + sub * 8);
        b0 = *(const float4*)(bias + sub * 8);
        b1 = *(const float4*)(bias + sub * 8 + 4);
    }

    float a[8] = {0.f, 0.f, 0.f, 0.f, 0.f, 0.f, 0.f, 0.f};
    int i = beg + grp;
    for (; i + 8 < end; i += 16) {
        int s0 = csr_src[i];
        int s1 = csr_src[i + 8];
        float w0 = dinv[s0] * dn;
        float w1 = dinv[s1] * dn;
        uint4 v0 = *(const uint4*)(hbf + (size_t)s0 * 64 + sub * 8);
        uint4 v1 = *(const uint4*)(hbf + (size_t)s1 * 64 + sub * 8);
        unpack_fma(a, w0, v0);
        unpack_fma(a, w1, v1);
    }
    if (i < end) {
        int s = csr_src[i];
        float w = dinv[s] * dn;
        uint4 v = *(const uint4*)(hbf + (size_t)s * 64 + sub * 8);
        unpack_fma(a, w, v);
    }

#pragma unroll
    for (int k = 0; k < 8; ++k) {
        a[k] += __shfl_xor(a[k], 8);
        a[k] += __shfl_xor(a[k], 16);
        a[k] += __shfl_xor(a[k], 32);
    }

    if (grp == 0) {
        float s[8] = {bflo(sv.x), bfhi(sv.x), bflo(sv.y), bfhi(sv.y),
                      bflo(sv.z), bfhi(sv.z), bflo(sv.w), bfhi(sv.w)};
        float bv[8] = {b0.x, b0.y, b0.z, b0.w, b1.x, b1.y, b1.z, b1.w};
        float w = dn * dn;
        unsigned short hi[8], lo[8];
#pragma unroll
        for (int k = 0; k < 8; ++k) {
            float f = fmaxf(fmaf(s[k], w, a[k]) + bv[k], 0.f);
            hi[k] = f2bf(f);
            lo[k] = f2bf(f - bf2f(hi[k]));
        }
        uint4 vh, vl;
        vh.x = (unsigned)hi[0] | ((unsigned)hi[1] << 16);
        vh.y = (unsigned)hi[2] | ((unsigned)hi[3] << 16);
        vh.z = (unsigned)hi[4] | ((unsigned)hi[5] << 16);
        vh.w = (unsigned)hi[6] | ((unsigned)hi[7] << 16);
        vl.x = (unsigned)lo[0] | ((unsigned)lo[1] << 16);
        vl.y = (unsigned)lo[2] | ((unsigned)lo[3] << 16);
        vl.z = (unsigned)lo[4] | ((unsigned)lo[5] << 16);
        vl.w = (unsigned)lo[6] | ((unsigned)lo[7] << 16);
        *(uint4*)(hhi + (size_t)node * 64 + sub * 8) = vh;
        *(uint4*)(hlo + (size_t)node * 64 + sub * 8) = vl;
    }
}

// ---------------- layer-1 GEMM, pure bf16 ----------------

__launch_bounds__(256, 2)
__global__ void gemm_mfma_l1(const float* __restrict__ A,
                             const unsigned short* __restrict__ Bt,
                             unsigned short* __restrict__ Cbf, int M)
{
    __shared__ unsigned short Ah[128 * 64];
    __shared__ unsigned short Bh[128 * 64];

    const int tid = threadIdx.x;
    const int m0 = blockIdx.x * 128;
    const int lane = tid & 63, wave = tid >> 6;
    const int wr = wave >> 1, wc = wave & 1;
    const int lrow = lane & 15, kgrp = lane >> 4;

    f32x4 acc[4][4] = {};

    for (int ph = 0; ph < 2; ++ph) {
        const int k0 = ph * 64;
        __syncthreads();
        {
            const int c4 = tid & 15, r0 = tid >> 4;
#pragma unroll
            for (int p = 0; p < 8; ++p) {
                int row = r0 + p * 16;
                int gr = m0 + row; if (gr >= M) gr = M - 1;
                float4 v = *(const float4*)(A + (size_t)gr * 128 + k0 + c4 * 4);
                ushort4 hv;
                hv.x = f2bf(v.x); hv.y = f2bf(v.y); hv.z = f2bf(v.z); hv.w = f2bf(v.w);
                *(ushort4*)((char*)Ah + row * 128 + ((c4 * 8) ^ ((row & 7) << 4))) = hv;
            }
        }
        {
            const int c = tid & 7, col0 = tid >> 3;
#pragma unroll
            for (int p = 0; p < 4; ++p) {
                int col = col0 + p * 32;
                uint4 v = *(const uint4*)(Bt + (size_t)col * 128 + k0 + c * 8);
                *(uint4*)((char*)Bh + col * 128 + ((c * 16) ^ ((col & 7) << 4))) = v;
            }
        }
        __syncthreads();

#pragma unroll
        for (int ks = 0; ks < 2; ++ks) {
            const int cIdx = kgrp + ks * 4;
            bf16x8 ah[4], bh[4];
#pragma unroll
            for (int i = 0; i < 4; ++i) {
                int row = wr * 64 + i * 16 + lrow;
                ah[i] = *(const bf16x8*)((const char*)Ah + row * 128 + ((cIdx * 16) ^ ((row & 7) << 4)));
            }
#pragma unroll
            for (int j = 0; j < 4; ++j) {
                int col = wc * 64 + j * 16 + lrow;
                bh[j] = *(const bf16x8*)((const char*)Bh + col * 128 + ((cIdx * 16) ^ ((col & 7) << 4)));
            }
#pragma unroll
            for (int i = 0; i < 4; ++i)
#pragma unroll
                for (int j = 0; j < 4; ++j)
                    acc[i][j] = __builtin_amdgcn_mfma_f32_16x16x32_bf16(bh[j], ah[i], acc[i][j], 0, 0, 0);
        }
    }

#pragma unroll
    for (int i = 0; i < 4; ++i) {
        int grow = m0 + wr * 64 + i * 16 + lrow;
        if (grow >= M) continue;
        unsigned short* crow = Cbf + (size_t)grow * 128;
#pragma unroll
        for (int j = 0; j < 4; ++j) {
            int gc = wc * 64 + j * 16 + kgrp * 4;
            ushort4 o;
            o.x = f2bf(acc[i][j][0]);
            o.y = f2bf(acc[i][j][1]);
            o.z = f2bf(acc[i][j][2]);
            o.w = f2bf(acc[i][j][3]);
            *(ushort4*)(crow + gc) = o;
        }
    }
}

// ---------------- layer-2 GEMM, pure bf16 ----------------

__launch_bounds__(256, 3)
__global__ void gemm_mfma_l2(const unsigned short* __restrict__ Abf,
                             const unsigned short* __restrict__ Bt,
                             unsigned short* __restrict__ Cbf, int M)
{
    __shared__ unsigned short Ah[128 * 64];
    __shared__ unsigned short Bh[64 * 64];

    const int tid = threadIdx.x;
    const int m0 = blockIdx.x * 128;
    const int lane = tid & 63, wave = tid >> 6;
    const int wr = wave >> 1, wc = wave & 1;
    const int lrow = lane & 15, kgrp = lane >> 4;

    f32x4 acc[4][2] = {};

    for (int ph = 0; ph < 2; ++ph) {
        const int k0 = ph * 64;
        __syncthreads();
        {
            const int c = tid & 7, r0 = tid >> 3;
#pragma unroll
            for (int p = 0; p < 4; ++p) {
                int row = r0 + p * 32;
                int gr = m0 + row; if (gr >= M) gr = M - 1;
                uint4 v = *(const uint4*)(Abf + (size_t)gr * 128 + k0 + c * 8);
                *(uint4*)((char*)Ah + row * 128 + ((c * 16) ^ ((row & 7) << 4))) = v;
            }
        }
        {
            const int c = tid & 7, col0 = tid >> 3;
#pragma unroll
            for (int p = 0; p < 2; ++p) {
                int col = col0 + p * 32;
                uint4 v = *(const uint4*)(Bt + (size_t)col * 128 + k0 + c * 8);
                *(uint4*)((char*)Bh + col * 128 + ((c * 16) ^ ((col & 7) << 4))) = v;
            }
        }
        __syncthreads();

#pragma unroll
        for (int ks = 0; ks < 2; ++ks) {
            const int cIdx = kgrp + ks * 4;
            bf16x8 ah[4], bh[2];
#pragma unroll
            for (int i = 0; i < 4; ++i) {
                int row = wr * 64 + i * 16 + lrow;
                ah[i] = *(const bf16x8*)((const char*)Ah + row * 128 + ((cIdx * 16) ^ ((row & 7) << 4)));
            }
#pragma unroll
            for (int j = 0; j < 2; ++j) {
                int col = wc * 32 + j * 16 + lrow;
                bh[j] = *(const bf16x8*)((const char*)Bh + col * 128 + ((cIdx * 16) ^ ((col & 7) << 4)));
            }
#pragma unroll
            for (int i = 0; i < 4; ++i)
#pragma unroll
                for (int j = 0; j < 2; ++j)
                    acc[i][j] = __builtin_amdgcn_mfma_f32_16x16x32_bf16(bh[j], ah[i], acc[i][j], 0, 0, 0);
        }
    }

#pragma unroll
    for (int i = 0; i < 4; ++i) {
        int grow = m0 + wr * 64 + i * 16 + lrow;
        if (grow >= M) continue;
        unsigned short* crow = Cbf + (size_t)grow * 64;
#pragma unroll
        for (int j = 0; j < 2; ++j) {
            int gc = wc * 32 + j * 16 + kgrp * 4;
            ushort4 o;
            o.x = f2bf(acc[i][j][0]);
            o.y = f2bf(acc[i][j][1]);
            o.z = f2bf(acc[i][j][2]);
            o.w = f2bf(acc[i][j][3]);
            *(ushort4*)(crow + gc) = o;
        }
    }
}

// ---------------- output MFMA GEMM: LDS-staged B, 2 M-tiles/block ------------
// HYPOTHESIS TEST: R8-R14 never restructured this kernel's load side. B-chunk
// (128 cols x 64k, hi+lo = 32 KB) staged to swizzled LDS ONCE per block;
// fragments then read conflict-free from LDS; only streaming A loads stay
// global. 2 M-tiles per block amortize staging; no barrier between tiles.
// grid = (8 N-chunks, ceil(M/256)).

__launch_bounds__(256, 3)
__global__ void gemm_mfma_out(const unsigned short* __restrict__ Ahi,
                              const unsigned short* __restrict__ Alo,
                              const unsigned short* __restrict__ Bhi,
                              const unsigned short* __restrict__ Blo,
                              const float* __restrict__ bias, float* __restrict__ C,
                              int M, int N)
{
    __shared__ unsigned short Bh[128 * 64], Bl[128 * 64];   // 16 KB each

    const int tid = threadIdx.x;
    const int nbase = blockIdx.x * 128;

    // ---- stage B chunk once (swizzled, same layout as l1/l2) ----
    {
        const int c = tid & 7, col0 = tid >> 3;
#pragma unroll
        for (int p = 0; p < 4; ++p) {
            int col = col0 + p * 32;
            int gcol = nbase + col; if (gcol >= N) gcol = N - 1;
            uint4 v = *(const uint4*)(Bhi + (size_t)gcol * 64 + c * 8);
            uint4 w = *(const uint4*)(Blo + (size_t)gcol * 64 + c * 8);
            int off = col * 128 + ((c * 16) ^ ((col & 7) << 4));
            *(uint4*)((char*)Bh + off) = v;
            *(uint4*)((char*)Bl + off) = w;
        }
    }
    __syncthreads();

    const int lane = tid & 63, wave = tid >> 6;
    const int wr = wave >> 1, wc = wave & 1;
    const int lrow = lane & 15, kgrp = lane >> 4;
    const int n0 = nbase + wc * 64;

#pragma unroll
    for (int mt = 0; mt < 2; ++mt) {
        const int m0 = (blockIdx.y * 2 + mt) * 128 + wr * 64;
        f32x4 acc[4][4] = {};

#pragma unroll
        for (int ks = 0; ks < 2; ++ks) {
            const int cIdx = kgrp + ks * 4;
            const int koff = cIdx * 8;
            bf16x8 ah[4], al[4], bh[4], bl[4];
#pragma unroll
            for (int i = 0; i < 4; ++i) {
                int row = m0 + i * 16 + lrow; if (row >= M) row = M - 1;
                ah[i] = *(const bf16x8*)(Ahi + (size_t)row * 64 + koff);
                al[i] = *(const bf16x8*)(Alo + (size_t)row * 64 + koff);
            }
#pragma unroll
            for (int j = 0; j < 4; ++j) {
                int col = wc * 64 + j * 16 + lrow;       // LDS col 0..127
                int off = col * 128 + ((cIdx * 16) ^ ((col & 7) << 4));
                bh[j] = *(const bf16x8*)((const char*)Bh + off);
                bl[j] = *(const bf16x8*)((const char*)Bl + off);
            }
#pragma unroll
            for (int i = 0; i < 4; ++i)
#pragma unroll
                for (int j = 0; j < 4; ++j) {
                    acc[i][j] = __builtin_amdgcn_mfma_f32_16x16x32_bf16(bh[j], ah[i], acc[i][j], 0, 0, 0);
                    acc[i][j] = __builtin_amdgcn_mfma_f32_16x16x32_bf16(bl[j], ah[i], acc[i][j], 0, 0, 0);
                    acc[i][j] = __builtin_amdgcn_mfma_f32_16x16x32_bf16(bh[j], al[i], acc[i][j], 0, 0, 0);
                }
        }

        // ---- epilogue: lane -> C row (m0+i*16+lrow), 4 cols (n0+j*16+kgrp*4) ----
#pragma unroll
        for (int i = 0; i < 4; ++i) {
            int grow = m0 + i * 16 + lrow;
            if (grow >= M) continue;
            float* crow = C + (size_t)grow * N;
#pragma unroll
            for (int j = 0; j < 4; ++j) {
                int gc = n0 + j * 16 + kgrp * 4;
                if (gc + 4 <= N) {
                    float4 bv = *(const float4*)(bias + gc);
                    *(float4*)(crow + gc) = make_float4(acc[i][j][0] + bv.x,
                                                        acc[i][j][1] + bv.y,
                                                        acc[i][j][2] + bv.z,
                                                        acc[i][j][3] + bv.w);
                }
            }
        }
    }
}

// ---------------- launch ----------------
// d_out (400 MB) scratch (all dead before final GEMM):
//   hbf[N,128]bf16 | h1bf[N,128]bf16 | h2bf[N,64]bf16 | csr_src[E] | offs |
//   cursor | deg_cnt | bsums
// d_ws (~27 MB): dinv | Wfc hi/lo | W1bf | W2bf | h2hi | h2lo

extern "C" void kernel_launch(void* const* d_in, const int* in_sizes, int n_in,
                              void* d_out, int out_size, void* d_ws, size_t ws_size,
                              hipStream_t stream)
{
    const float* x   = (const float*)d_in[0];
    const float* W1  = (const float*)d_in[1];
    const float* b1  = (const float*)d_in[2];
    const float* W2  = (const float*)d_in[3];
    const float* b2  = (const float*)d_in[4];
    const float* Wfc = (const float*)d_in[5];
    const float* bfc = (const float*)d_in[6];
    const int*   ei  = (const int*)d_in[7];     // int32 in the harness

    const int Nn = in_sizes[0] / 128;      // 100000 nodes
    const int E  = in_sizes[7] / 2;        // 1600000 edges
    const int* src = ei;
    const int* dst = ei + E;

    char* ws = (char*)d_ws;
    float*          dinv   = (float*)(ws);
    unsigned short* Wfc_hi = (unsigned short*)(ws + 512 * 1024);
    unsigned short* Wfc_lo = (unsigned short*)(ws + 768 * 1024);
    unsigned short* W1_bf  = (unsigned short*)(ws + 1024 * 1024);
    unsigned short* W2_bf  = (unsigned short*)(ws + 1088 * 1024);
    unsigned short* h2hi   = (unsigned short*)(ws + 1152 * 1024);
    unsigned short* h2lo   = (unsigned short*)(ws + 1152 * 1024 + (size_t)Nn * 64 * 2);

    char* ob = (char*)d_out;
    unsigned short* hbf     = (unsigned short*)ob;                       // Nn*128 bf16
    unsigned short* h1bf    = (unsigned short*)(ob + (size_t)Nn * 256);  // Nn*128 bf16
    unsigned short* h2bf    = (unsigned short*)(ob + (size_t)Nn * 512);  // Nn*64 bf16
    int*            csr_src = (int*)(ob + (size_t)Nn * 640);             // E ints
    int*            offs    = (int*)((char*)csr_src + (size_t)E * 4);
    int*            cursor  = (int*)((char*)offs + (size_t)Nn * 4);
    int*            deg_cnt = (int*)((char*)cursor + (size_t)Nn * 4);
    int*            bsums   = (int*)((char*)deg_cnt + (size_t)Nn * 4);

    const int nScanBlocks = (Nn + SCAN_B - 1) / SCAN_B;

    // ---- setup: degree, dinv(+scan1), CSR, weight conversion (1 launch) ----
    k_zero_i<<<128, 256, 0, stream>>>(deg_cnt, Nn);
    k_deg_i<<<(E + 255) / 256, 256, 0, stream>>>(dst, deg_cnt, E);
    k_scan1<<<nScanBlocks, SCAN_B, 0, stream>>>(deg_cnt, offs, bsums, dinv, Nn);
    k_scan2<<<1, 128, 0, stream>>>(bsums, nScanBlocks);
    k_scan3<<<nScanBlocks, SCAN_B, 0, stream>>>(offs, cursor, bsums, Nn);
    k_fill<<<(E + 255) / 256, 256, 0, stream>>>(src, dst, cursor, csr_src, E);
    k_conv_all<<<1192, 128, 0, stream>>>(W1, W2, Wfc, W1_bf, W2_bf, Wfc_hi, Wfc_lo);

    // ---- layer 1: hbf = bf16(x @ W1) ----
    gemm_mfma_l1<<<dim3((Nn + 127) / 128, 1), 256, 0, stream>>>(x, W1_bf, hbf, Nn);
    k_gather128<<<(Nn + 3) / 4, 256, 0, stream>>>(hbf, csr_src, offs, dinv, b1,
                                                  h1bf, Nn, E);

    // ---- layer 2: h2bf = bf16(h1 @ W2) ----
    gemm_mfma_l2<<<dim3((Nn + 127) / 128, 1), 256, 0, stream>>>(h1bf, W2_bf, h2bf, Nn);
    k_gather64<<<(Nn + 3) / 4, 256, 0, stream>>>(h2bf, csr_src, offs, dinv, b2,
                                                 h2hi, h2lo, Nn, E);

    // ---- output layer: out = h2 @ Wfc + bfc (LDS-B, 2 M-tiles/block) ----
    gemm_mfma_out<<<dim3(8, (Nn + 255) / 256), 256, 0, stream>>>(
        h2hi, h2lo, Wfc_hi, Wfc_lo, bfc, (float*)d_out, Nn, 1000);
}